// Round 7
// baseline (878.389 us; speedup 1.0000x reference)
//
#include <hip/hip_runtime.h>
#include <hip/hip_bf16.h>
#include <math.h>

constexpr int Bc   = 4;
constexpr int Nc   = 200;
constexpr int Cc   = 64;
constexpr int Mc   = 600;    // 3*N
constexpr int ATTc = 128;
constexpr int OUTFc = 128;
constexpr int PREDc = 12;
constexpr int MAXBW = 40;
constexpr int MPAD  = 640;   // padded V^T leading dim

typedef short short4v __attribute__((ext_vector_type(4)));
typedef short short8 __attribute__((ext_vector_type(8)));
typedef float f32x4  __attribute__((ext_vector_type(4)));
typedef float f32x16 __attribute__((ext_vector_type(16)));

static __device__ __forceinline__ void bsplit(float v, short& h, short& l) {
    __hip_bfloat16 hb = __float2bfloat16(v);
    float hf = __bfloat162float(hb);
    __hip_bfloat16 lb = __float2bfloat16(v - hf);
    h = *(short*)&hb; l = *(short*)&lb;
}

// ---------------- embed + sliding window ----------------
__global__ __launch_bounds__(256)
void embed_window_k(const float* __restrict__ src, const float* __restrict__ temb,
                    const float* __restrict__ semb, float* __restrict__ dst,
                    int Tin, int nw, long total)
{
    long idx = (long)blockIdx.x * 256 + threadIdx.x;
    if (idx >= total) return;
    int c = (int)(idx & 63);
    long r = idx >> 6;
    int n = (int)(r % Nc); r /= Nc;
    int j = (int)(r % 3);  r /= 3;
    int w = (int)(r % nw);
    int b = (int)(r / nw);
    int t = w + j;
    dst[idx] = src[(((long)b * Tin + t) * Nc + n) * Cc + c]
             + temb[t * Cc + c] + semb[n * Cc + c];
}

// ------- fused node-mean + NA/NB projection -> bf16 hi/lo outputs ---------
__global__ __launch_bounds__(256)
void mean_nab_k(const float* __restrict__ cur, const float* __restrict__ Wa,
                const float* __restrict__ Wb,
                ushort* __restrict__ NAH, ushort* __restrict__ NAL,
                ushort* __restrict__ NBH, ushort* __restrict__ NBL, int BW)
{
    __shared__ float Ns[64][17];   // [k][row]
    __shared__ float Ws[64][132];  // [k][ Wa | Wb ]
    const int m0 = blockIdx.x * 16;
    const int t = threadIdx.x;
    for (int e = t; e < 1024; e += 256) {
        int r = e >> 4, c4 = (e & 15) << 2;
        *(float4*)&Ws[r][c4]      = *(const float4*)&Wa[r * 64 + c4];
        *(float4*)&Ws[r][64 + c4] = *(const float4*)&Wb[r * 64 + c4];
    }
    {
        int row = t >> 4, c4 = (t & 15) << 2;
        int gm = m0 + row;
        float4 sv = make_float4(0.f, 0.f, 0.f, 0.f);
        if (gm < Mc) {
            for (int bw = 0; bw < BW; bw++) {
                const float4 v = *(const float4*)&cur[((long)bw * Mc + gm) * Cc + c4];
                sv.x += v.x; sv.y += v.y; sv.z += v.z; sv.w += v.w;
            }
        }
        const float inv = 1.f / BW;
        Ns[c4 + 0][row] = sv.x * inv; Ns[c4 + 1][row] = sv.y * inv;
        Ns[c4 + 2][row] = sv.z * inv; Ns[c4 + 3][row] = sv.w * inv;
    }
    __syncthreads();
    const int row = t >> 4, c8 = (t & 15) * 8;
    float acc[8] = {};
    for (int k = 0; k < 64; k++) {
        float a = Ns[k][row];
        float b[8];
        *(float4*)&b[0] = *(const float4*)&Ws[k][c8];
        *(float4*)&b[4] = *(const float4*)&Ws[k][c8 + 4];
#pragma unroll
        for (int j = 0; j < 8; j++) acc[j] += a * b[j];
    }
    int gm = m0 + row;
    if (gm < Mc) {
#pragma unroll
        for (int j = 0; j < 8; j++) {
            int col = c8 + j;
            short h, l;
            bsplit(acc[j], h, l);
            if (col < 64) { NAH[gm * 64 + col] = (ushort)h; NAL[gm * 64 + col] = (ushort)l; }
            else { NBH[gm * 64 + col - 64] = (ushort)h; NBL[gm * 64 + col - 64] = (ushort)l; }
        }
    }
}

// ---------------- combined one-shot weight prep ----------------------------
__global__ __launch_bounds__(256)
void prep_k(const float* __restrict__ Wlin,
            ushort* __restrict__ WTH, ushort* __restrict__ WTL,
            const float* __restrict__ Wqkv,
            ushort* __restrict__ WQH, ushort* __restrict__ WQL)
{
    int i = blockIdx.x * 256 + threadIdx.x;
    if (i < 64 * 128) {
        int c = i >> 7, a = i & 127;
        short h, l;
        bsplit(Wlin[a * 64 + c], h, l);
        WTH[c * 128 + a] = (ushort)h;
        WTL[c * 128 + a] = (ushort)l;
    } else {
        int j = i - 64 * 128;
        if (j < 384 * 64) {
            int n = j >> 6, c = j & 63;
            short h, l;
            bsplit(Wqkv[c * 384 + n], h, l);
            WQH[n * 64 + c] = (ushort)h;
            WQL[n * 64 + c] = (ushort)l;
        }
    }
}

// ---- merged QKV projection + adjacency MM (R19-proven) --------------------
__global__ __launch_bounds__(256)
void qkv_adj_k(const float* __restrict__ CURp,
               const ushort* __restrict__ WQH, const ushort* __restrict__ WQL,
               const float* __restrict__ bias,
               ushort* __restrict__ QH, ushort* __restrict__ QL,
               ushort* __restrict__ KH, ushort* __restrict__ KL,
               ushort* __restrict__ VTH, ushort* __restrict__ VTL,
               const ushort* __restrict__ Ah, const ushort* __restrict__ Al,
               const ushort* __restrict__ Bh, const ushort* __restrict__ Bl,
               float* __restrict__ ADJ, int nqkv)
{
    __shared__ __align__(16) ushort SM[36864];   // 72 KB, multi-purpose
    const int t = threadIdx.x;
    const int lane = t & 63, w = t >> 6;
    const int lm = lane & 15, lq = lane >> 4;

    if ((int)blockIdx.x >= nqkv) {
        // ================= adjmm body =================
        const int b2 = blockIdx.x - nqkv;
        const int m0 = (b2 / 5) * 128, n0 = (b2 % 5) * 128;
        ushort (*As)[128][40] = (ushort (*)[128][40])(SM);          // 20 KB
        ushort (*Bs)[128][40] = (ushort (*)[128][40])(SM + 10240);  // 20 KB
        const int wm = (w >> 1) * 64, wn = (w & 1) * 64;

        f32x4 acc[4][4];
#pragma unroll
        for (int i = 0; i < 4; i++)
#pragma unroll
            for (int j = 0; j < 4; j++)
#pragma unroll
                for (int r = 0; r < 4; r++) acc[i][j][r] = 0.f;

        for (int k0 = 0; k0 < 64; k0 += 32) {
            __syncthreads();
#pragma unroll
            for (int p = 0; p < 2; p++) {
                int e = t + p * 256;
                int row = e >> 2, ks = (e & 3) << 3;
                {
                    int gm = m0 + row;
                    short8 vh, vl;
#pragma unroll
                    for (int q = 0; q < 8; q++) { vh[q] = 0; vl[q] = 0; }
                    if (gm < Mc) {
                        vh = *(const short8*)(Ah + (long)gm * 64 + k0 + ks);
                        vl = *(const short8*)(Al + (long)gm * 64 + k0 + ks);
                    }
                    *(short8*)&As[0][row][ks] = vh;
                    *(short8*)&As[1][row][ks] = vl;
                }
                {
                    int gn = n0 + row;
                    short8 vh, vl;
#pragma unroll
                    for (int q = 0; q < 8; q++) { vh[q] = 0; vl[q] = 0; }
                    if (gn < Mc) {
                        vh = *(const short8*)(Bh + (long)gn * 64 + k0 + ks);
                        vl = *(const short8*)(Bl + (long)gn * 64 + k0 + ks);
                    }
                    *(short8*)&Bs[0][row][ks] = vh;
                    *(short8*)&Bs[1][row][ks] = vl;
                }
            }
            __syncthreads();

            short8 af[4][2], bf[4][2];
#pragma unroll
            for (int i = 0; i < 4; i++) {
                af[i][0] = *(const short8*)&As[0][wm + i * 16 + lm][lq * 8];
                af[i][1] = *(const short8*)&As[1][wm + i * 16 + lm][lq * 8];
            }
#pragma unroll
            for (int j = 0; j < 4; j++) {
                bf[j][0] = *(const short8*)&Bs[0][wn + j * 16 + lm][lq * 8];
                bf[j][1] = *(const short8*)&Bs[1][wn + j * 16 + lm][lq * 8];
            }
#pragma unroll
            for (int i = 0; i < 4; i++)
#pragma unroll
                for (int j = 0; j < 4; j++) {
                    acc[i][j] = __builtin_amdgcn_mfma_f32_16x16x32_bf16(af[i][0], bf[j][0], acc[i][j], 0, 0, 0);
                    acc[i][j] = __builtin_amdgcn_mfma_f32_16x16x32_bf16(af[i][0], bf[j][1], acc[i][j], 0, 0, 0);
                    acc[i][j] = __builtin_amdgcn_mfma_f32_16x16x32_bf16(af[i][1], bf[j][0], acc[i][j], 0, 0, 0);
                }
        }
#pragma unroll
        for (int i = 0; i < 4; i++) {
            int gmb = m0 + wm + i * 16 + lq * 4;
#pragma unroll
            for (int j = 0; j < 4; j++) {
                int gn = n0 + wn + j * 16 + lm;
                if (gn >= Mc) continue;
#pragma unroll
                for (int r = 0; r < 4; r++) {
                    int gm = gmb + r;
                    if (gm < Mc)
                        ADJ[(long)gm * Mc + gn] = 1.f / (1.f + __expf(-acc[i][j][r] * 0.125f));
                }
            }
        }
        return;
    }

    // ================= qkv body (R14-proven) =================
    ushort* AsH = SM;                 // [128][72]
    ushort* AsL = SM + 9216;
    ushort* BsH = SM + 18432;
    ushort* BsL = SM + 27648;
    const int bid = blockIdx.x;
    const int xcd = bid & 7, slot = bid >> 3;
    const int z = (slot / 15) * 8 + xcd;
    const int r15 = slot % 15;
    const int which = r15 % 3;             // 0=q 1=k 2=v
    const int m0 = (r15 / 3) * 128;
    const int nb = which * 128;
    const float* A = CURp + (long)z * Mc * Cc;
    const int wm = (w >> 1) * 64, wn = (w & 1) * 64;

#pragma unroll
    for (int p = 0; p < 8; p++) {
        int e = t + p * 256;              // 0..2047
        int row = e >> 4, k4 = (e & 15) * 4;
        int gm = m0 + row;
        float4 v = make_float4(0.f, 0.f, 0.f, 0.f);
        if (gm < Mc) v = *(const float4*)(A + (long)gm * 64 + k4);
        short4v h4, l4;
        short hs, ls;
        bsplit(v.x, hs, ls); h4[0] = hs; l4[0] = ls;
        bsplit(v.y, hs, ls); h4[1] = hs; l4[1] = ls;
        bsplit(v.z, hs, ls); h4[2] = hs; l4[2] = ls;
        bsplit(v.w, hs, ls); h4[3] = hs; l4[3] = ls;
        *(short4v*)(AsH + row * 72 + k4) = h4;
        *(short4v*)(AsL + row * 72 + k4) = l4;
    }
#pragma unroll
    for (int p = 0; p < 4; p++) {
        int e = t + p * 256;              // 0..1023
        int row = e >> 3, seg = (e & 7) * 8;
        *(short8*)(BsH + row * 72 + seg) = *(const short8*)(WQH + (long)(nb + row) * 64 + seg);
        *(short8*)(BsL + row * 72 + seg) = *(const short8*)(WQL + (long)(nb + row) * 64 + seg);
    }
    __syncthreads();

    f32x4 acc[4][4];
#pragma unroll
    for (int i = 0; i < 4; i++)
#pragma unroll
        for (int j = 0; j < 4; j++)
#pragma unroll
            for (int r = 0; r < 4; r++) acc[i][j][r] = 0.f;

#pragma unroll
    for (int ks = 0; ks < 2; ks++) {
        short8 af[4][2], bf[4][2];
#pragma unroll
        for (int i = 0; i < 4; i++) {
            af[i][0] = *(const short8*)(AsH + (wm + i * 16 + lm) * 72 + ks * 32 + lq * 8);
            af[i][1] = *(const short8*)(AsL + (wm + i * 16 + lm) * 72 + ks * 32 + lq * 8);
        }
#pragma unroll
        for (int j = 0; j < 4; j++) {
            bf[j][0] = *(const short8*)(BsH + (wn + j * 16 + lm) * 72 + ks * 32 + lq * 8);
            bf[j][1] = *(const short8*)(BsL + (wn + j * 16 + lm) * 72 + ks * 32 + lq * 8);
        }
#pragma unroll
        for (int i = 0; i < 4; i++)
#pragma unroll
            for (int j = 0; j < 4; j++) {
                acc[i][j] = __builtin_amdgcn_mfma_f32_16x16x32_bf16(af[i][0], bf[j][0], acc[i][j], 0, 0, 0);
                acc[i][j] = __builtin_amdgcn_mfma_f32_16x16x32_bf16(af[i][0], bf[j][1], acc[i][j], 0, 0, 0);
                acc[i][j] = __builtin_amdgcn_mfma_f32_16x16x32_bf16(af[i][1], bf[j][0], acc[i][j], 0, 0, 0);
            }
    }
    __syncthreads();   // frags consumed; SM reused as C scratch

    uint* CP = (uint*)SM;                 // [128][132] uints
#pragma unroll
    for (int i = 0; i < 4; i++)
#pragma unroll
        for (int j = 0; j < 4; j++) {
            int col = wn + j * 16 + lm;
            float b = bias[nb + col];
#pragma unroll
            for (int r = 0; r < 4; r++) {
                int row = wm + i * 16 + lq * 4 + r;
                float v = acc[i][j][r] + b;
                if (which == 2) v = fmaxf(v, 0.f);
                short hs, ls;
                bsplit(v, hs, ls);
                CP[row * 132 + col] = ((uint)(ushort)ls << 16) | (uint)(ushort)hs;
            }
        }
    __syncthreads();

    if (which == 2) {
        ushort* vh = VTH + (long)z * ATTc * MPAD;
        ushort* vl = VTL + (long)z * ATTc * MPAD;
#pragma unroll
        for (int p = 0; p < 8; p++) {
            int e = t + p * 256;          // 0..2047
            int col = e >> 4, rg = (e & 15) * 8;
            if (m0 + rg < Mc) {
                short8 h8, l8;
#pragma unroll
                for (int q = 0; q < 8; q++) {
                    uint u = CP[(rg + q) * 132 + col];
                    h8[q] = (short)(u & 0xffff);
                    l8[q] = (short)(u >> 16);
                }
                *(short8*)(vh + (long)col * MPAD + m0 + rg) = h8;
                *(short8*)(vl + (long)col * MPAD + m0 + rg) = l8;
            }
        }
    } else {
        ushort* dh = (which == 0 ? QH : KH) + (long)z * Mc * ATTc;
        ushort* dl = (which == 0 ? QL : KL) + (long)z * Mc * ATTc;
#pragma unroll
        for (int p = 0; p < 8; p++) {
            int e = t + p * 256;
            int row = e >> 4, seg = (e & 15) * 8;
            int gm = m0 + row;
            if (gm < Mc) {
                short8 h8, l8;
#pragma unroll
                for (int q = 0; q < 8; q++) {
                    uint u = CP[row * 132 + seg + q];
                    h8[q] = (short)(u & 0xffff);
                    l8[q] = (short)(u >> 16);
                }
                *(short8*)(dh + (long)gm * ATTc + seg) = h8;
                *(short8*)(dl + (long)gm * ATTc + seg) = l8;
            }
        }
    }
}

// ---- fused attention R20: 32x32x16 MFMA (R16-verified math), budget-fixed -
// Waves: qt = w&1 (32 q-rows), kh = w>>1 (64-key half / 64-att half).
// Single staging reg buffer (RA only), Er/Sr merged into T, adj prefetched
// in round 1. P block-shared [64][136]. Peak live VGPR ~233 (fits 2 w/SIMD).
#define ISSUE_K(kc_, g_)                                                \
  _Pragma("unroll")                                                     \
  for (int p = 0; p < 4; p++) {                                         \
    int key = (kc_) + srow0 + 32 * p;                                   \
    short8 vh, vl;                                                      \
    _Pragma("unroll")                                                   \
    for (int q2 = 0; q2 < 8; q2++) { vh[q2] = 0; vl[q2] = 0; }          \
    if (key < Mc) {                                                     \
      vh = *(const short8*)(Khz + (long)key * ATTc + (g_) * 64 + sks);  \
      vl = *(const short8*)(Klz + (long)key * ATTc + (g_) * 64 + sks);  \
    }                                                                   \
    RAh[p] = vh; RAl[p] = vl;                                           \
  }

#define ISSUE_V(kc_, g_)                                                           \
  _Pragma("unroll")                                                                \
  for (int p = 0; p < 4; p++) {                                                    \
    int att = srow0 + 32 * p;                                                      \
    RAh[p] = *(const short8*)(Vhz + (long)att * MPAD + (kc_) + (g_) * 64 + sks);   \
    RAl[p] = *(const short8*)(Vlz + (long)att * MPAD + (kc_) + (g_) * 64 + sks);   \
  }

#define WRITE_SB()                                                      \
  _Pragma("unroll")                                                     \
  for (int p = 0; p < 4; p++) {                                         \
    *(short8*)&SB[0][srow0 + 32 * p][sks] = RAh[p];                     \
    *(short8*)&SB[1][srow0 + 32 * p][sks] = RAl[p];                     \
  }

#define MFMA32(a, b, c) __builtin_amdgcn_mfma_f32_32x32x16_bf16(a, b, c, 0, 0, 0)

#define QK_ROUND(g_)                                                       \
  _Pragma("unroll")                                                        \
  for (int al = 0; al < 4; al++) {                                         \
    short8 b0h = *(const short8*)&SB[0][kh64 + l31][al * 16 + lh8];        \
    short8 b0l = *(const short8*)&SB[1][kh64 + l31][al * 16 + lh8];        \
    short8 b1h = *(const short8*)&SB[0][kh64 + 32 + l31][al * 16 + lh8];   \
    short8 b1l = *(const short8*)&SB[1][kh64 + 32 + l31][al * 16 + lh8];   \
    s0 = MFMA32(qh[(g_) * 4 + al], b0h, s0);                               \
    s1 = MFMA32(qh[(g_) * 4 + al], b1h, s1);                               \
    s0 = MFMA32(qh[(g_) * 4 + al], b0l, s0);                               \
    s1 = MFMA32(qh[(g_) * 4 + al], b1l, s1);                               \
    s0 = MFMA32(ql[(g_) * 4 + al], b0h, s0);                               \
    s1 = MFMA32(ql[(g_) * 4 + al], b1h, s1);                               \
  }

#define PV_ROUND(g_)                                                       \
  _Pragma("unroll")                                                        \
  for (int kp = 0; kp < 4; kp++) {                                         \
    short8 pA = *(const short8*)&PHs[qt32 + l31][(g_) * 64 + kp * 16 + lh8]; \
    short8 pB = *(const short8*)&PLs[qt32 + l31][(g_) * 64 + kp * 16 + lh8]; \
    short8 v0h = *(const short8*)&SB[0][kh64 + l31][kp * 16 + lh8];        \
    short8 v0l = *(const short8*)&SB[1][kh64 + l31][kp * 16 + lh8];        \
    short8 v1h = *(const short8*)&SB[0][kh64 + 32 + l31][kp * 16 + lh8];   \
    short8 v1l = *(const short8*)&SB[1][kh64 + 32 + l31][kp * 16 + lh8];   \
    o0 = MFMA32(pA, v0h, o0); o1 = MFMA32(pA, v1h, o1);                    \
    o0 = MFMA32(pA, v0l, o0); o1 = MFMA32(pA, v1l, o1);                    \
    o0 = MFMA32(pB, v0h, o0); o1 = MFMA32(pB, v1h, o1);                    \
  }

__global__ __launch_bounds__(256, 2)
void attn_k(const ushort* __restrict__ QH, const ushort* __restrict__ QL,
            const ushort* __restrict__ KH, const ushort* __restrict__ KL,
            const ushort* __restrict__ VTH, const ushort* __restrict__ VTL,
            const float* __restrict__ adj, uint* __restrict__ OB, float scale)
{
    __shared__ __align__(16) ushort SB[2][128][72];   // K or V stage (64 k)
    __shared__ __align__(16) ushort PHs[64][136];     // block-shared P hi
    __shared__ __align__(16) ushort PLs[64][136];     //                lo
    __shared__ float RED[2][2][2][16];                // [qt][kh][lh][reg]
    const int bid = blockIdx.x;
    const int xcd = bid & 7, slot = bid >> 3;
    const int z = (slot / 10) * 8 + xcd;
    const int m0 = (slot % 10) * 64;
    const int t = threadIdx.x;
    const int lane = t & 63, w = t >> 6;
    const int l31 = lane & 31, lh = lane >> 5, lh8 = lh * 8;
    const int qt = w & 1, kh = w >> 1;
    const int qt32 = qt * 32, kh64 = kh * 64;
    const int srow0 = t >> 3;          // staging row base 0..31
    const int sks   = (t & 7) << 3;    // staging col 0..56 (x8 shorts)

    const ushort* Qhz = QH + (long)z * Mc * ATTc;
    const ushort* Qlz = QL + (long)z * Mc * ATTc;
    const ushort* Khz = KH + (long)z * Mc * ATTc;
    const ushort* Klz = KL + (long)z * Mc * ATTc;
    const ushort* Vhz = VTH + (long)z * ATTc * MPAD;
    const ushort* Vlz = VTL + (long)z * ATTc * MPAD;

    // ---- prefetch round 0 (chunk 0, K half0) ----
    short8 RAh[4], RAl[4];
    ISSUE_K(0, 0);

    // ---- Q fragments: 32 q-rows x 128 att, A-layout for 32x32x16 ----
    short8 qh[8], ql[8];
    {
        int qr = m0 + qt32 + l31;
        if (qr < Mc) {
            const ushort* qp  = Qhz + (long)qr * ATTc;
            const ushort* qp2 = Qlz + (long)qr * ATTc;
#pragma unroll
            for (int a = 0; a < 8; a++) {
                qh[a] = *(const short8*)(qp + a * 16 + lh8);
                ql[a] = *(const short8*)(qp2 + a * 16 + lh8);
            }
        } else {
#pragma unroll
            for (int a = 0; a < 8; a++)
#pragma unroll
                for (int q = 0; q < 8; q++) { qh[a][q] = 0; ql[a][q] = 0; }
        }
    }

    f32x16 o0, o1;
#pragma unroll
    for (int r = 0; r < 16; r++) { o0[r] = 0.f; o1[r] = 0.f; }
    float Tr[16] = {};
    float adjv[16][2];

    for (int c = 0; c < 5; c++) {
        const int kc = c * 128;
        f32x16 s0, s1;
#pragma unroll
        for (int r = 0; r < 16; r++) { s0[r] = 0.f; s1[r] = 0.f; }

        // ---------- round 0: K half0 (atts 0..63) ----------
        __syncthreads();
        WRITE_SB();
        ISSUE_K(kc, 1);
        __syncthreads();
        QK_ROUND(0);

        // ---------- round 1: K half1 (atts 64..127) ----------
        __syncthreads();
        WRITE_SB();
        ISSUE_V(kc, 0);
        // prefetch this chunk's adj block (consumed in epilogue)
        {
            int c0 = kc + kh64 + l31, c1 = c0 + 32;
            bool c0ok = c0 < Mc, c1ok = c1 < Mc;
#pragma unroll
            for (int r = 0; r < 16; r++) {
                int rl = (r & 3) + 8 * (r >> 2) + 4 * lh;
                int row = m0 + qt32 + rl;
                bool rok = row < Mc;
                adjv[r][0] = (rok && c0ok) ? adj[(long)row * Mc + c0] : 0.f;
                adjv[r][1] = (rok && c1ok) ? adj[(long)row * Mc + c1] : 0.f;
            }
        }
        __syncthreads();
        QK_ROUND(1);

        // ---------- epilogue: P = exp(s*scale)*adj -> shared LDS ----------
        {
            int c0 = kc + kh64 + l31, c1 = c0 + 32;
            bool c0ok = c0 < Mc, c1ok = c1 < Mc;
#pragma unroll
            for (int r = 0; r < 16; r++) {
                int rl = (r & 3) + 8 * (r >> 2) + 4 * lh;
                float e0 = c0ok ? __expf(s0[r] * scale) : 0.f;
                float e1 = c1ok ? __expf(s1[r] * scale) : 0.f;
                float p0 = e0 * adjv[r][0], p1 = e1 * adjv[r][1];
                Tr[r] += p0 + p1 + 1e-8f * (e0 + e1);
                short hs, ls;
                bsplit(p0, hs, ls);
                PHs[qt32 + rl][kh64 + l31] = (ushort)hs;
                PLs[qt32 + rl][kh64 + l31] = (ushort)ls;
                bsplit(p1, hs, ls);
                PHs[qt32 + rl][kh64 + 32 + l31] = (ushort)hs;
                PLs[qt32 + rl][kh64 + 32 + l31] = (ushort)ls;
            }
        }

        // ---------- round 2: V half0 (keys 0..63) ----------
        __syncthreads();
        WRITE_SB();
        ISSUE_V(kc, 1);
        __syncthreads();
        PV_ROUND(0);

        // ---------- round 3: V half1 (keys 64..127) ----------
        __syncthreads();
        WRITE_SB();
        if (c < 4) { ISSUE_K(kc + 128, 0); }
        __syncthreads();
        PV_ROUND(1);
    }

    // ---- combine per-wave row partials (kh split) and normalize ----
#pragma unroll
    for (int mk = 1; mk <= 16; mk <<= 1)
#pragma unroll
        for (int r = 0; r < 16; r++)
            Tr[r] += __shfl_xor(Tr[r], mk, 64);
    if (l31 == 0) {
#pragma unroll
        for (int r = 0; r < 16; r++) RED[qt][kh][lh][r] = Tr[r];
    }
    __syncthreads();
    float inv[16];
#pragma unroll
    for (int r = 0; r < 16; r++)
        inv[r] = 1.f / (RED[qt][0][lh][r] + RED[qt][1][lh][r]);
    uint* Oz = OB + (long)z * Mc * ATTc;
#pragma unroll
    for (int r = 0; r < 16; r++) {
        int rl = (r & 3) + 8 * (r >> 2) + 4 * lh;
        int row = m0 + qt32 + rl;
        if (row < Mc) {
            short hs, ls;
            float v0 = o0[r] * inv[r];
            bsplit(v0, hs, ls);
            Oz[(long)row * ATTc + kh64 + l31] =
                ((uint)(ushort)ls << 16) | (uint)(ushort)hs;
            float v1 = o1[r] * inv[r];
            bsplit(v1, hs, ls);
            Oz[(long)row * ATTc + kh64 + 32 + l31] =
                ((uint)(ushort)ls << 16) | (uint)(ushort)hs;
        }
    }
}

#undef ISSUE_K
#undef ISSUE_V
#undef WRITE_SB
#undef QK_ROUND
#undef PV_ROUND
#undef MFMA32

// ---- Wlin GEMM: CUR = unpack(OB) @ Wlin + blin; fused cand-max epilogue ---
__global__ __launch_bounds__(256)
void wlin_k(const uint* __restrict__ OB, const ushort* __restrict__ WTH,
            const ushort* __restrict__ WTL, const float* __restrict__ blin,
            float* __restrict__ CUR, int Mtot,
            float* __restrict__ cand, int first)
{
    __shared__ __align__(16) ushort As[2][128][40];
    __shared__ __align__(16) ushort Bs[2][64][136];
    const int m0 = blockIdx.x * 128;
    const int t = threadIdx.x;
    const int lane = t & 63, w = t >> 6;
    const int wm = (w >> 1) * 64, wn = (w & 1) * 32;
    const int lm = lane & 15, lq = lane >> 4;

#pragma unroll
    for (int p = 0; p < 4; p++) {
        int e = t + p * 256;
        int row = e >> 4, seg = (e & 15) << 3;
        *(short8*)&Bs[0][row][seg] = *(const short8*)(WTH + row * 128 + seg);
        *(short8*)&Bs[1][row][seg] = *(const short8*)(WTL + row * 128 + seg);
    }

    f32x4 acc[4][2];
#pragma unroll
    for (int i = 0; i < 4; i++)
#pragma unroll
        for (int j = 0; j < 2; j++)
#pragma unroll
            for (int r = 0; r < 4; r++) acc[i][j][r] = 0.f;

    for (int k0 = 0; k0 < 128; k0 += 32) {
        __syncthreads();
#pragma unroll
        for (int p = 0; p < 2; p++) {
            int e = t + p * 256;
            int row = e >> 2, seg = (e & 3) << 3;
            int gm = m0 + row;
            short8 vh, vl;
#pragma unroll
            for (int q = 0; q < 8; q++) { vh[q] = 0; vl[q] = 0; }
            if (gm < Mtot) {
                const uint4 u0 = *(const uint4*)(OB + (long)gm * 128 + k0 + seg);
                const uint4 u1 = *(const uint4*)(OB + (long)gm * 128 + k0 + seg + 4);
#pragma unroll
                for (int q = 0; q < 4; q++) {
                    uint u = ((const uint*)&u0)[q];
                    vh[q] = (short)(u & 0xffff); vl[q] = (short)(u >> 16);
                }
#pragma unroll
                for (int q = 0; q < 4; q++) {
                    uint u = ((const uint*)&u1)[q];
                    vh[4 + q] = (short)(u & 0xffff); vl[4 + q] = (short)(u >> 16);
                }
            }
            *(short8*)&As[0][row][seg] = vh;
            *(short8*)&As[1][row][seg] = vl;
        }
        __syncthreads();

        short8 af[4][2], bf[2][2];
#pragma unroll
        for (int i = 0; i < 4; i++) {
            af[i][0] = *(const short8*)&As[0][wm + i * 16 + lm][lq * 8];
            af[i][1] = *(const short8*)&As[1][wm + i * 16 + lm][lq * 8];
        }
#pragma unroll
        for (int j = 0; j < 2; j++) {
            bf[j][0] = *(const short8*)&Bs[0][wn + j * 16 + lm][k0 + lq * 8];
            bf[j][1] = *(const short8*)&Bs[1][wn + j * 16 + lm][k0 + lq * 8];
        }
#pragma unroll
        for (int i = 0; i < 4; i++)
#pragma unroll
            for (int j = 0; j < 2; j++) {
                acc[i][j] = __builtin_amdgcn_mfma_f32_16x16x32_bf16(af[i][0], bf[j][0], acc[i][j], 0, 0, 0);
                acc[i][j] = __builtin_amdgcn_mfma_f32_16x16x32_bf16(af[i][0], bf[j][1], acc[i][j], 0, 0, 0);
                acc[i][j] = __builtin_amdgcn_mfma_f32_16x16x32_bf16(af[i][1], bf[j][0], acc[i][j], 0, 0, 0);
            }
    }
#pragma unroll
    for (int i = 0; i < 4; i++) {
        int gmb = m0 + wm + i * 16 + lq * 4;
#pragma unroll
        for (int j = 0; j < 2; j++) {
            int col = wn + j * 16 + lm;
            float b = blin[col];
#pragma unroll
            for (int r = 0; r < 4; r++) {
                int gm = gmb + r;
                if (gm < Mtot) {
                    float v = acc[i][j][r] + b;
                    CUR[(long)gm * 64 + col] = v;
                    int bw = gm / Mc;
                    int m = gm - bw * Mc;
                    if (m >= 2 * Nc) {        // middle-window slice [2N:3N)
                        long o = ((long)bw * Nc + (m - 2 * Nc)) * Cc + col;
                        cand[o] = first ? v : fmaxf(cand[o], v);
                    }
                }
            }
        }
    }
}

// ---------------- output layer ----------------
__global__ __launch_bounds__(128)
void output_k(const float* __restrict__ h2, const float* __restrict__ Wo,
              const float* __restrict__ bo, float* __restrict__ out)
{
    __shared__ float ds[512];
    int row = blockIdx.x;
    int b = row / Nc, n = row % Nc;
    int t = threadIdx.x;
    for (int e = t; e < 512; e += 128) {
        int tt = e >> 6, c = e & 63;
        ds[e] = h2[(((long)b * 8 + tt) * Nc + n) * Cc + c];
    }
    __syncthreads();
    float acc = bo[t];
    for (int e = 0; e < 512; e++) acc += ds[e] * Wo[e * OUTFc + t];
    acc = fmaxf(acc, 0.f);
    for (int p = 0; p < PREDc; p++)
        out[(((long)b * PREDc + p) * Nc + n) * (long)OUTFc + t] = acc;
}

extern "C" void kernel_launch(void* const* d_in, const int* in_sizes, int n_in,
                              void* d_out, int out_size, void* d_ws, size_t ws_size,
                              hipStream_t stream)
{
    (void)in_sizes; (void)n_in; (void)out_size; (void)ws_size;
    const float* x     = (const float*)d_in[0];
    const float* Wqkv  = (const float*)d_in[4];
    const float* bqkv  = (const float*)d_in[5];
    const float* Wlin  = (const float*)d_in[6];
    const float* blin  = (const float*)d_in[7];
    const float* Wa    = (const float*)d_in[8];
    const float* Wb    = (const float*)d_in[9];
    const float* temb0 = (const float*)d_in[13];
    const float* temb1 = (const float*)d_in[14];
    const float* semb  = (const float*)d_in[15];
    const float* Wo    = (const float*)d_in[16];
    const float* bo    = (const float*)d_in[17];
    float* out = (float*)d_out;

    // ---- workspace (float offsets), ~60 MB ----
    float* ws   = (float*)d_ws;
    float* CUR  = ws;                                  // 1,536,000
    float* ADJ  = CUR + (long)MAXBW * Mc * Cc;         // 360,000
    float* CAND = ADJ + (long)Mc * Mc;                 // 512,000
    uint*  OB   = (uint*)(CAND + (long)MAXBW * Nc * Cc); // 3,072,000 u32
    float* QHf  = (float*)(OB + (long)MAXBW * Mc * ATTc);
    const long QSZ = (long)MAXBW * Mc * ATTc / 2;      // in floats
    float* QLf  = QHf + QSZ;
    float* KHf  = QLf + QSZ;
    float* KLf  = KHf + QSZ;
    float* VTHf = KLf + QSZ;
    float* VTLf = VTHf + (long)MAXBW * ATTc * MPAD / 2;
    ushort* NAH = (ushort*)(VTLf + (long)MAXBW * ATTc * MPAD / 2);
    ushort* NAL = NAH + Mc * Cc;
    ushort* NBH = NAL + Mc * Cc;
    ushort* NBL = NBH + Mc * Cc;
    ushort* WTH = NBL + Mc * Cc;                       // 64*128 each
    ushort* WTL = WTH + 64 * 128;
    ushort* WQH = WTL + 64 * 128;                      // 384*64 each
    ushort* WQL = WQH + 384 * 64;

    ushort* QH  = (ushort*)QHf;
    ushort* QL  = (ushort*)QLf;
    ushort* KH  = (ushort*)KHf;
    ushort* KL  = (ushort*)KLf;
    ushort* VTH = (ushort*)VTHf;
    ushort* VTL = (ushort*)VTLf;

    const float inv_sqrt_att = 0.08838834764831845f;   // 1/sqrt(128)

    // one-shot weight prep (both transposed bf16 hi/lo splits)
    prep_k<<<dim3(128), dim3(256), 0, stream>>>(Wlin, WTH, WTL, Wqkv, WQH, WQL);

    for (int layer = 0; layer < 2; layer++) {
        int Tin = layer ? 10 : 12;
        int nw  = Tin - 2;
        int BW  = Bc * nw;                             // 40 then 32
        int Mtot = BW * Mc;
        const float* src  = layer ? CAND : x;
        const float* temb = layer ? temb1 : temb0;

        long etotal = (long)BW * Mc * Cc;
        embed_window_k<<<dim3((unsigned)((etotal + 255) / 256)), dim3(256), 0, stream>>>(
            src, temb, semb, CUR, Tin, nw, etotal);

        for (int it = 0; it < 3; it++) {
            // node-mean -> NA/NB (bf16 split)
            mean_nab_k<<<dim3(38), dim3(256), 0, stream>>>(
                CUR, Wa, Wb, NAH, NAL, NBH, NBL, BW);

            // merged: QKV projection + adjacency MM (25 tail blocks)
            int nqkv = BW * 15;
            qkv_adj_k<<<dim3(nqkv + 25), dim3(256), 0, stream>>>(
                CUR, WQH, WQL, bqkv, QH, QL, KH, KL, VTH, VTL,
                NAH, NAL, NBH, NBL, ADJ, nqkv);

            // fused attention (R20: 32x32 MFMA, budget-fixed)
            attn_k<<<dim3(BW * 10), dim3(256), 0, stream>>>(
                QH, QL, KH, KL, VTH, VTL, ADJ, OB, inv_sqrt_att);

            // cur = O @ Wlin + blin, with fused middle-window running max
            wlin_k<<<dim3((Mtot + 127) / 128), dim3(256), 0, stream>>>(
                OB, WTH, WTL, blin, CUR, Mtot, CAND, it == 0 ? 1 : 0);
        }
    }
    output_k<<<dim3(Bc * Nc), dim3(128), 0, stream>>>(CAND, Wo, bo, out);
}

// Round 8
// 721.085 us; speedup vs baseline: 1.2181x; 1.2181x over previous
//
#include <hip/hip_runtime.h>
#include <hip/hip_bf16.h>
#include <math.h>

constexpr int Bc   = 4;
constexpr int Nc   = 200;
constexpr int Cc   = 64;
constexpr int Mc   = 600;    // 3*N
constexpr int ATTc = 128;
constexpr int OUTFc = 128;
constexpr int PREDc = 12;
constexpr int MAXBW = 40;
constexpr int MPAD  = 640;   // padded V^T leading dim

typedef short short4v __attribute__((ext_vector_type(4)));
typedef short short8 __attribute__((ext_vector_type(8)));
typedef float f32x4  __attribute__((ext_vector_type(4)));

static __device__ __forceinline__ void bsplit(float v, short& h, short& l) {
    __hip_bfloat16 hb = __float2bfloat16(v);
    float hf = __bfloat162float(hb);
    __hip_bfloat16 lb = __float2bfloat16(v - hf);
    h = *(short*)&hb; l = *(short*)&lb;
}

// ---------------- embed + sliding window ----------------
__global__ __launch_bounds__(256)
void embed_window_k(const float* __restrict__ src, const float* __restrict__ temb,
                    const float* __restrict__ semb, float* __restrict__ dst,
                    int Tin, int nw, long total)
{
    long idx = (long)blockIdx.x * 256 + threadIdx.x;
    if (idx >= total) return;
    int c = (int)(idx & 63);
    long r = idx >> 6;
    int n = (int)(r % Nc); r /= Nc;
    int j = (int)(r % 3);  r /= 3;
    int w = (int)(r % nw);
    int b = (int)(r / nw);
    int t = w + j;
    dst[idx] = src[(((long)b * Tin + t) * Nc + n) * Cc + c]
             + temb[t * Cc + c] + semb[n * Cc + c];
}

// ------- fused node-mean + NA/NB projection -> bf16 hi/lo outputs ---------
__global__ __launch_bounds__(256)
void mean_nab_k(const float* __restrict__ cur, const float* __restrict__ Wa,
                const float* __restrict__ Wb,
                ushort* __restrict__ NAH, ushort* __restrict__ NAL,
                ushort* __restrict__ NBH, ushort* __restrict__ NBL, int BW)
{
    __shared__ float Ns[64][17];   // [k][row]
    __shared__ float Ws[64][132];  // [k][ Wa | Wb ]
    const int m0 = blockIdx.x * 16;
    const int t = threadIdx.x;
    for (int e = t; e < 1024; e += 256) {
        int r = e >> 4, c4 = (e & 15) << 2;
        *(float4*)&Ws[r][c4]      = *(const float4*)&Wa[r * 64 + c4];
        *(float4*)&Ws[r][64 + c4] = *(const float4*)&Wb[r * 64 + c4];
    }
    {
        int row = t >> 4, c4 = (t & 15) << 2;
        int gm = m0 + row;
        float4 sv = make_float4(0.f, 0.f, 0.f, 0.f);
        if (gm < Mc) {
            for (int bw = 0; bw < BW; bw++) {
                const float4 v = *(const float4*)&cur[((long)bw * Mc + gm) * Cc + c4];
                sv.x += v.x; sv.y += v.y; sv.z += v.z; sv.w += v.w;
            }
        }
        const float inv = 1.f / BW;
        Ns[c4 + 0][row] = sv.x * inv; Ns[c4 + 1][row] = sv.y * inv;
        Ns[c4 + 2][row] = sv.z * inv; Ns[c4 + 3][row] = sv.w * inv;
    }
    __syncthreads();
    const int row = t >> 4, c8 = (t & 15) * 8;
    float acc[8] = {};
    for (int k = 0; k < 64; k++) {
        float a = Ns[k][row];
        float b[8];
        *(float4*)&b[0] = *(const float4*)&Ws[k][c8];
        *(float4*)&b[4] = *(const float4*)&Ws[k][c8 + 4];
#pragma unroll
        for (int j = 0; j < 8; j++) acc[j] += a * b[j];
    }
    int gm = m0 + row;
    if (gm < Mc) {
#pragma unroll
        for (int j = 0; j < 8; j++) {
            int col = c8 + j;
            short h, l;
            bsplit(acc[j], h, l);
            if (col < 64) { NAH[gm * 64 + col] = (ushort)h; NAL[gm * 64 + col] = (ushort)l; }
            else { NBH[gm * 64 + col - 64] = (ushort)h; NBL[gm * 64 + col - 64] = (ushort)l; }
        }
    }
}

// ---------------- combined one-shot weight prep ----------------------------
__global__ __launch_bounds__(256)
void prep_k(const float* __restrict__ Wlin,
            ushort* __restrict__ WTH, ushort* __restrict__ WTL,
            const float* __restrict__ Wqkv,
            ushort* __restrict__ WQH, ushort* __restrict__ WQL)
{
    int i = blockIdx.x * 256 + threadIdx.x;
    if (i < 64 * 128) {
        int c = i >> 7, a = i & 127;
        short h, l;
        bsplit(Wlin[a * 64 + c], h, l);
        WTH[c * 128 + a] = (ushort)h;
        WTL[c * 128 + a] = (ushort)l;
    } else {
        int j = i - 64 * 128;
        if (j < 384 * 64) {
            int n = j >> 6, c = j & 63;
            short h, l;
            bsplit(Wqkv[c * 384 + n], h, l);
            WQH[n * 64 + c] = (ushort)h;
            WQL[n * 64 + c] = (ushort)l;
        }
    }
}

// ---- merged QKV projection + adjacency MM (R19-proven) --------------------
__global__ __launch_bounds__(256)
void qkv_adj_k(const float* __restrict__ CURp,
               const ushort* __restrict__ WQH, const ushort* __restrict__ WQL,
               const float* __restrict__ bias,
               ushort* __restrict__ QH, ushort* __restrict__ QL,
               ushort* __restrict__ KH, ushort* __restrict__ KL,
               ushort* __restrict__ VTH, ushort* __restrict__ VTL,
               const ushort* __restrict__ Ah, const ushort* __restrict__ Al,
               const ushort* __restrict__ Bh, const ushort* __restrict__ Bl,
               float* __restrict__ ADJ, int nqkv)
{
    __shared__ __align__(16) ushort SM[36864];   // 72 KB, multi-purpose
    const int t = threadIdx.x;
    const int lane = t & 63, w = t >> 6;
    const int lm = lane & 15, lq = lane >> 4;

    if ((int)blockIdx.x >= nqkv) {
        // ================= adjmm body =================
        const int b2 = blockIdx.x - nqkv;
        const int m0 = (b2 / 5) * 128, n0 = (b2 % 5) * 128;
        ushort (*As)[128][40] = (ushort (*)[128][40])(SM);          // 20 KB
        ushort (*Bs)[128][40] = (ushort (*)[128][40])(SM + 10240);  // 20 KB
        const int wm = (w >> 1) * 64, wn = (w & 1) * 64;

        f32x4 acc[4][4];
#pragma unroll
        for (int i = 0; i < 4; i++)
#pragma unroll
            for (int j = 0; j < 4; j++)
#pragma unroll
                for (int r = 0; r < 4; r++) acc[i][j][r] = 0.f;

        for (int k0 = 0; k0 < 64; k0 += 32) {
            __syncthreads();
#pragma unroll
            for (int p = 0; p < 2; p++) {
                int e = t + p * 256;
                int row = e >> 2, ks = (e & 3) << 3;
                {
                    int gm = m0 + row;
                    short8 vh, vl;
#pragma unroll
                    for (int q = 0; q < 8; q++) { vh[q] = 0; vl[q] = 0; }
                    if (gm < Mc) {
                        vh = *(const short8*)(Ah + (long)gm * 64 + k0 + ks);
                        vl = *(const short8*)(Al + (long)gm * 64 + k0 + ks);
                    }
                    *(short8*)&As[0][row][ks] = vh;
                    *(short8*)&As[1][row][ks] = vl;
                }
                {
                    int gn = n0 + row;
                    short8 vh, vl;
#pragma unroll
                    for (int q = 0; q < 8; q++) { vh[q] = 0; vl[q] = 0; }
                    if (gn < Mc) {
                        vh = *(const short8*)(Bh + (long)gn * 64 + k0 + ks);
                        vl = *(const short8*)(Bl + (long)gn * 64 + k0 + ks);
                    }
                    *(short8*)&Bs[0][row][ks] = vh;
                    *(short8*)&Bs[1][row][ks] = vl;
                }
            }
            __syncthreads();

            short8 af[4][2], bf[4][2];
#pragma unroll
            for (int i = 0; i < 4; i++) {
                af[i][0] = *(const short8*)&As[0][wm + i * 16 + lm][lq * 8];
                af[i][1] = *(const short8*)&As[1][wm + i * 16 + lm][lq * 8];
            }
#pragma unroll
            for (int j = 0; j < 4; j++) {
                bf[j][0] = *(const short8*)&Bs[0][wn + j * 16 + lm][lq * 8];
                bf[j][1] = *(const short8*)&Bs[1][wn + j * 16 + lm][lq * 8];
            }
#pragma unroll
            for (int i = 0; i < 4; i++)
#pragma unroll
                for (int j = 0; j < 4; j++) {
                    acc[i][j] = __builtin_amdgcn_mfma_f32_16x16x32_bf16(af[i][0], bf[j][0], acc[i][j], 0, 0, 0);
                    acc[i][j] = __builtin_amdgcn_mfma_f32_16x16x32_bf16(af[i][0], bf[j][1], acc[i][j], 0, 0, 0);
                    acc[i][j] = __builtin_amdgcn_mfma_f32_16x16x32_bf16(af[i][1], bf[j][0], acc[i][j], 0, 0, 0);
                }
        }
#pragma unroll
        for (int i = 0; i < 4; i++) {
            int gmb = m0 + wm + i * 16 + lq * 4;
#pragma unroll
            for (int j = 0; j < 4; j++) {
                int gn = n0 + wn + j * 16 + lm;
                if (gn >= Mc) continue;
#pragma unroll
                for (int r = 0; r < 4; r++) {
                    int gm = gmb + r;
                    if (gm < Mc)
                        ADJ[(long)gm * Mc + gn] = 1.f / (1.f + __expf(-acc[i][j][r] * 0.125f));
                }
            }
        }
        return;
    }

    // ================= qkv body (R14-proven) =================
    ushort* AsH = SM;                 // [128][72]
    ushort* AsL = SM + 9216;
    ushort* BsH = SM + 18432;
    ushort* BsL = SM + 27648;
    const int bid = blockIdx.x;
    const int xcd = bid & 7, slot = bid >> 3;
    const int z = (slot / 15) * 8 + xcd;
    const int r15 = slot % 15;
    const int which = r15 % 3;             // 0=q 1=k 2=v
    const int m0 = (r15 / 3) * 128;
    const int nb = which * 128;
    const float* A = CURp + (long)z * Mc * Cc;
    const int wm = (w >> 1) * 64, wn = (w & 1) * 64;

#pragma unroll
    for (int p = 0; p < 8; p++) {
        int e = t + p * 256;              // 0..2047
        int row = e >> 4, k4 = (e & 15) * 4;
        int gm = m0 + row;
        float4 v = make_float4(0.f, 0.f, 0.f, 0.f);
        if (gm < Mc) v = *(const float4*)(A + (long)gm * 64 + k4);
        short4v h4, l4;
        short hs, ls;
        bsplit(v.x, hs, ls); h4[0] = hs; l4[0] = ls;
        bsplit(v.y, hs, ls); h4[1] = hs; l4[1] = ls;
        bsplit(v.z, hs, ls); h4[2] = hs; l4[2] = ls;
        bsplit(v.w, hs, ls); h4[3] = hs; l4[3] = ls;
        *(short4v*)(AsH + row * 72 + k4) = h4;
        *(short4v*)(AsL + row * 72 + k4) = l4;
    }
#pragma unroll
    for (int p = 0; p < 4; p++) {
        int e = t + p * 256;              // 0..1023
        int row = e >> 3, seg = (e & 7) * 8;
        *(short8*)(BsH + row * 72 + seg) = *(const short8*)(WQH + (long)(nb + row) * 64 + seg);
        *(short8*)(BsL + row * 72 + seg) = *(const short8*)(WQL + (long)(nb + row) * 64 + seg);
    }
    __syncthreads();

    f32x4 acc[4][4];
#pragma unroll
    for (int i = 0; i < 4; i++)
#pragma unroll
        for (int j = 0; j < 4; j++)
#pragma unroll
            for (int r = 0; r < 4; r++) acc[i][j][r] = 0.f;

#pragma unroll
    for (int ks = 0; ks < 2; ks++) {
        short8 af[4][2], bf[4][2];
#pragma unroll
        for (int i = 0; i < 4; i++) {
            af[i][0] = *(const short8*)(AsH + (wm + i * 16 + lm) * 72 + ks * 32 + lq * 8);
            af[i][1] = *(const short8*)(AsL + (wm + i * 16 + lm) * 72 + ks * 32 + lq * 8);
        }
#pragma unroll
        for (int j = 0; j < 4; j++) {
            bf[j][0] = *(const short8*)(BsH + (wn + j * 16 + lm) * 72 + ks * 32 + lq * 8);
            bf[j][1] = *(const short8*)(BsL + (wn + j * 16 + lm) * 72 + ks * 32 + lq * 8);
        }
#pragma unroll
        for (int i = 0; i < 4; i++)
#pragma unroll
            for (int j = 0; j < 4; j++) {
                acc[i][j] = __builtin_amdgcn_mfma_f32_16x16x32_bf16(af[i][0], bf[j][0], acc[i][j], 0, 0, 0);
                acc[i][j] = __builtin_amdgcn_mfma_f32_16x16x32_bf16(af[i][0], bf[j][1], acc[i][j], 0, 0, 0);
                acc[i][j] = __builtin_amdgcn_mfma_f32_16x16x32_bf16(af[i][1], bf[j][0], acc[i][j], 0, 0, 0);
            }
    }
    __syncthreads();   // frags consumed; SM reused as C scratch

    uint* CP = (uint*)SM;                 // [128][132] uints
#pragma unroll
    for (int i = 0; i < 4; i++)
#pragma unroll
        for (int j = 0; j < 4; j++) {
            int col = wn + j * 16 + lm;
            float b = bias[nb + col];
#pragma unroll
            for (int r = 0; r < 4; r++) {
                int row = wm + i * 16 + lq * 4 + r;
                float v = acc[i][j][r] + b;
                if (which == 2) v = fmaxf(v, 0.f);
                short hs, ls;
                bsplit(v, hs, ls);
                CP[row * 132 + col] = ((uint)(ushort)ls << 16) | (uint)(ushort)hs;
            }
        }
    __syncthreads();

    if (which == 2) {
        ushort* vh = VTH + (long)z * ATTc * MPAD;
        ushort* vl = VTL + (long)z * ATTc * MPAD;
#pragma unroll
        for (int p = 0; p < 8; p++) {
            int e = t + p * 256;          // 0..2047
            int col = e >> 4, rg = (e & 15) * 8;
            if (m0 + rg < Mc) {
                short8 h8, l8;
#pragma unroll
                for (int q = 0; q < 8; q++) {
                    uint u = CP[(rg + q) * 132 + col];
                    h8[q] = (short)(u & 0xffff);
                    l8[q] = (short)(u >> 16);
                }
                *(short8*)(vh + (long)col * MPAD + m0 + rg) = h8;
                *(short8*)(vl + (long)col * MPAD + m0 + rg) = l8;
            }
        }
    } else {
        ushort* dh = (which == 0 ? QH : KH) + (long)z * Mc * ATTc;
        ushort* dl = (which == 0 ? QL : KL) + (long)z * Mc * ATTc;
#pragma unroll
        for (int p = 0; p < 8; p++) {
            int e = t + p * 256;
            int row = e >> 4, seg = (e & 15) * 8;
            int gm = m0 + row;
            if (gm < Mc) {
                short8 h8, l8;
#pragma unroll
                for (int q = 0; q < 8; q++) {
                    uint u = CP[row * 132 + seg + q];
                    h8[q] = (short)(u & 0xffff);
                    l8[q] = (short)(u >> 16);
                }
                *(short8*)(dh + (long)gm * ATTc + seg) = h8;
                *(short8*)(dl + (long)gm * ATTc + seg) = l8;
            }
        }
    }
}

// ---- fused attention (R14-proven, PERMANENT): S=QK^T -> P=exp(s)*adj -> PV
// Three redesigns (R15 direct-global, R16/R20 32x32) all spilled; this
// 128-VGPR 4-wave structure is the verified local optimum. Do not restructure.
#define ISSUE_K(Dh, Dl, kc_, g_)                                        \
  _Pragma("unroll")                                                     \
  for (int p = 0; p < 4; p++) {                                         \
    int key = (kc_) + srow0 + 32 * p;                                   \
    short8 vh, vl;                                                      \
    _Pragma("unroll")                                                   \
    for (int q2 = 0; q2 < 8; q2++) { vh[q2] = 0; vl[q2] = 0; }          \
    if (key < Mc) {                                                     \
      vh = *(const short8*)(Khz + (long)key * ATTc + (g_) * 64 + sks);  \
      vl = *(const short8*)(Klz + (long)key * ATTc + (g_) * 64 + sks);  \
    }                                                                   \
    Dh[p] = vh; Dl[p] = vl;                                             \
  }

#define ISSUE_V(Dh, Dl, kc_, g_)                                                   \
  _Pragma("unroll")                                                                \
  for (int p = 0; p < 4; p++) {                                                    \
    int att = srow0 + 32 * p;                                                      \
    Dh[p] = *(const short8*)(Vhz + (long)att * MPAD + (kc_) + (g_) * 64 + sks);    \
    Dl[p] = *(const short8*)(Vlz + (long)att * MPAD + (kc_) + (g_) * 64 + sks);    \
  }

#define WRITE_SB(Dh, Dl)                                                \
  _Pragma("unroll")                                                     \
  for (int p = 0; p < 4; p++) {                                         \
    *(short8*)&SB[0][srow0 + 32 * p][sks] = Dh[p];                      \
    *(short8*)&SB[1][srow0 + 32 * p][sks] = Dl[p];                      \
  }

#define MFMA_QK(base_)                                                   \
  _Pragma("unroll")                                                      \
  for (int kk = 0; kk < 2; kk++) {                                       \
    _Pragma("unroll")                                                    \
    for (int j = 0; j < 8; j++) {                                        \
      short8 bh = *(const short8*)&SB[0][j * 16 + lm][kk * 32 + lq * 8]; \
      short8 bl = *(const short8*)&SB[1][j * 16 + lm][kk * 32 + lq * 8]; \
      sacc[j] = __builtin_amdgcn_mfma_f32_16x16x32_bf16(qh[(base_) + kk], bh, sacc[j], 0, 0, 0); \
      sacc[j] = __builtin_amdgcn_mfma_f32_16x16x32_bf16(qh[(base_) + kk], bl, sacc[j], 0, 0, 0); \
      sacc[j] = __builtin_amdgcn_mfma_f32_16x16x32_bf16(ql[(base_) + kk], bh, sacc[j], 0, 0, 0); \
    }                                                                    \
  }

#define MFMA_PV(g_)                                                      \
  _Pragma("unroll")                                                      \
  for (int kk = 0; kk < 2; kk++) {                                       \
    int po = ((g_) * 64 + kk * 32 + lq * 8) ^ ((lm >> 2) << 3);          \
    short8 ph = *(const short8*)&PH[w][lm][po];                          \
    short8 pl = *(const short8*)&PL[w][lm][po];                          \
    _Pragma("unroll")                                                    \
    for (int j = 0; j < 8; j++) {                                        \
      short8 vh = *(const short8*)&SB[0][j * 16 + lm][kk * 32 + lq * 8]; \
      short8 vl = *(const short8*)&SB[1][j * 16 + lm][kk * 32 + lq * 8]; \
      oacc[j] = __builtin_amdgcn_mfma_f32_16x16x32_bf16(ph, vh, oacc[j], 0, 0, 0); \
      oacc[j] = __builtin_amdgcn_mfma_f32_16x16x32_bf16(ph, vl, oacc[j], 0, 0, 0); \
      oacc[j] = __builtin_amdgcn_mfma_f32_16x16x32_bf16(pl, vh, oacc[j], 0, 0, 0); \
    }                                                                    \
  }

__global__ __launch_bounds__(256, 2)
void attn_k(const ushort* __restrict__ QH, const ushort* __restrict__ QL,
            const ushort* __restrict__ KH, const ushort* __restrict__ KL,
            const ushort* __restrict__ VTH, const ushort* __restrict__ VTL,
            const float* __restrict__ adj, uint* __restrict__ OB, float scale)
{
    __shared__ __align__(16) ushort SB[2][128][72];   // K or V stage (64 k)
    __shared__ __align__(16) ushort PH[4][16][152];   // wave-private P hi
    __shared__ __align__(16) ushort PL[4][16][152];   //                lo
    const int bid = blockIdx.x;
    const int xcd = bid & 7, slot = bid >> 3;
    const int z = (slot / 10) * 8 + xcd;
    const int m0 = (slot % 10) * 64;
    const int t = threadIdx.x;
    const int lane = t & 63, w = t >> 6;
    const int lm = lane & 15, lq = lane >> 4;
    const int qrow0 = m0 + w * 16;
    const int srow0 = t >> 3;          // staging row base 0..31
    const int sks   = (t & 7) << 3;    // staging col 0..56 (x8 shorts)

    const ushort* Qhz = QH + (long)z * Mc * ATTc;
    const ushort* Qlz = QL + (long)z * Mc * ATTc;
    const ushort* Khz = KH + (long)z * Mc * ATTc;
    const ushort* Klz = KL + (long)z * Mc * ATTc;
    const ushort* Vhz = VTH + (long)z * ATTc * MPAD;
    const ushort* Vlz = VTL + (long)z * ATTc * MPAD;

    // ---- prefetch round 0 (chunk 0, K half0) ----
    short8 RAh[4], RAl[4], RBh[4], RBl[4];
    ISSUE_K(RAh, RAl, 0, 0);

    // ---- Q fragments ----
    short8 qh[4], ql[4];
    {
        int qr = qrow0 + lm;
        if (qr < Mc) {
            const ushort* qp = Qhz + (long)qr * ATTc;
            const ushort* qp2 = Qlz + (long)qr * ATTc;
#pragma unroll
            for (int ks = 0; ks < 4; ks++) {
                qh[ks] = *(const short8*)(qp + ks * 32 + lq * 8);
                ql[ks] = *(const short8*)(qp2 + ks * 32 + lq * 8);
            }
        } else {
#pragma unroll
            for (int ks = 0; ks < 4; ks++)
#pragma unroll
                for (int q = 0; q < 8; q++) { qh[ks][q] = 0; ql[ks][q] = 0; }
        }
    }

    f32x4 oacc[8];
#pragma unroll
    for (int j = 0; j < 8; j++)
#pragma unroll
        for (int r = 0; r < 4; r++) oacc[j][r] = 0.f;
    float Er[4] = {}, Sr[4] = {};
    float adjv[8][4];

    for (int c = 0; c < 5; c++) {
        const int kc = c * 128;
        f32x4 sacc[8];
#pragma unroll
        for (int j = 0; j < 8; j++)
#pragma unroll
            for (int r = 0; r < 4; r++) sacc[j][r] = 0.f;

        // ---------- round 0: K half0 ----------
        __syncthreads();
        WRITE_SB(RAh, RAl);
        ISSUE_K(RBh, RBl, kc, 1);
        // prefetch this chunk's adj block into regs (consumed 2 phases later)
#pragma unroll
        for (int j = 0; j < 8; j++) {
            int col = kc + j * 16 + lm;
#pragma unroll
            for (int r = 0; r < 4; r++) {
                int row = qrow0 + lq * 4 + r;
                adjv[j][r] = (col < Mc && row < Mc) ? adj[(long)row * Mc + col] : 0.f;
            }
        }
        __syncthreads();
        MFMA_QK(0);

        // ---------- round 1: K half1 ----------
        __syncthreads();
        WRITE_SB(RBh, RBl);
        ISSUE_V(RAh, RAl, kc, 0);
        __syncthreads();
        MFMA_QK(2);

        // ---------- epilogue: P = exp(s*scale)*adj -> wave-private LDS ----
#pragma unroll
        for (int j = 0; j < 8; j++) {
            int col = kc + j * 16 + lm;
            bool cok = col < Mc;
#pragma unroll
            for (int r = 0; r < 4; r++) {
                float e = cok ? __expf(sacc[j][r] * scale) : 0.f;
                float p = e * adjv[j][r];
                Er[r] += e; Sr[r] += p;
                short hs, ls;
                bsplit(p, hs, ls);
                int cs = (j * 16 + lm) ^ (lq << 3);   // row>>2 == lq swizzle
                PH[w][lq * 4 + r][cs] = (ushort)hs;
                PL[w][lq * 4 + r][cs] = (ushort)ls;
            }
        }

        // ---------- round 2: V half0 ----------
        __syncthreads();
        WRITE_SB(RAh, RAl);
        ISSUE_V(RBh, RBl, kc, 1);
        __syncthreads();
        MFMA_PV(0);

        // ---------- round 3: V half1 ----------
        __syncthreads();
        WRITE_SB(RBh, RBl);
        if (c < 4) { ISSUE_K(RAh, RAl, kc + 128, 0); }
        __syncthreads();
        MFMA_PV(1);
    }

    // ---- row sums, then packed bf16 hi/lo store ----
#pragma unroll
    for (int mk = 1; mk <= 8; mk <<= 1)
#pragma unroll
        for (int r = 0; r < 4; r++) {
            Er[r] += __shfl_xor(Er[r], mk, 64);
            Sr[r] += __shfl_xor(Sr[r], mk, 64);
        }
    float inv[4];
#pragma unroll
    for (int r = 0; r < 4; r++) inv[r] = 1.f / (Sr[r] + 1e-8f * Er[r]);
    uint* Oz = OB + (long)z * Mc * ATTc;
#pragma unroll
    for (int j = 0; j < 8; j++)
#pragma unroll
        for (int r = 0; r < 4; r++) {
            int row = qrow0 + lq * 4 + r;
            if (row < Mc) {
                float v = oacc[j][r] * inv[r];
                short hs, ls;
                bsplit(v, hs, ls);
                Oz[(long)row * ATTc + j * 16 + lm] =
                    ((uint)(ushort)ls << 16) | (uint)(ushort)hs;
            }
        }
}

#undef ISSUE_K
#undef ISSUE_V
#undef WRITE_SB
#undef MFMA_QK
#undef MFMA_PV

// ---- Wlin GEMM: CUR = unpack(OB) @ Wlin + blin; fused cand-max epilogue ---
__global__ __launch_bounds__(256)
void wlin_k(const uint* __restrict__ OB, const ushort* __restrict__ WTH,
            const ushort* __restrict__ WTL, const float* __restrict__ blin,
            float* __restrict__ CUR, int Mtot,
            float* __restrict__ cand, int first)
{
    __shared__ __align__(16) ushort As[2][128][40];
    __shared__ __align__(16) ushort Bs[2][64][136];
    const int m0 = blockIdx.x * 128;
    const int t = threadIdx.x;
    const int lane = t & 63, w = t >> 6;
    const int wm = (w >> 1) * 64, wn = (w & 1) * 32;
    const int lm = lane & 15, lq = lane >> 4;

#pragma unroll
    for (int p = 0; p < 4; p++) {
        int e = t + p * 256;
        int row = e >> 4, seg = (e & 15) << 3;
        *(short8*)&Bs[0][row][seg] = *(const short8*)(WTH + row * 128 + seg);
        *(short8*)&Bs[1][row][seg] = *(const short8*)(WTL + row * 128 + seg);
    }

    f32x4 acc[4][2];
#pragma unroll
    for (int i = 0; i < 4; i++)
#pragma unroll
        for (int j = 0; j < 2; j++)
#pragma unroll
            for (int r = 0; r < 4; r++) acc[i][j][r] = 0.f;

    for (int k0 = 0; k0 < 128; k0 += 32) {
        __syncthreads();
#pragma unroll
        for (int p = 0; p < 2; p++) {
            int e = t + p * 256;
            int row = e >> 2, seg = (e & 3) << 3;
            int gm = m0 + row;
            short8 vh, vl;
#pragma unroll
            for (int q = 0; q < 8; q++) { vh[q] = 0; vl[q] = 0; }
            if (gm < Mtot) {
                const uint4 u0 = *(const uint4*)(OB + (long)gm * 128 + k0 + seg);
                const uint4 u1 = *(const uint4*)(OB + (long)gm * 128 + k0 + seg + 4);
#pragma unroll
                for (int q = 0; q < 4; q++) {
                    uint u = ((const uint*)&u0)[q];
                    vh[q] = (short)(u & 0xffff); vl[q] = (short)(u >> 16);
                }
#pragma unroll
                for (int q = 0; q < 4; q++) {
                    uint u = ((const uint*)&u1)[q];
                    vh[4 + q] = (short)(u & 0xffff); vl[4 + q] = (short)(u >> 16);
                }
            }
            *(short8*)&As[0][row][seg] = vh;
            *(short8*)&As[1][row][seg] = vl;
        }
        __syncthreads();

        short8 af[4][2], bf[2][2];
#pragma unroll
        for (int i = 0; i < 4; i++) {
            af[i][0] = *(const short8*)&As[0][wm + i * 16 + lm][lq * 8];
            af[i][1] = *(const short8*)&As[1][wm + i * 16 + lm][lq * 8];
        }
#pragma unroll
        for (int j = 0; j < 2; j++) {
            bf[j][0] = *(const short8*)&Bs[0][wn + j * 16 + lm][k0 + lq * 8];
            bf[j][1] = *(const short8*)&Bs[1][wn + j * 16 + lm][k0 + lq * 8];
        }
#pragma unroll
        for (int i = 0; i < 4; i++)
#pragma unroll
            for (int j = 0; j < 2; j++) {
                acc[i][j] = __builtin_amdgcn_mfma_f32_16x16x32_bf16(af[i][0], bf[j][0], acc[i][j], 0, 0, 0);
                acc[i][j] = __builtin_amdgcn_mfma_f32_16x16x32_bf16(af[i][0], bf[j][1], acc[i][j], 0, 0, 0);
                acc[i][j] = __builtin_amdgcn_mfma_f32_16x16x32_bf16(af[i][1], bf[j][0], acc[i][j], 0, 0, 0);
            }
    }
#pragma unroll
    for (int i = 0; i < 4; i++) {
        int gmb = m0 + wm + i * 16 + lq * 4;
#pragma unroll
        for (int j = 0; j < 2; j++) {
            int col = wn + j * 16 + lm;
            float b = blin[col];
#pragma unroll
            for (int r = 0; r < 4; r++) {
                int gm = gmb + r;
                if (gm < Mtot) {
                    float v = acc[i][j][r] + b;
                    CUR[(long)gm * 64 + col] = v;
                    int bw = gm / Mc;
                    int m = gm - bw * Mc;
                    if (m >= 2 * Nc) {        // middle-window slice [2N:3N)
                        long o = ((long)bw * Nc + (m - 2 * Nc)) * Cc + col;
                        cand[o] = first ? v : fmaxf(cand[o], v);
                    }
                }
            }
        }
    }
}

// ---------------- output layer ----------------
__global__ __launch_bounds__(128)
void output_k(const float* __restrict__ h2, const float* __restrict__ Wo,
              const float* __restrict__ bo, float* __restrict__ out)
{
    __shared__ float ds[512];
    int row = blockIdx.x;
    int b = row / Nc, n = row % Nc;
    int t = threadIdx.x;
    for (int e = t; e < 512; e += 128) {
        int tt = e >> 6, c = e & 63;
        ds[e] = h2[(((long)b * 8 + tt) * Nc + n) * Cc + c];
    }
    __syncthreads();
    float acc = bo[t];
    for (int e = 0; e < 512; e++) acc += ds[e] * Wo[e * OUTFc + t];
    acc = fmaxf(acc, 0.f);
    for (int p = 0; p < PREDc; p++)
        out[(((long)b * PREDc + p) * Nc + n) * (long)OUTFc + t] = acc;
}

extern "C" void kernel_launch(void* const* d_in, const int* in_sizes, int n_in,
                              void* d_out, int out_size, void* d_ws, size_t ws_size,
                              hipStream_t stream)
{
    (void)in_sizes; (void)n_in; (void)out_size; (void)ws_size;
    const float* x     = (const float*)d_in[0];
    const float* Wqkv  = (const float*)d_in[4];
    const float* bqkv  = (const float*)d_in[5];
    const float* Wlin  = (const float*)d_in[6];
    const float* blin  = (const float*)d_in[7];
    const float* Wa    = (const float*)d_in[8];
    const float* Wb    = (const float*)d_in[9];
    const float* temb0 = (const float*)d_in[13];
    const float* temb1 = (const float*)d_in[14];
    const float* semb  = (const float*)d_in[15];
    const float* Wo    = (const float*)d_in[16];
    const float* bo    = (const float*)d_in[17];
    float* out = (float*)d_out;

    // ---- workspace (float offsets), ~60 MB ----
    float* ws   = (float*)d_ws;
    float* CUR  = ws;                                  // 1,536,000
    float* ADJ  = CUR + (long)MAXBW * Mc * Cc;         // 360,000
    float* CAND = ADJ + (long)Mc * Mc;                 // 512,000
    uint*  OB   = (uint*)(CAND + (long)MAXBW * Nc * Cc); // 3,072,000 u32
    float* QHf  = (float*)(OB + (long)MAXBW * Mc * ATTc);
    const long QSZ = (long)MAXBW * Mc * ATTc / 2;      // in floats
    float* QLf  = QHf + QSZ;
    float* KHf  = QLf + QSZ;
    float* KLf  = KHf + QSZ;
    float* VTHf = KLf + QSZ;
    float* VTLf = VTHf + (long)MAXBW * ATTc * MPAD / 2;
    ushort* NAH = (ushort*)(VTLf + (long)MAXBW * ATTc * MPAD / 2);
    ushort* NAL = NAH + Mc * Cc;
    ushort* NBH = NAL + Mc * Cc;
    ushort* NBL = NBH + Mc * Cc;
    ushort* WTH = NBL + Mc * Cc;                       // 64*128 each
    ushort* WTL = WTH + 64 * 128;
    ushort* WQH = WTL + 64 * 128;                      // 384*64 each
    ushort* WQL = WQH + 384 * 64;

    ushort* QH  = (ushort*)QHf;
    ushort* QL  = (ushort*)QLf;
    ushort* KH  = (ushort*)KHf;
    ushort* KL  = (ushort*)KLf;
    ushort* VTH = (ushort*)VTHf;
    ushort* VTL = (ushort*)VTLf;

    const float inv_sqrt_att = 0.08838834764831845f;   // 1/sqrt(128)

    // one-shot weight prep (both transposed bf16 hi/lo splits)
    prep_k<<<dim3(128), dim3(256), 0, stream>>>(Wlin, WTH, WTL, Wqkv, WQH, WQL);

    for (int layer = 0; layer < 2; layer++) {
        int Tin = layer ? 10 : 12;
        int nw  = Tin - 2;
        int BW  = Bc * nw;                             // 40 then 32
        int Mtot = BW * Mc;
        const float* src  = layer ? CAND : x;
        const float* temb = layer ? temb1 : temb0;

        long etotal = (long)BW * Mc * Cc;
        embed_window_k<<<dim3((unsigned)((etotal + 255) / 256)), dim3(256), 0, stream>>>(
            src, temb, semb, CUR, Tin, nw, etotal);

        for (int it = 0; it < 3; it++) {
            // node-mean -> NA/NB (bf16 split)
            mean_nab_k<<<dim3(38), dim3(256), 0, stream>>>(
                CUR, Wa, Wb, NAH, NAL, NBH, NBL, BW);

            // merged: QKV projection + adjacency MM (25 tail blocks)
            int nqkv = BW * 15;
            qkv_adj_k<<<dim3(nqkv + 25), dim3(256), 0, stream>>>(
                CUR, WQH, WQL, bqkv, QH, QL, KH, KL, VTH, VTL,
                NAH, NAL, NBH, NBL, ADJ, nqkv);

            // fused attention (R14-proven config, permanent)
            attn_k<<<dim3(BW * 10), dim3(256), 0, stream>>>(
                QH, QL, KH, KL, VTH, VTL, ADJ, OB, inv_sqrt_att);

            // cur = O @ Wlin + blin, with fused middle-window running max
            wlin_k<<<dim3((Mtot + 127) / 128), dim3(256), 0, stream>>>(
                OB, WTH, WTL, blin, CUR, Mtot, CAND, it == 0 ? 1 : 0);
        }
    }
    output_k<<<dim3(Bc * Nc), dim3(128), 0, stream>>>(CAND, Wo, bo, out);
}

// Round 9
// 647.440 us; speedup vs baseline: 1.3567x; 1.1137x over previous
//
#include <hip/hip_runtime.h>
#include <hip/hip_bf16.h>
#include <math.h>

constexpr int Bc   = 4;
constexpr int Nc   = 200;
constexpr int Cc   = 64;
constexpr int Mc   = 600;    // 3*N
constexpr int ATTc = 128;
constexpr int OUTFc = 128;
constexpr int PREDc = 12;
constexpr int MAXBW = 40;
constexpr int MPAD  = 640;   // padded V^T leading dim

typedef short short4v __attribute__((ext_vector_type(4)));
typedef short short8 __attribute__((ext_vector_type(8)));
typedef float f32x4  __attribute__((ext_vector_type(4)));

static __device__ __forceinline__ void bsplit(float v, short& h, short& l) {
    __hip_bfloat16 hb = __float2bfloat16(v);
    float hf = __bfloat162float(hb);
    __hip_bfloat16 lb = __float2bfloat16(v - hf);
    h = *(short*)&hb; l = *(short*)&lb;
}

// ---------------- embed + sliding window ----------------
__global__ __launch_bounds__(256)
void embed_window_k(const float* __restrict__ src, const float* __restrict__ temb,
                    const float* __restrict__ semb, float* __restrict__ dst,
                    int Tin, int nw, long total)
{
    long idx = (long)blockIdx.x * 256 + threadIdx.x;
    if (idx >= total) return;
    int c = (int)(idx & 63);
    long r = idx >> 6;
    int n = (int)(r % Nc); r /= Nc;
    int j = (int)(r % 3);  r /= 3;
    int w = (int)(r % nw);
    int b = (int)(r / nw);
    int t = w + j;
    dst[idx] = src[(((long)b * Tin + t) * Nc + n) * Cc + c]
             + temb[t * Cc + c] + semb[n * Cc + c];
}

// ------- fused node-mean + NA/NB projection -> bf16 hi/lo outputs ---------
__global__ __launch_bounds__(256)
void mean_nab_k(const float* __restrict__ cur, const float* __restrict__ Wa,
                const float* __restrict__ Wb,
                ushort* __restrict__ NAH, ushort* __restrict__ NAL,
                ushort* __restrict__ NBH, ushort* __restrict__ NBL, int BW)
{
    __shared__ float Ns[64][17];   // [k][row]
    __shared__ float Ws[64][132];  // [k][ Wa | Wb ]
    const int m0 = blockIdx.x * 16;
    const int t = threadIdx.x;
    for (int e = t; e < 1024; e += 256) {
        int r = e >> 4, c4 = (e & 15) << 2;
        *(float4*)&Ws[r][c4]      = *(const float4*)&Wa[r * 64 + c4];
        *(float4*)&Ws[r][64 + c4] = *(const float4*)&Wb[r * 64 + c4];
    }
    {
        int row = t >> 4, c4 = (t & 15) << 2;
        int gm = m0 + row;
        float4 sv = make_float4(0.f, 0.f, 0.f, 0.f);
        if (gm < Mc) {
            for (int bw = 0; bw < BW; bw++) {
                const float4 v = *(const float4*)&cur[((long)bw * Mc + gm) * Cc + c4];
                sv.x += v.x; sv.y += v.y; sv.z += v.z; sv.w += v.w;
            }
        }
        const float inv = 1.f / BW;
        Ns[c4 + 0][row] = sv.x * inv; Ns[c4 + 1][row] = sv.y * inv;
        Ns[c4 + 2][row] = sv.z * inv; Ns[c4 + 3][row] = sv.w * inv;
    }
    __syncthreads();
    const int row = t >> 4, c8 = (t & 15) * 8;
    float acc[8] = {};
    for (int k = 0; k < 64; k++) {
        float a = Ns[k][row];
        float b[8];
        *(float4*)&b[0] = *(const float4*)&Ws[k][c8];
        *(float4*)&b[4] = *(const float4*)&Ws[k][c8 + 4];
#pragma unroll
        for (int j = 0; j < 8; j++) acc[j] += a * b[j];
    }
    int gm = m0 + row;
    if (gm < Mc) {
#pragma unroll
        for (int j = 0; j < 8; j++) {
            int col = c8 + j;
            short h, l;
            bsplit(acc[j], h, l);
            if (col < 64) { NAH[gm * 64 + col] = (ushort)h; NAL[gm * 64 + col] = (ushort)l; }
            else { NBH[gm * 64 + col - 64] = (ushort)h; NBL[gm * 64 + col - 64] = (ushort)l; }
        }
    }
}

// ---------------- combined one-shot weight prep ----------------------------
__global__ __launch_bounds__(256)
void prep_k(const float* __restrict__ Wlin,
            ushort* __restrict__ WTH, ushort* __restrict__ WTL,
            const float* __restrict__ Wqkv,
            ushort* __restrict__ WQH, ushort* __restrict__ WQL)
{
    int i = blockIdx.x * 256 + threadIdx.x;
    if (i < 64 * 128) {
        int c = i >> 7, a = i & 127;
        short h, l;
        bsplit(Wlin[a * 64 + c], h, l);
        WTH[c * 128 + a] = (ushort)h;
        WTL[c * 128 + a] = (ushort)l;
    } else {
        int j = i - 64 * 128;
        if (j < 384 * 64) {
            int n = j >> 6, c = j & 63;
            short h, l;
            bsplit(Wqkv[c * 384 + n], h, l);
            WQH[n * 64 + c] = (ushort)h;
            WQL[n * 64 + c] = (ushort)l;
        }
    }
}

// ---- merged QKV projection + adjacency MM (R19-proven) --------------------
__global__ __launch_bounds__(256)
void qkv_adj_k(const float* __restrict__ CURp,
               const ushort* __restrict__ WQH, const ushort* __restrict__ WQL,
               const float* __restrict__ bias,
               ushort* __restrict__ QH, ushort* __restrict__ QL,
               ushort* __restrict__ KH, ushort* __restrict__ KL,
               ushort* __restrict__ VTH, ushort* __restrict__ VTL,
               const ushort* __restrict__ Ah, const ushort* __restrict__ Al,
               const ushort* __restrict__ Bh, const ushort* __restrict__ Bl,
               float* __restrict__ ADJ, int nqkv)
{
    __shared__ __align__(16) ushort SM[36864];   // 72 KB, multi-purpose
    const int t = threadIdx.x;
    const int lane = t & 63, w = t >> 6;
    const int lm = lane & 15, lq = lane >> 4;

    if ((int)blockIdx.x >= nqkv) {
        // ================= adjmm body =================
        const int b2 = blockIdx.x - nqkv;
        const int m0 = (b2 / 5) * 128, n0 = (b2 % 5) * 128;
        ushort (*As)[128][40] = (ushort (*)[128][40])(SM);          // 20 KB
        ushort (*Bs)[128][40] = (ushort (*)[128][40])(SM + 10240);  // 20 KB
        const int wm = (w >> 1) * 64, wn = (w & 1) * 64;

        f32x4 acc[4][4];
#pragma unroll
        for (int i = 0; i < 4; i++)
#pragma unroll
            for (int j = 0; j < 4; j++)
#pragma unroll
                for (int r = 0; r < 4; r++) acc[i][j][r] = 0.f;

        for (int k0 = 0; k0 < 64; k0 += 32) {
            __syncthreads();
#pragma unroll
            for (int p = 0; p < 2; p++) {
                int e = t + p * 256;
                int row = e >> 2, ks = (e & 3) << 3;
                {
                    int gm = m0 + row;
                    short8 vh, vl;
#pragma unroll
                    for (int q = 0; q < 8; q++) { vh[q] = 0; vl[q] = 0; }
                    if (gm < Mc) {
                        vh = *(const short8*)(Ah + (long)gm * 64 + k0 + ks);
                        vl = *(const short8*)(Al + (long)gm * 64 + k0 + ks);
                    }
                    *(short8*)&As[0][row][ks] = vh;
                    *(short8*)&As[1][row][ks] = vl;
                }
                {
                    int gn = n0 + row;
                    short8 vh, vl;
#pragma unroll
                    for (int q = 0; q < 8; q++) { vh[q] = 0; vl[q] = 0; }
                    if (gn < Mc) {
                        vh = *(const short8*)(Bh + (long)gn * 64 + k0 + ks);
                        vl = *(const short8*)(Bl + (long)gn * 64 + k0 + ks);
                    }
                    *(short8*)&Bs[0][row][ks] = vh;
                    *(short8*)&Bs[1][row][ks] = vl;
                }
            }
            __syncthreads();

            short8 af[4][2], bf[4][2];
#pragma unroll
            for (int i = 0; i < 4; i++) {
                af[i][0] = *(const short8*)&As[0][wm + i * 16 + lm][lq * 8];
                af[i][1] = *(const short8*)&As[1][wm + i * 16 + lm][lq * 8];
            }
#pragma unroll
            for (int j = 0; j < 4; j++) {
                bf[j][0] = *(const short8*)&Bs[0][wn + j * 16 + lm][lq * 8];
                bf[j][1] = *(const short8*)&Bs[1][wn + j * 16 + lm][lq * 8];
            }
#pragma unroll
            for (int i = 0; i < 4; i++)
#pragma unroll
                for (int j = 0; j < 4; j++) {
                    acc[i][j] = __builtin_amdgcn_mfma_f32_16x16x32_bf16(af[i][0], bf[j][0], acc[i][j], 0, 0, 0);
                    acc[i][j] = __builtin_amdgcn_mfma_f32_16x16x32_bf16(af[i][0], bf[j][1], acc[i][j], 0, 0, 0);
                    acc[i][j] = __builtin_amdgcn_mfma_f32_16x16x32_bf16(af[i][1], bf[j][0], acc[i][j], 0, 0, 0);
                }
        }
#pragma unroll
        for (int i = 0; i < 4; i++) {
            int gmb = m0 + wm + i * 16 + lq * 4;
#pragma unroll
            for (int j = 0; j < 4; j++) {
                int gn = n0 + wn + j * 16 + lm;
                if (gn >= Mc) continue;
#pragma unroll
                for (int r = 0; r < 4; r++) {
                    int gm = gmb + r;
                    if (gm < Mc)
                        ADJ[(long)gm * Mc + gn] = 1.f / (1.f + __expf(-acc[i][j][r] * 0.125f));
                }
            }
        }
        return;
    }

    // ================= qkv body (R14-proven) =================
    ushort* AsH = SM;                 // [128][72]
    ushort* AsL = SM + 9216;
    ushort* BsH = SM + 18432;
    ushort* BsL = SM + 27648;
    const int bid = blockIdx.x;
    const int xcd = bid & 7, slot = bid >> 3;
    const int z = (slot / 15) * 8 + xcd;
    const int r15 = slot % 15;
    const int which = r15 % 3;             // 0=q 1=k 2=v
    const int m0 = (r15 / 3) * 128;
    const int nb = which * 128;
    const float* A = CURp + (long)z * Mc * Cc;
    const int wm = (w >> 1) * 64, wn = (w & 1) * 64;

#pragma unroll
    for (int p = 0; p < 8; p++) {
        int e = t + p * 256;              // 0..2047
        int row = e >> 4, k4 = (e & 15) * 4;
        int gm = m0 + row;
        float4 v = make_float4(0.f, 0.f, 0.f, 0.f);
        if (gm < Mc) v = *(const float4*)(A + (long)gm * 64 + k4);
        short4v h4, l4;
        short hs, ls;
        bsplit(v.x, hs, ls); h4[0] = hs; l4[0] = ls;
        bsplit(v.y, hs, ls); h4[1] = hs; l4[1] = ls;
        bsplit(v.z, hs, ls); h4[2] = hs; l4[2] = ls;
        bsplit(v.w, hs, ls); h4[3] = hs; l4[3] = ls;
        *(short4v*)(AsH + row * 72 + k4) = h4;
        *(short4v*)(AsL + row * 72 + k4) = l4;
    }
#pragma unroll
    for (int p = 0; p < 4; p++) {
        int e = t + p * 256;              // 0..1023
        int row = e >> 3, seg = (e & 7) * 8;
        *(short8*)(BsH + row * 72 + seg) = *(const short8*)(WQH + (long)(nb + row) * 64 + seg);
        *(short8*)(BsL + row * 72 + seg) = *(const short8*)(WQL + (long)(nb + row) * 64 + seg);
    }
    __syncthreads();

    f32x4 acc[4][4];
#pragma unroll
    for (int i = 0; i < 4; i++)
#pragma unroll
        for (int j = 0; j < 4; j++)
#pragma unroll
            for (int r = 0; r < 4; r++) acc[i][j][r] = 0.f;

#pragma unroll
    for (int ks = 0; ks < 2; ks++) {
        short8 af[4][2], bf[4][2];
#pragma unroll
        for (int i = 0; i < 4; i++) {
            af[i][0] = *(const short8*)(AsH + (wm + i * 16 + lm) * 72 + ks * 32 + lq * 8);
            af[i][1] = *(const short8*)(AsL + (wm + i * 16 + lm) * 72 + ks * 32 + lq * 8);
        }
#pragma unroll
        for (int j = 0; j < 4; j++) {
            bf[j][0] = *(const short8*)(BsH + (wn + j * 16 + lm) * 72 + ks * 32 + lq * 8);
            bf[j][1] = *(const short8*)(BsL + (wn + j * 16 + lm) * 72 + ks * 32 + lq * 8);
        }
#pragma unroll
        for (int i = 0; i < 4; i++)
#pragma unroll
            for (int j = 0; j < 4; j++) {
                acc[i][j] = __builtin_amdgcn_mfma_f32_16x16x32_bf16(af[i][0], bf[j][0], acc[i][j], 0, 0, 0);
                acc[i][j] = __builtin_amdgcn_mfma_f32_16x16x32_bf16(af[i][0], bf[j][1], acc[i][j], 0, 0, 0);
                acc[i][j] = __builtin_amdgcn_mfma_f32_16x16x32_bf16(af[i][1], bf[j][0], acc[i][j], 0, 0, 0);
            }
    }
    __syncthreads();   // frags consumed; SM reused as C scratch

    uint* CP = (uint*)SM;                 // [128][132] uints
#pragma unroll
    for (int i = 0; i < 4; i++)
#pragma unroll
        for (int j = 0; j < 4; j++) {
            int col = wn + j * 16 + lm;
            float b = bias[nb + col];
#pragma unroll
            for (int r = 0; r < 4; r++) {
                int row = wm + i * 16 + lq * 4 + r;
                float v = acc[i][j][r] + b;
                if (which == 2) v = fmaxf(v, 0.f);
                short hs, ls;
                bsplit(v, hs, ls);
                CP[row * 132 + col] = ((uint)(ushort)ls << 16) | (uint)(ushort)hs;
            }
        }
    __syncthreads();

    if (which == 2) {
        ushort* vh = VTH + (long)z * ATTc * MPAD;
        ushort* vl = VTL + (long)z * ATTc * MPAD;
#pragma unroll
        for (int p = 0; p < 8; p++) {
            int e = t + p * 256;          // 0..2047
            int col = e >> 4, rg = (e & 15) * 8;
            if (m0 + rg < Mc) {
                short8 h8, l8;
#pragma unroll
                for (int q = 0; q < 8; q++) {
                    uint u = CP[(rg + q) * 132 + col];
                    h8[q] = (short)(u & 0xffff);
                    l8[q] = (short)(u >> 16);
                }
                *(short8*)(vh + (long)col * MPAD + m0 + rg) = h8;
                *(short8*)(vl + (long)col * MPAD + m0 + rg) = l8;
            }
        }
    } else {
        ushort* dh = (which == 0 ? QH : KH) + (long)z * Mc * ATTc;
        ushort* dl = (which == 0 ? QL : KL) + (long)z * Mc * ATTc;
#pragma unroll
        for (int p = 0; p < 8; p++) {
            int e = t + p * 256;
            int row = e >> 4, seg = (e & 15) * 8;
            int gm = m0 + row;
            if (gm < Mc) {
                short8 h8, l8;
#pragma unroll
                for (int q = 0; q < 8; q++) {
                    uint u = CP[row * 132 + seg + q];
                    h8[q] = (short)(u & 0xffff);
                    l8[q] = (short)(u >> 16);
                }
                *(short8*)(dh + (long)gm * ATTc + seg) = h8;
                *(short8*)(dl + (long)gm * ATTc + seg) = l8;
            }
        }
    }
}

// ---- fused attention + Wlin (R22) -----------------------------------------
// Main loop = R14-proven structure (PERMANENT — 3 redesigns all spilled).
// Epilogue: each block holds 64 complete normalized O rows -> block-local
// 64x128x64 GEMM O@Wlin via LDS overlay (OP packed-O + Bs WlinT copy of the
// proven wlin layout), + blin bias, CUR write, fused cand-max. OB eliminated.
#define ISSUE_K(Dh, Dl, kc_, g_)                                        \
  _Pragma("unroll")                                                     \
  for (int p = 0; p < 4; p++) {                                         \
    int key = (kc_) + srow0 + 32 * p;                                   \
    short8 vh, vl;                                                      \
    _Pragma("unroll")                                                   \
    for (int q2 = 0; q2 < 8; q2++) { vh[q2] = 0; vl[q2] = 0; }          \
    if (key < Mc) {                                                     \
      vh = *(const short8*)(Khz + (long)key * ATTc + (g_) * 64 + sks);  \
      vl = *(const short8*)(Klz + (long)key * ATTc + (g_) * 64 + sks);  \
    }                                                                   \
    Dh[p] = vh; Dl[p] = vl;                                             \
  }

#define ISSUE_V(Dh, Dl, kc_, g_)                                                   \
  _Pragma("unroll")                                                                \
  for (int p = 0; p < 4; p++) {                                                    \
    int att = srow0 + 32 * p;                                                      \
    Dh[p] = *(const short8*)(Vhz + (long)att * MPAD + (kc_) + (g_) * 64 + sks);    \
    Dl[p] = *(const short8*)(Vlz + (long)att * MPAD + (kc_) + (g_) * 64 + sks);    \
  }

#define WRITE_SB(Dh, Dl)                                                \
  _Pragma("unroll")                                                     \
  for (int p = 0; p < 4; p++) {                                         \
    *(short8*)&SB[0][srow0 + 32 * p][sks] = Dh[p];                      \
    *(short8*)&SB[1][srow0 + 32 * p][sks] = Dl[p];                      \
  }

#define MFMA_QK(base_)                                                   \
  _Pragma("unroll")                                                      \
  for (int kk = 0; kk < 2; kk++) {                                       \
    _Pragma("unroll")                                                    \
    for (int j = 0; j < 8; j++) {                                        \
      short8 bh = *(const short8*)&SB[0][j * 16 + lm][kk * 32 + lq * 8]; \
      short8 bl = *(const short8*)&SB[1][j * 16 + lm][kk * 32 + lq * 8]; \
      sacc[j] = __builtin_amdgcn_mfma_f32_16x16x32_bf16(qh[(base_) + kk], bh, sacc[j], 0, 0, 0); \
      sacc[j] = __builtin_amdgcn_mfma_f32_16x16x32_bf16(qh[(base_) + kk], bl, sacc[j], 0, 0, 0); \
      sacc[j] = __builtin_amdgcn_mfma_f32_16x16x32_bf16(ql[(base_) + kk], bh, sacc[j], 0, 0, 0); \
    }                                                                    \
  }

#define MFMA_PV(g_)                                                      \
  _Pragma("unroll")                                                      \
  for (int kk = 0; kk < 2; kk++) {                                       \
    int po = ((g_) * 64 + kk * 32 + lq * 8) ^ ((lm >> 2) << 3);          \
    short8 ph = *(const short8*)&PH[w][lm][po];                          \
    short8 pl = *(const short8*)&PL[w][lm][po];                          \
    _Pragma("unroll")                                                    \
    for (int j = 0; j < 8; j++) {                                        \
      short8 vh = *(const short8*)&SB[0][j * 16 + lm][kk * 32 + lq * 8]; \
      short8 vl = *(const short8*)&SB[1][j * 16 + lm][kk * 32 + lq * 8]; \
      oacc[j] = __builtin_amdgcn_mfma_f32_16x16x32_bf16(ph, vh, oacc[j], 0, 0, 0); \
      oacc[j] = __builtin_amdgcn_mfma_f32_16x16x32_bf16(ph, vl, oacc[j], 0, 0, 0); \
      oacc[j] = __builtin_amdgcn_mfma_f32_16x16x32_bf16(pl, vh, oacc[j], 0, 0, 0); \
    }                                                                    \
  }

__global__ __launch_bounds__(256, 2)
void attn_k(const ushort* __restrict__ QH, const ushort* __restrict__ QL,
            const ushort* __restrict__ KH, const ushort* __restrict__ KL,
            const ushort* __restrict__ VTH, const ushort* __restrict__ VTL,
            const float* __restrict__ adj,
            const ushort* __restrict__ WTH, const ushort* __restrict__ WTL,
            const float* __restrict__ blin,
            float* __restrict__ CUR, float* __restrict__ cand, int first,
            float scale)
{
    __shared__ __align__(16) ushort SMEM[37888];      // 75,776 B (same as R21)
    typedef ushort sb_t[128][72];
    typedef ushort ph_t[16][152];
    sb_t* SB = (sb_t*)SMEM;                           // [2][128][72]
    ph_t* PH = (ph_t*)(SMEM + 18432);                 // [4][16][152]
    ph_t* PL = (ph_t*)(SMEM + 28160);                 // [4][16][152]
    const int bid = blockIdx.x;
    const int xcd = bid & 7, slot = bid >> 3;
    const int z = (slot / 10) * 8 + xcd;
    const int m0 = (slot % 10) * 64;
    const int t = threadIdx.x;
    const int lane = t & 63, w = t >> 6;
    const int lm = lane & 15, lq = lane >> 4;
    const int qrow0 = m0 + w * 16;
    const int srow0 = t >> 3;          // staging row base 0..31
    const int sks   = (t & 7) << 3;    // staging col 0..56 (x8 shorts)

    const ushort* Qhz = QH + (long)z * Mc * ATTc;
    const ushort* Qlz = QL + (long)z * Mc * ATTc;
    const ushort* Khz = KH + (long)z * Mc * ATTc;
    const ushort* Klz = KL + (long)z * Mc * ATTc;
    const ushort* Vhz = VTH + (long)z * ATTc * MPAD;
    const ushort* Vlz = VTL + (long)z * ATTc * MPAD;

    // ---- prefetch round 0 (chunk 0, K half0) ----
    short8 RAh[4], RAl[4], RBh[4], RBl[4];
    ISSUE_K(RAh, RAl, 0, 0);

    // ---- Q fragments ----
    short8 qh[4], ql[4];
    {
        int qr = qrow0 + lm;
        if (qr < Mc) {
            const ushort* qp = Qhz + (long)qr * ATTc;
            const ushort* qp2 = Qlz + (long)qr * ATTc;
#pragma unroll
            for (int ks = 0; ks < 4; ks++) {
                qh[ks] = *(const short8*)(qp + ks * 32 + lq * 8);
                ql[ks] = *(const short8*)(qp2 + ks * 32 + lq * 8);
            }
        } else {
#pragma unroll
            for (int ks = 0; ks < 4; ks++)
#pragma unroll
                for (int q = 0; q < 8; q++) { qh[ks][q] = 0; ql[ks][q] = 0; }
        }
    }

    f32x4 oacc[8];
#pragma unroll
    for (int j = 0; j < 8; j++)
#pragma unroll
        for (int r = 0; r < 4; r++) oacc[j][r] = 0.f;
    float Er[4] = {}, Sr[4] = {};
    float adjv[8][4];

    for (int c = 0; c < 5; c++) {
        const int kc = c * 128;
        f32x4 sacc[8];
#pragma unroll
        for (int j = 0; j < 8; j++)
#pragma unroll
            for (int r = 0; r < 4; r++) sacc[j][r] = 0.f;

        // ---------- round 0: K half0 ----------
        __syncthreads();
        WRITE_SB(RAh, RAl);
        ISSUE_K(RBh, RBl, kc, 1);
        // prefetch this chunk's adj block into regs (consumed 2 phases later)
#pragma unroll
        for (int j = 0; j < 8; j++) {
            int col = kc + j * 16 + lm;
#pragma unroll
            for (int r = 0; r < 4; r++) {
                int row = qrow0 + lq * 4 + r;
                adjv[j][r] = (col < Mc && row < Mc) ? adj[(long)row * Mc + col] : 0.f;
            }
        }
        __syncthreads();
        MFMA_QK(0);

        // ---------- round 1: K half1 ----------
        __syncthreads();
        WRITE_SB(RBh, RBl);
        ISSUE_V(RAh, RAl, kc, 0);
        __syncthreads();
        MFMA_QK(2);

        // ---------- epilogue: P = exp(s*scale)*adj -> wave-private LDS ----
#pragma unroll
        for (int j = 0; j < 8; j++) {
            int col = kc + j * 16 + lm;
            bool cok = col < Mc;
#pragma unroll
            for (int r = 0; r < 4; r++) {
                float e = cok ? __expf(sacc[j][r] * scale) : 0.f;
                float p = e * adjv[j][r];
                Er[r] += e; Sr[r] += p;
                short hs, ls;
                bsplit(p, hs, ls);
                int cs = (j * 16 + lm) ^ (lq << 3);   // row>>2 == lq swizzle
                PH[w][lq * 4 + r][cs] = (ushort)hs;
                PL[w][lq * 4 + r][cs] = (ushort)ls;
            }
        }

        // ---------- round 2: V half0 ----------
        __syncthreads();
        WRITE_SB(RAh, RAl);
        ISSUE_V(RBh, RBl, kc, 1);
        __syncthreads();
        MFMA_PV(0);

        // ---------- round 3: V half1 ----------
        __syncthreads();
        WRITE_SB(RBh, RBl);
        if (c < 4) { ISSUE_K(RAh, RAl, kc + 128, 0); }
        __syncthreads();
        MFMA_PV(1);
    }

    // ---- row sums ----
#pragma unroll
    for (int mk = 1; mk <= 8; mk <<= 1)
#pragma unroll
        for (int r = 0; r < 4; r++) {
            Er[r] += __shfl_xor(Er[r], mk, 64);
            Sr[r] += __shfl_xor(Sr[r], mk, 64);
        }
    float inv[4];
#pragma unroll
    for (int r = 0; r < 4; r++) inv[r] = 1.f / (Sr[r] + 1e-8f * Er[r]);

    // ---- fused O @ Wlin: overlay LDS (SB/PH/PL dead) ----
    __syncthreads();                       // all waves done with SB/PH/PL
    uint*   OP  = (uint*)SMEM;             // [64][132] packed O (33.8 KB)
    ushort* BsF = SMEM + 16896;            // [2][64][136] WlinT (34.8 KB)

    // stage WlinT (proven wlin layout: row = out-col, 136-stride)
#pragma unroll
    for (int p = 0; p < 4; p++) {
        int e = t + p * 256;               // 0..1023
        int row = e >> 4, seg = (e & 15) << 3;
        *(short8*)(BsF + row * 136 + seg) = *(const short8*)(WTH + row * 128 + seg);
        *(short8*)(BsF + 64 * 136 + row * 136 + seg) = *(const short8*)(WTL + row * 128 + seg);
    }
    // normalized O (packed bf16 hi|lo) -> OP, wave-private rows
#pragma unroll
    for (int j = 0; j < 8; j++)
#pragma unroll
        for (int r = 0; r < 4; r++) {
            int lrow = w * 16 + lq * 4 + r;
            float v = oacc[j][r] * inv[r];
            short hs, ls;
            bsplit(v, hs, ls);
            OP[lrow * 132 + j * 16 + lm] = ((uint)(ushort)ls << 16) | (uint)(ushort)hs;
        }
    __syncthreads();

    // block-local GEMM: each wave computes its 16 rows x 64 cols
    f32x4 cacc[4];
#pragma unroll
    for (int jj = 0; jj < 4; jj++)
#pragma unroll
        for (int r = 0; r < 4; r++) cacc[jj][r] = 0.f;

#pragma unroll
    for (int ks = 0; ks < 4; ks++) {
        short8 ah, al;
        {
            const uint* src = OP + (w * 16 + lm) * 132 + ks * 32 + lq * 8;
            const uint4 u0 = *(const uint4*)src;
            const uint4 u1 = *(const uint4*)(src + 4);
#pragma unroll
            for (int q = 0; q < 4; q++) {
                uint u = ((const uint*)&u0)[q];
                ah[q] = (short)(u & 0xffff); al[q] = (short)(u >> 16);
            }
#pragma unroll
            for (int q = 0; q < 4; q++) {
                uint u = ((const uint*)&u1)[q];
                ah[4 + q] = (short)(u & 0xffff); al[4 + q] = (short)(u >> 16);
            }
        }
#pragma unroll
        for (int jj = 0; jj < 4; jj++) {
            short8 bh = *(const short8*)(BsF + (jj * 16 + lm) * 136 + ks * 32 + lq * 8);
            short8 bl = *(const short8*)(BsF + 64 * 136 + (jj * 16 + lm) * 136 + ks * 32 + lq * 8);
            cacc[jj] = __builtin_amdgcn_mfma_f32_16x16x32_bf16(ah, bh, cacc[jj], 0, 0, 0);
            cacc[jj] = __builtin_amdgcn_mfma_f32_16x16x32_bf16(ah, bl, cacc[jj], 0, 0, 0);
            cacc[jj] = __builtin_amdgcn_mfma_f32_16x16x32_bf16(al, bh, cacc[jj], 0, 0, 0);
        }
    }

    // epilogue: bias + CUR write + fused middle-window running max
    float* CURz = CUR + (long)z * Mc * Cc;
#pragma unroll
    for (int jj = 0; jj < 4; jj++) {
        int col = jj * 16 + lm;
        float b = blin[col];
#pragma unroll
        for (int r = 0; r < 4; r++) {
            int row = m0 + w * 16 + lq * 4 + r;
            if (row < Mc) {
                float v = cacc[jj][r] + b;
                CURz[(long)row * Cc + col] = v;
                if (row >= 2 * Nc) {
                    long o = ((long)z * Nc + (row - 2 * Nc)) * Cc + col;
                    cand[o] = first ? v : fmaxf(cand[o], v);
                }
            }
        }
    }
}

#undef ISSUE_K
#undef ISSUE_V
#undef WRITE_SB
#undef MFMA_QK
#undef MFMA_PV

// ---------------- output layer ----------------
__global__ __launch_bounds__(128)
void output_k(const float* __restrict__ h2, const float* __restrict__ Wo,
              const float* __restrict__ bo, float* __restrict__ out)
{
    __shared__ float ds[512];
    int row = blockIdx.x;
    int b = row / Nc, n = row % Nc;
    int t = threadIdx.x;
    for (int e = t; e < 512; e += 128) {
        int tt = e >> 6, c = e & 63;
        ds[e] = h2[(((long)b * 8 + tt) * Nc + n) * Cc + c];
    }
    __syncthreads();
    float acc = bo[t];
    for (int e = 0; e < 512; e++) acc += ds[e] * Wo[e * OUTFc + t];
    acc = fmaxf(acc, 0.f);
    for (int p = 0; p < PREDc; p++)
        out[(((long)b * PREDc + p) * Nc + n) * (long)OUTFc + t] = acc;
}

extern "C" void kernel_launch(void* const* d_in, const int* in_sizes, int n_in,
                              void* d_out, int out_size, void* d_ws, size_t ws_size,
                              hipStream_t stream)
{
    (void)in_sizes; (void)n_in; (void)out_size; (void)ws_size;
    const float* x     = (const float*)d_in[0];
    const float* Wqkv  = (const float*)d_in[4];
    const float* bqkv  = (const float*)d_in[5];
    const float* Wlin  = (const float*)d_in[6];
    const float* blin  = (const float*)d_in[7];
    const float* Wa    = (const float*)d_in[8];
    const float* Wb    = (const float*)d_in[9];
    const float* temb0 = (const float*)d_in[13];
    const float* temb1 = (const float*)d_in[14];
    const float* semb  = (const float*)d_in[15];
    const float* Wo    = (const float*)d_in[16];
    const float* bo    = (const float*)d_in[17];
    float* out = (float*)d_out;

    // ---- workspace (float offsets, layout unchanged; OB slot now unused) --
    float* ws   = (float*)d_ws;
    float* CUR  = ws;                                  // 1,536,000
    float* ADJ  = CUR + (long)MAXBW * Mc * Cc;         // 360,000
    float* CAND = ADJ + (long)Mc * Mc;                 // 512,000
    uint*  OB   = (uint*)(CAND + (long)MAXBW * Nc * Cc); // 3,072,000 u32 (unused)
    float* QHf  = (float*)(OB + (long)MAXBW * Mc * ATTc);
    const long QSZ = (long)MAXBW * Mc * ATTc / 2;      // in floats
    float* QLf  = QHf + QSZ;
    float* KHf  = QLf + QSZ;
    float* KLf  = KHf + QSZ;
    float* VTHf = KLf + QSZ;
    float* VTLf = VTHf + (long)MAXBW * ATTc * MPAD / 2;
    ushort* NAH = (ushort*)(VTLf + (long)MAXBW * ATTc * MPAD / 2);
    ushort* NAL = NAH + Mc * Cc;
    ushort* NBH = NAL + Mc * Cc;
    ushort* NBL = NBH + Mc * Cc;
    ushort* WTH = NBL + Mc * Cc;                       // 64*128 each
    ushort* WTL = WTH + 64 * 128;
    ushort* WQH = WTL + 64 * 128;                      // 384*64 each
    ushort* WQL = WQH + 384 * 64;

    ushort* QH  = (ushort*)QHf;
    ushort* QL  = (ushort*)QLf;
    ushort* KH  = (ushort*)KHf;
    ushort* KL  = (ushort*)KLf;
    ushort* VTH = (ushort*)VTHf;
    ushort* VTL = (ushort*)VTLf;

    const float inv_sqrt_att = 0.08838834764831845f;   // 1/sqrt(128)

    // one-shot weight prep (both transposed bf16 hi/lo splits)
    prep_k<<<dim3(128), dim3(256), 0, stream>>>(Wlin, WTH, WTL, Wqkv, WQH, WQL);

    for (int layer = 0; layer < 2; layer++) {
        int Tin = layer ? 10 : 12;
        int nw  = Tin - 2;
        int BW  = Bc * nw;                             // 40 then 32
        const float* src  = layer ? CAND : x;
        const float* temb = layer ? temb1 : temb0;

        long etotal = (long)BW * Mc * Cc;
        embed_window_k<<<dim3((unsigned)((etotal + 255) / 256)), dim3(256), 0, stream>>>(
            src, temb, semb, CUR, Tin, nw, etotal);

        for (int it = 0; it < 3; it++) {
            // node-mean -> NA/NB (bf16 split)
            mean_nab_k<<<dim3(38), dim3(256), 0, stream>>>(
                CUR, Wa, Wb, NAH, NAL, NBH, NBL, BW);

            // merged: QKV projection + adjacency MM (25 tail blocks)
            int nqkv = BW * 15;
            qkv_adj_k<<<dim3(nqkv + 25), dim3(256), 0, stream>>>(
                CUR, WQH, WQL, bqkv, QH, QL, KH, KL, VTH, VTL,
                NAH, NAL, NBH, NBL, ADJ, nqkv);

            // fused attention + O@Wlin + cand-max (R22)
            attn_k<<<dim3(BW * 10), dim3(256), 0, stream>>>(
                QH, QL, KH, KL, VTH, VTL, ADJ, WTH, WTL, blin,
                CUR, CAND, it == 0 ? 1 : 0, inv_sqrt_att);
        }
    }
    output_k<<<dim3(Bc * Nc), dim3(128), 0, stream>>>(CAND, Wo, bo, out);
}

// Round 10
// 631.143 us; speedup vs baseline: 1.3917x; 1.0258x over previous
//
#include <hip/hip_runtime.h>
#include <hip/hip_bf16.h>
#include <math.h>

constexpr int Bc   = 4;
constexpr int Nc   = 200;
constexpr int Cc   = 64;
constexpr int Mc   = 600;    // 3*N
constexpr int ATTc = 128;
constexpr int OUTFc = 128;
constexpr int PREDc = 12;
constexpr int MAXBW = 40;
constexpr int MPAD  = 640;   // padded V^T leading dim

typedef short short4v __attribute__((ext_vector_type(4)));
typedef short short8 __attribute__((ext_vector_type(8)));
typedef float f32x4  __attribute__((ext_vector_type(4)));

static __device__ __forceinline__ void bsplit(float v, short& h, short& l) {
    __hip_bfloat16 hb = __float2bfloat16(v);
    float hf = __bfloat162float(hb);
    __hip_bfloat16 lb = __float2bfloat16(v - hf);
    h = *(short*)&hb; l = *(short*)&lb;
}

// ---------------- embed + sliding window ----------------
__global__ __launch_bounds__(256)
void embed_window_k(const float* __restrict__ src, const float* __restrict__ temb,
                    const float* __restrict__ semb, float* __restrict__ dst,
                    int Tin, int nw, long total)
{
    long idx = (long)blockIdx.x * 256 + threadIdx.x;
    if (idx >= total) return;
    int c = (int)(idx & 63);
    long r = idx >> 6;
    int n = (int)(r % Nc); r /= Nc;
    int j = (int)(r % 3);  r /= 3;
    int w = (int)(r % nw);
    int b = (int)(r / nw);
    int t = w + j;
    dst[idx] = src[(((long)b * Tin + t) * Nc + n) * Cc + c]
             + temb[t * Cc + c] + semb[n * Cc + c];
}

// ------- fused node-mean + NA/NB projection (R23: 150-block layout) --------
// 4 rows/block. Phase 1: coalesced bw-sum (64 threads per row). Phase 2:
// 512 projection outputs via broadcast Ns + conflict-free Ws LDS reads.
__global__ __launch_bounds__(256)
void mean_nab_k(const float* __restrict__ cur, const float* __restrict__ Wa,
                const float* __restrict__ Wb,
                ushort* __restrict__ NAH, ushort* __restrict__ NAL,
                ushort* __restrict__ NBH, ushort* __restrict__ NBL, int BW)
{
    __shared__ float Ns[4][64];    // [row][k] mean
    __shared__ float Ws[64][132];  // [k][ Wa | Wb ]
    const int m0 = blockIdx.x * 4;
    const int t = threadIdx.x;
    for (int e = t; e < 1024; e += 256) {
        int r = e >> 4, c4 = (e & 15) << 2;
        *(float4*)&Ws[r][c4]      = *(const float4*)&Wa[r * 64 + c4];
        *(float4*)&Ws[r][64 + c4] = *(const float4*)&Wb[r * 64 + c4];
    }
    {
        int row = t >> 6, c = t & 63;      // 4 rows x 64 channels
        int gm = m0 + row;
        float sv = 0.f;
        for (int bw = 0; bw < BW; bw++)
            sv += cur[((long)bw * Mc + gm) * Cc + c];
        Ns[row][c] = sv / BW;
    }
    __syncthreads();
#pragma unroll
    for (int o = 0; o < 2; o++) {
        int e = t + o * 256;               // 0..511
        int row = e >> 7, col = e & 127;
        float acc = 0.f;
        for (int k = 0; k < 64; k++)
            acc += Ns[row][k] * Ws[k][col];
        int gm = m0 + row;
        short h, l;
        bsplit(acc, h, l);
        if (col < 64) { NAH[gm * 64 + col] = (ushort)h; NAL[gm * 64 + col] = (ushort)l; }
        else { NBH[gm * 64 + col - 64] = (ushort)h; NBL[gm * 64 + col - 64] = (ushort)l; }
    }
}

// ---------------- combined one-shot weight prep ----------------------------
__global__ __launch_bounds__(256)
void prep_k(const float* __restrict__ Wlin,
            ushort* __restrict__ WTH, ushort* __restrict__ WTL,
            const float* __restrict__ Wqkv,
            ushort* __restrict__ WQH, ushort* __restrict__ WQL)
{
    int i = blockIdx.x * 256 + threadIdx.x;
    if (i < 64 * 128) {
        int c = i >> 7, a = i & 127;
        short h, l;
        bsplit(Wlin[a * 64 + c], h, l);
        WTH[c * 128 + a] = (ushort)h;
        WTL[c * 128 + a] = (ushort)l;
    } else {
        int j = i - 64 * 128;
        if (j < 384 * 64) {
            int n = j >> 6, c = j & 63;
            short h, l;
            bsplit(Wqkv[c * 384 + n], h, l);
            WQH[n * 64 + c] = (ushort)h;
            WQL[n * 64 + c] = (ushort)l;
        }
    }
}

// ---- merged QKV projection + adjacency MM (R19-proven) --------------------
__global__ __launch_bounds__(256)
void qkv_adj_k(const float* __restrict__ CURp,
               const ushort* __restrict__ WQH, const ushort* __restrict__ WQL,
               const float* __restrict__ bias,
               ushort* __restrict__ QH, ushort* __restrict__ QL,
               ushort* __restrict__ KH, ushort* __restrict__ KL,
               ushort* __restrict__ VTH, ushort* __restrict__ VTL,
               const ushort* __restrict__ Ah, const ushort* __restrict__ Al,
               const ushort* __restrict__ Bh, const ushort* __restrict__ Bl,
               float* __restrict__ ADJ, int nqkv)
{
    __shared__ __align__(16) ushort SM[36864];   // 72 KB, multi-purpose
    const int t = threadIdx.x;
    const int lane = t & 63, w = t >> 6;
    const int lm = lane & 15, lq = lane >> 4;

    if ((int)blockIdx.x >= nqkv) {
        // ================= adjmm body =================
        const int b2 = blockIdx.x - nqkv;
        const int m0 = (b2 / 5) * 128, n0 = (b2 % 5) * 128;
        ushort (*As)[128][40] = (ushort (*)[128][40])(SM);          // 20 KB
        ushort (*Bs)[128][40] = (ushort (*)[128][40])(SM + 10240);  // 20 KB
        const int wm = (w >> 1) * 64, wn = (w & 1) * 64;

        f32x4 acc[4][4];
#pragma unroll
        for (int i = 0; i < 4; i++)
#pragma unroll
            for (int j = 0; j < 4; j++)
#pragma unroll
                for (int r = 0; r < 4; r++) acc[i][j][r] = 0.f;

        for (int k0 = 0; k0 < 64; k0 += 32) {
            __syncthreads();
#pragma unroll
            for (int p = 0; p < 2; p++) {
                int e = t + p * 256;
                int row = e >> 2, ks = (e & 3) << 3;
                {
                    int gm = m0 + row;
                    short8 vh, vl;
#pragma unroll
                    for (int q = 0; q < 8; q++) { vh[q] = 0; vl[q] = 0; }
                    if (gm < Mc) {
                        vh = *(const short8*)(Ah + (long)gm * 64 + k0 + ks);
                        vl = *(const short8*)(Al + (long)gm * 64 + k0 + ks);
                    }
                    *(short8*)&As[0][row][ks] = vh;
                    *(short8*)&As[1][row][ks] = vl;
                }
                {
                    int gn = n0 + row;
                    short8 vh, vl;
#pragma unroll
                    for (int q = 0; q < 8; q++) { vh[q] = 0; vl[q] = 0; }
                    if (gn < Mc) {
                        vh = *(const short8*)(Bh + (long)gn * 64 + k0 + ks);
                        vl = *(const short8*)(Bl + (long)gn * 64 + k0 + ks);
                    }
                    *(short8*)&Bs[0][row][ks] = vh;
                    *(short8*)&Bs[1][row][ks] = vl;
                }
            }
            __syncthreads();

            short8 af[4][2], bf[4][2];
#pragma unroll
            for (int i = 0; i < 4; i++) {
                af[i][0] = *(const short8*)&As[0][wm + i * 16 + lm][lq * 8];
                af[i][1] = *(const short8*)&As[1][wm + i * 16 + lm][lq * 8];
            }
#pragma unroll
            for (int j = 0; j < 4; j++) {
                bf[j][0] = *(const short8*)&Bs[0][wn + j * 16 + lm][lq * 8];
                bf[j][1] = *(const short8*)&Bs[1][wn + j * 16 + lm][lq * 8];
            }
#pragma unroll
            for (int i = 0; i < 4; i++)
#pragma unroll
                for (int j = 0; j < 4; j++) {
                    acc[i][j] = __builtin_amdgcn_mfma_f32_16x16x32_bf16(af[i][0], bf[j][0], acc[i][j], 0, 0, 0);
                    acc[i][j] = __builtin_amdgcn_mfma_f32_16x16x32_bf16(af[i][0], bf[j][1], acc[i][j], 0, 0, 0);
                    acc[i][j] = __builtin_amdgcn_mfma_f32_16x16x32_bf16(af[i][1], bf[j][0], acc[i][j], 0, 0, 0);
                }
        }
#pragma unroll
        for (int i = 0; i < 4; i++) {
            int gmb = m0 + wm + i * 16 + lq * 4;
#pragma unroll
            for (int j = 0; j < 4; j++) {
                int gn = n0 + wn + j * 16 + lm;
                if (gn >= Mc) continue;
#pragma unroll
                for (int r = 0; r < 4; r++) {
                    int gm = gmb + r;
                    if (gm < Mc)
                        ADJ[(long)gm * Mc + gn] = 1.f / (1.f + __expf(-acc[i][j][r] * 0.125f));
                }
            }
        }
        return;
    }

    // ================= qkv body (R14-proven) =================
    ushort* AsH = SM;                 // [128][72]
    ushort* AsL = SM + 9216;
    ushort* BsH = SM + 18432;
    ushort* BsL = SM + 27648;
    const int bid = blockIdx.x;
    const int xcd = bid & 7, slot = bid >> 3;
    const int z = (slot / 15) * 8 + xcd;
    const int r15 = slot % 15;
    const int which = r15 % 3;             // 0=q 1=k 2=v
    const int m0 = (r15 / 3) * 128;
    const int nb = which * 128;
    const float* A = CURp + (long)z * Mc * Cc;
    const int wm = (w >> 1) * 64, wn = (w & 1) * 64;

#pragma unroll
    for (int p = 0; p < 8; p++) {
        int e = t + p * 256;              // 0..2047
        int row = e >> 4, k4 = (e & 15) * 4;
        int gm = m0 + row;
        float4 v = make_float4(0.f, 0.f, 0.f, 0.f);
        if (gm < Mc) v = *(const float4*)(A + (long)gm * 64 + k4);
        short4v h4, l4;
        short hs, ls;
        bsplit(v.x, hs, ls); h4[0] = hs; l4[0] = ls;
        bsplit(v.y, hs, ls); h4[1] = hs; l4[1] = ls;
        bsplit(v.z, hs, ls); h4[2] = hs; l4[2] = ls;
        bsplit(v.w, hs, ls); h4[3] = hs; l4[3] = ls;
        *(short4v*)(AsH + row * 72 + k4) = h4;
        *(short4v*)(AsL + row * 72 + k4) = l4;
    }
#pragma unroll
    for (int p = 0; p < 4; p++) {
        int e = t + p * 256;              // 0..1023
        int row = e >> 3, seg = (e & 7) * 8;
        *(short8*)(BsH + row * 72 + seg) = *(const short8*)(WQH + (long)(nb + row) * 64 + seg);
        *(short8*)(BsL + row * 72 + seg) = *(const short8*)(WQL + (long)(nb + row) * 64 + seg);
    }
    __syncthreads();

    f32x4 acc[4][4];
#pragma unroll
    for (int i = 0; i < 4; i++)
#pragma unroll
        for (int j = 0; j < 4; j++)
#pragma unroll
            for (int r = 0; r < 4; r++) acc[i][j][r] = 0.f;

#pragma unroll
    for (int ks = 0; ks < 2; ks++) {
        short8 af[4][2], bf[4][2];
#pragma unroll
        for (int i = 0; i < 4; i++) {
            af[i][0] = *(const short8*)(AsH + (wm + i * 16 + lm) * 72 + ks * 32 + lq * 8);
            af[i][1] = *(const short8*)(AsL + (wm + i * 16 + lm) * 72 + ks * 32 + lq * 8);
        }
#pragma unroll
        for (int j = 0; j < 4; j++) {
            bf[j][0] = *(const short8*)(BsH + (wn + j * 16 + lm) * 72 + ks * 32 + lq * 8);
            bf[j][1] = *(const short8*)(BsL + (wn + j * 16 + lm) * 72 + ks * 32 + lq * 8);
        }
#pragma unroll
        for (int i = 0; i < 4; i++)
#pragma unroll
            for (int j = 0; j < 4; j++) {
                acc[i][j] = __builtin_amdgcn_mfma_f32_16x16x32_bf16(af[i][0], bf[j][0], acc[i][j], 0, 0, 0);
                acc[i][j] = __builtin_amdgcn_mfma_f32_16x16x32_bf16(af[i][0], bf[j][1], acc[i][j], 0, 0, 0);
                acc[i][j] = __builtin_amdgcn_mfma_f32_16x16x32_bf16(af[i][1], bf[j][0], acc[i][j], 0, 0, 0);
            }
    }
    __syncthreads();   // frags consumed; SM reused as C scratch

    uint* CP = (uint*)SM;                 // [128][132] uints
#pragma unroll
    for (int i = 0; i < 4; i++)
#pragma unroll
        for (int j = 0; j < 4; j++) {
            int col = wn + j * 16 + lm;
            float b = bias[nb + col];
#pragma unroll
            for (int r = 0; r < 4; r++) {
                int row = wm + i * 16 + lq * 4 + r;
                float v = acc[i][j][r] + b;
                if (which == 2) v = fmaxf(v, 0.f);
                short hs, ls;
                bsplit(v, hs, ls);
                CP[row * 132 + col] = ((uint)(ushort)ls << 16) | (uint)(ushort)hs;
            }
        }
    __syncthreads();

    if (which == 2) {
        ushort* vh = VTH + (long)z * ATTc * MPAD;
        ushort* vl = VTL + (long)z * ATTc * MPAD;
#pragma unroll
        for (int p = 0; p < 8; p++) {
            int e = t + p * 256;          // 0..2047
            int col = e >> 4, rg = (e & 15) * 8;
            if (m0 + rg < Mc) {
                short8 h8, l8;
#pragma unroll
                for (int q = 0; q < 8; q++) {
                    uint u = CP[(rg + q) * 132 + col];
                    h8[q] = (short)(u & 0xffff);
                    l8[q] = (short)(u >> 16);
                }
                *(short8*)(vh + (long)col * MPAD + m0 + rg) = h8;
                *(short8*)(vl + (long)col * MPAD + m0 + rg) = l8;
            }
        }
    } else {
        ushort* dh = (which == 0 ? QH : KH) + (long)z * Mc * ATTc;
        ushort* dl = (which == 0 ? QL : KL) + (long)z * Mc * ATTc;
#pragma unroll
        for (int p = 0; p < 8; p++) {
            int e = t + p * 256;
            int row = e >> 4, seg = (e & 15) * 8;
            int gm = m0 + row;
            if (gm < Mc) {
                short8 h8, l8;
#pragma unroll
                for (int q = 0; q < 8; q++) {
                    uint u = CP[row * 132 + seg + q];
                    h8[q] = (short)(u & 0xffff);
                    l8[q] = (short)(u >> 16);
                }
                *(short8*)(dh + (long)gm * ATTc + seg) = h8;
                *(short8*)(dl + (long)gm * ATTc + seg) = l8;
            }
        }
    }
}

// ---- fused attention + Wlin (R22-proven main loop; R23: T14 WlinT stage) --
#define ISSUE_K(Dh, Dl, kc_, g_)                                        \
  _Pragma("unroll")                                                     \
  for (int p = 0; p < 4; p++) {                                         \
    int key = (kc_) + srow0 + 32 * p;                                   \
    short8 vh, vl;                                                      \
    _Pragma("unroll")                                                   \
    for (int q2 = 0; q2 < 8; q2++) { vh[q2] = 0; vl[q2] = 0; }          \
    if (key < Mc) {                                                     \
      vh = *(const short8*)(Khz + (long)key * ATTc + (g_) * 64 + sks);  \
      vl = *(const short8*)(Klz + (long)key * ATTc + (g_) * 64 + sks);  \
    }                                                                   \
    Dh[p] = vh; Dl[p] = vl;                                             \
  }

#define ISSUE_V(Dh, Dl, kc_, g_)                                                   \
  _Pragma("unroll")                                                                \
  for (int p = 0; p < 4; p++) {                                                    \
    int att = srow0 + 32 * p;                                                      \
    Dh[p] = *(const short8*)(Vhz + (long)att * MPAD + (kc_) + (g_) * 64 + sks);    \
    Dl[p] = *(const short8*)(Vlz + (long)att * MPAD + (kc_) + (g_) * 64 + sks);    \
  }

#define WRITE_SB(Dh, Dl)                                                \
  _Pragma("unroll")                                                     \
  for (int p = 0; p < 4; p++) {                                         \
    *(short8*)&SB[0][srow0 + 32 * p][sks] = Dh[p];                      \
    *(short8*)&SB[1][srow0 + 32 * p][sks] = Dl[p];                      \
  }

#define MFMA_QK(base_)                                                   \
  _Pragma("unroll")                                                      \
  for (int kk = 0; kk < 2; kk++) {                                       \
    _Pragma("unroll")                                                    \
    for (int j = 0; j < 8; j++) {                                        \
      short8 bh = *(const short8*)&SB[0][j * 16 + lm][kk * 32 + lq * 8]; \
      short8 bl = *(const short8*)&SB[1][j * 16 + lm][kk * 32 + lq * 8]; \
      sacc[j] = __builtin_amdgcn_mfma_f32_16x16x32_bf16(qh[(base_) + kk], bh, sacc[j], 0, 0, 0); \
      sacc[j] = __builtin_amdgcn_mfma_f32_16x16x32_bf16(qh[(base_) + kk], bl, sacc[j], 0, 0, 0); \
      sacc[j] = __builtin_amdgcn_mfma_f32_16x16x32_bf16(ql[(base_) + kk], bh, sacc[j], 0, 0, 0); \
    }                                                                    \
  }

#define MFMA_PV(g_)                                                      \
  _Pragma("unroll")                                                      \
  for (int kk = 0; kk < 2; kk++) {                                       \
    int po = ((g_) * 64 + kk * 32 + lq * 8) ^ ((lm >> 2) << 3);          \
    short8 ph = *(const short8*)&PH[w][lm][po];                          \
    short8 pl = *(const short8*)&PL[w][lm][po];                          \
    _Pragma("unroll")                                                    \
    for (int j = 0; j < 8; j++) {                                        \
      short8 vh = *(const short8*)&SB[0][j * 16 + lm][kk * 32 + lq * 8]; \
      short8 vl = *(const short8*)&SB[1][j * 16 + lm][kk * 32 + lq * 8]; \
      oacc[j] = __builtin_amdgcn_mfma_f32_16x16x32_bf16(ph, vh, oacc[j], 0, 0, 0); \
      oacc[j] = __builtin_amdgcn_mfma_f32_16x16x32_bf16(ph, vl, oacc[j], 0, 0, 0); \
      oacc[j] = __builtin_amdgcn_mfma_f32_16x16x32_bf16(pl, vh, oacc[j], 0, 0, 0); \
    }                                                                    \
  }

__global__ __launch_bounds__(256, 2)
void attn_k(const ushort* __restrict__ QH, const ushort* __restrict__ QL,
            const ushort* __restrict__ KH, const ushort* __restrict__ KL,
            const ushort* __restrict__ VTH, const ushort* __restrict__ VTL,
            const float* __restrict__ adj,
            const ushort* __restrict__ WTH, const ushort* __restrict__ WTL,
            const float* __restrict__ blin,
            float* __restrict__ CUR, float* __restrict__ cand, int first,
            float scale)
{
    __shared__ __align__(16) ushort SMEM[37888];      // 75,776 B
    typedef ushort sb_t[128][72];
    typedef ushort ph_t[16][152];
    sb_t* SB = (sb_t*)SMEM;                           // [2][128][72]
    ph_t* PH = (ph_t*)(SMEM + 18432);                 // [4][16][152]
    ph_t* PL = (ph_t*)(SMEM + 28160);                 // [4][16][152]
    const int bid = blockIdx.x;
    const int xcd = bid & 7, slot = bid >> 3;
    const int z = (slot / 10) * 8 + xcd;
    const int m0 = (slot % 10) * 64;
    const int t = threadIdx.x;
    const int lane = t & 63, w = t >> 6;
    const int lm = lane & 15, lq = lane >> 4;
    const int qrow0 = m0 + w * 16;
    const int srow0 = t >> 3;          // staging row base 0..31
    const int sks   = (t & 7) << 3;    // staging col 0..56 (x8 shorts)

    const ushort* Qhz = QH + (long)z * Mc * ATTc;
    const ushort* Qlz = QL + (long)z * Mc * ATTc;
    const ushort* Khz = KH + (long)z * Mc * ATTc;
    const ushort* Klz = KL + (long)z * Mc * ATTc;
    const ushort* Vhz = VTH + (long)z * ATTc * MPAD;
    const ushort* Vlz = VTL + (long)z * ATTc * MPAD;

    // ---- prefetch round 0 (chunk 0, K half0) ----
    short8 RAh[4], RAl[4], RBh[4], RBl[4];
    ISSUE_K(RAh, RAl, 0, 0);

    // ---- Q fragments ----
    short8 qh[4], ql[4];
    {
        int qr = qrow0 + lm;
        if (qr < Mc) {
            const ushort* qp = Qhz + (long)qr * ATTc;
            const ushort* qp2 = Qlz + (long)qr * ATTc;
#pragma unroll
            for (int ks = 0; ks < 4; ks++) {
                qh[ks] = *(const short8*)(qp + ks * 32 + lq * 8);
                ql[ks] = *(const short8*)(qp2 + ks * 32 + lq * 8);
            }
        } else {
#pragma unroll
            for (int ks = 0; ks < 4; ks++)
#pragma unroll
                for (int q = 0; q < 8; q++) { qh[ks][q] = 0; ql[ks][q] = 0; }
        }
    }

    f32x4 oacc[8];
#pragma unroll
    for (int j = 0; j < 8; j++)
#pragma unroll
        for (int r = 0; r < 4; r++) oacc[j][r] = 0.f;
    float Er[4] = {}, Sr[4] = {};
    float adjv[8][4];

    for (int c = 0; c < 5; c++) {
        const int kc = c * 128;
        f32x4 sacc[8];
#pragma unroll
        for (int j = 0; j < 8; j++)
#pragma unroll
            for (int r = 0; r < 4; r++) sacc[j][r] = 0.f;

        // ---------- round 0: K half0 ----------
        __syncthreads();
        WRITE_SB(RAh, RAl);
        ISSUE_K(RBh, RBl, kc, 1);
        // prefetch this chunk's adj block into regs (consumed 2 phases later)
#pragma unroll
        for (int j = 0; j < 8; j++) {
            int col = kc + j * 16 + lm;
#pragma unroll
            for (int r = 0; r < 4; r++) {
                int row = qrow0 + lq * 4 + r;
                adjv[j][r] = (col < Mc && row < Mc) ? adj[(long)row * Mc + col] : 0.f;
            }
        }
        __syncthreads();
        MFMA_QK(0);

        // ---------- round 1: K half1 ----------
        __syncthreads();
        WRITE_SB(RBh, RBl);
        ISSUE_V(RAh, RAl, kc, 0);
        __syncthreads();
        MFMA_QK(2);

        // ---------- epilogue: P = exp(s*scale)*adj -> wave-private LDS ----
#pragma unroll
        for (int j = 0; j < 8; j++) {
            int col = kc + j * 16 + lm;
            bool cok = col < Mc;
#pragma unroll
            for (int r = 0; r < 4; r++) {
                float e = cok ? __expf(sacc[j][r] * scale) : 0.f;
                float p = e * adjv[j][r];
                Er[r] += e; Sr[r] += p;
                short hs, ls;
                bsplit(p, hs, ls);
                int cs = (j * 16 + lm) ^ (lq << 3);   // row>>2 == lq swizzle
                PH[w][lq * 4 + r][cs] = (ushort)hs;
                PL[w][lq * 4 + r][cs] = (ushort)ls;
            }
        }

        // ---------- round 2: V half0 ----------
        __syncthreads();
        WRITE_SB(RAh, RAl);
        ISSUE_V(RBh, RBl, kc, 1);
        __syncthreads();
        MFMA_PV(0);

        // ---------- round 3: V half1 ----------
        __syncthreads();
        WRITE_SB(RBh, RBl);
        if (c < 4) {
            ISSUE_K(RAh, RAl, kc + 128, 0);
        } else {
            // T14: issue WlinT epilogue staging loads; latency hides under
            // MFMA_PV(1) + row sums. RAh=WTH parts, RAl=WTL parts.
#pragma unroll
            for (int p = 0; p < 4; p++) {
                int e = t + p * 256;           // 0..1023
                int row = e >> 4, seg = (e & 15) << 3;
                RAh[p] = *(const short8*)(WTH + row * 128 + seg);
                RAl[p] = *(const short8*)(WTL + row * 128 + seg);
            }
        }
        __syncthreads();
        MFMA_PV(1);
    }

    // ---- row sums ----
#pragma unroll
    for (int mk = 1; mk <= 8; mk <<= 1)
#pragma unroll
        for (int r = 0; r < 4; r++) {
            Er[r] += __shfl_xor(Er[r], mk, 64);
            Sr[r] += __shfl_xor(Sr[r], mk, 64);
        }
    float inv[4];
#pragma unroll
    for (int r = 0; r < 4; r++) inv[r] = 1.f / (Sr[r] + 1e-8f * Er[r]);

    // ---- fused O @ Wlin: overlay LDS (SB/PH/PL dead) ----
    __syncthreads();                       // all waves done with SB/PH/PL
    uint*   OP  = (uint*)SMEM;             // [64][132] packed O (33.8 KB)
    ushort* BsF = SMEM + 16896;            // [2][64][136] WlinT (34.8 KB)

    // write pre-staged WlinT regs (loaded in last PV round)
#pragma unroll
    for (int p = 0; p < 4; p++) {
        int e = t + p * 256;               // 0..1023
        int row = e >> 4, seg = (e & 15) << 3;
        *(short8*)(BsF + row * 136 + seg) = RAh[p];
        *(short8*)(BsF + 64 * 136 + row * 136 + seg) = RAl[p];
    }
    // normalized O (packed bf16 hi|lo) -> OP, wave-private rows
#pragma unroll
    for (int j = 0; j < 8; j++)
#pragma unroll
        for (int r = 0; r < 4; r++) {
            int lrow = w * 16 + lq * 4 + r;
            float v = oacc[j][r] * inv[r];
            short hs, ls;
            bsplit(v, hs, ls);
            OP[lrow * 132 + j * 16 + lm] = ((uint)(ushort)ls << 16) | (uint)(ushort)hs;
        }
    __syncthreads();

    // block-local GEMM: each wave computes its 16 rows x 64 cols
    f32x4 cacc[4];
#pragma unroll
    for (int jj = 0; jj < 4; jj++)
#pragma unroll
        for (int r = 0; r < 4; r++) cacc[jj][r] = 0.f;

#pragma unroll
    for (int ks = 0; ks < 4; ks++) {
        short8 ah, al;
        {
            const uint* src = OP + (w * 16 + lm) * 132 + ks * 32 + lq * 8;
            const uint4 u0 = *(const uint4*)src;
            const uint4 u1 = *(const uint4*)(src + 4);
#pragma unroll
            for (int q = 0; q < 4; q++) {
                uint u = ((const uint*)&u0)[q];
                ah[q] = (short)(u & 0xffff); al[q] = (short)(u >> 16);
            }
#pragma unroll
            for (int q = 0; q < 4; q++) {
                uint u = ((const uint*)&u1)[q];
                ah[4 + q] = (short)(u & 0xffff); al[4 + q] = (short)(u >> 16);
            }
        }
#pragma unroll
        for (int jj = 0; jj < 4; jj++) {
            short8 bh = *(const short8*)(BsF + (jj * 16 + lm) * 136 + ks * 32 + lq * 8);
            short8 bl = *(const short8*)(BsF + 64 * 136 + (jj * 16 + lm) * 136 + ks * 32 + lq * 8);
            cacc[jj] = __builtin_amdgcn_mfma_f32_16x16x32_bf16(ah, bh, cacc[jj], 0, 0, 0);
            cacc[jj] = __builtin_amdgcn_mfma_f32_16x16x32_bf16(ah, bl, cacc[jj], 0, 0, 0);
            cacc[jj] = __builtin_amdgcn_mfma_f32_16x16x32_bf16(al, bh, cacc[jj], 0, 0, 0);
        }
    }

    // epilogue: bias + CUR write + fused middle-window running max
    float* CURz = CUR + (long)z * Mc * Cc;
#pragma unroll
    for (int jj = 0; jj < 4; jj++) {
        int col = jj * 16 + lm;
        float b = blin[col];
#pragma unroll
        for (int r = 0; r < 4; r++) {
            int row = m0 + w * 16 + lq * 4 + r;
            if (row < Mc) {
                float v = cacc[jj][r] + b;
                CURz[(long)row * Cc + col] = v;
                if (row >= 2 * Nc) {
                    long o = ((long)z * Nc + (row - 2 * Nc)) * Cc + col;
                    cand[o] = first ? v : fmaxf(cand[o], v);
                }
            }
        }
    }
}

#undef ISSUE_K
#undef ISSUE_V
#undef WRITE_SB
#undef MFMA_QK
#undef MFMA_PV

// ---------------- output layer ----------------
__global__ __launch_bounds__(128)
void output_k(const float* __restrict__ h2, const float* __restrict__ Wo,
              const float* __restrict__ bo, float* __restrict__ out)
{
    __shared__ float ds[512];
    int row = blockIdx.x;
    int b = row / Nc, n = row % Nc;
    int t = threadIdx.x;
    for (int e = t; e < 512; e += 128) {
        int tt = e >> 6, c = e & 63;
        ds[e] = h2[(((long)b * 8 + tt) * Nc + n) * Cc + c];
    }
    __syncthreads();
    float acc = bo[t];
    for (int e = 0; e < 512; e++) acc += ds[e] * Wo[e * OUTFc + t];
    acc = fmaxf(acc, 0.f);
    for (int p = 0; p < PREDc; p++)
        out[(((long)b * PREDc + p) * Nc + n) * (long)OUTFc + t] = acc;
}

extern "C" void kernel_launch(void* const* d_in, const int* in_sizes, int n_in,
                              void* d_out, int out_size, void* d_ws, size_t ws_size,
                              hipStream_t stream)
{
    (void)in_sizes; (void)n_in; (void)out_size; (void)ws_size;
    const float* x     = (const float*)d_in[0];
    const float* Wqkv  = (const float*)d_in[4];
    const float* bqkv  = (const float*)d_in[5];
    const float* Wlin  = (const float*)d_in[6];
    const float* blin  = (const float*)d_in[7];
    const float* Wa    = (const float*)d_in[8];
    const float* Wb    = (const float*)d_in[9];
    const float* temb0 = (const float*)d_in[13];
    const float* temb1 = (const float*)d_in[14];
    const float* semb  = (const float*)d_in[15];
    const float* Wo    = (const float*)d_in[16];
    const float* bo    = (const float*)d_in[17];
    float* out = (float*)d_out;

    // ---- workspace (float offsets, layout unchanged; OB slot unused) ------
    float* ws   = (float*)d_ws;
    float* CUR  = ws;                                  // 1,536,000
    float* ADJ  = CUR + (long)MAXBW * Mc * Cc;         // 360,000
    float* CAND = ADJ + (long)Mc * Mc;                 // 512,000
    uint*  OB   = (uint*)(CAND + (long)MAXBW * Nc * Cc); // unused
    float* QHf  = (float*)(OB + (long)MAXBW * Mc * ATTc);
    const long QSZ = (long)MAXBW * Mc * ATTc / 2;      // in floats
    float* QLf  = QHf + QSZ;
    float* KHf  = QLf + QSZ;
    float* KLf  = KHf + QSZ;
    float* VTHf = KLf + QSZ;
    float* VTLf = VTHf + (long)MAXBW * ATTc * MPAD / 2;
    ushort* NAH = (ushort*)(VTLf + (long)MAXBW * ATTc * MPAD / 2);
    ushort* NAL = NAH + Mc * Cc;
    ushort* NBH = NAL + Mc * Cc;
    ushort* NBL = NBH + Mc * Cc;
    ushort* WTH = NBL + Mc * Cc;                       // 64*128 each
    ushort* WTL = WTH + 64 * 128;
    ushort* WQH = WTL + 64 * 128;                      // 384*64 each
    ushort* WQL = WQH + 384 * 64;

    ushort* QH  = (ushort*)QHf;
    ushort* QL  = (ushort*)QLf;
    ushort* KH  = (ushort*)KHf;
    ushort* KL  = (ushort*)KLf;
    ushort* VTH = (ushort*)VTHf;
    ushort* VTL = (ushort*)VTLf;

    const float inv_sqrt_att = 0.08838834764831845f;   // 1/sqrt(128)

    // one-shot weight prep (both transposed bf16 hi/lo splits)
    prep_k<<<dim3(128), dim3(256), 0, stream>>>(Wlin, WTH, WTL, Wqkv, WQH, WQL);

    for (int layer = 0; layer < 2; layer++) {
        int Tin = layer ? 10 : 12;
        int nw  = Tin - 2;
        int BW  = Bc * nw;                             // 40 then 32
        const float* src  = layer ? CAND : x;
        const float* temb = layer ? temb1 : temb0;

        long etotal = (long)BW * Mc * Cc;
        embed_window_k<<<dim3((unsigned)((etotal + 255) / 256)), dim3(256), 0, stream>>>(
            src, temb, semb, CUR, Tin, nw, etotal);

        for (int it = 0; it < 3; it++) {
            // node-mean -> NA/NB (R23: 150-block layout)
            mean_nab_k<<<dim3(150), dim3(256), 0, stream>>>(
                CUR, Wa, Wb, NAH, NAL, NBH, NBL, BW);

            // merged: QKV projection + adjacency MM (25 tail blocks)
            int nqkv = BW * 15;
            qkv_adj_k<<<dim3(nqkv + 25), dim3(256), 0, stream>>>(
                CUR, WQH, WQL, bqkv, QH, QL, KH, KL, VTH, VTL,
                NAH, NAL, NBH, NBL, ADJ, nqkv);

            // fused attention + O@Wlin + cand-max (R22 + T14 stage)
            attn_k<<<dim3(BW * 10), dim3(256), 0, stream>>>(
                QH, QL, KH, KL, VTH, VTL, ADJ, WTH, WTL, blin,
                CUR, CAND, it == 0 ? 1 : 0, inv_sqrt_att);
        }
    }
    output_k<<<dim3(Bc * Nc), dim3(128), 0, stream>>>(CAND, Wo, bo, out);
}

// Round 11
// 622.556 us; speedup vs baseline: 1.4109x; 1.0138x over previous
//
#include <hip/hip_runtime.h>
#include <hip/hip_bf16.h>
#include <math.h>

constexpr int Bc   = 4;
constexpr int Nc   = 200;
constexpr int Cc   = 64;
constexpr int Mc   = 600;    // 3*N
constexpr int ATTc = 128;
constexpr int OUTFc = 128;
constexpr int PREDc = 12;
constexpr int MAXBW = 40;
constexpr int MPAD  = 640;   // padded V^T leading dim

typedef short short4v __attribute__((ext_vector_type(4)));
typedef short short8 __attribute__((ext_vector_type(8)));
typedef float f32x4  __attribute__((ext_vector_type(4)));

static __device__ __forceinline__ void bsplit(float v, short& h, short& l) {
    __hip_bfloat16 hb = __float2bfloat16(v);
    float hf = __bfloat162float(hb);
    __hip_bfloat16 lb = __float2bfloat16(v - hf);
    h = *(short*)&hb; l = *(short*)&lb;
}

// ---------------- embed + sliding window ----------------
__global__ __launch_bounds__(256)
void embed_window_k(const float* __restrict__ src, const float* __restrict__ temb,
                    const float* __restrict__ semb, float* __restrict__ dst,
                    int Tin, int nw, long total)
{
    long idx = (long)blockIdx.x * 256 + threadIdx.x;
    if (idx >= total) return;
    int c = (int)(idx & 63);
    long r = idx >> 6;
    int n = (int)(r % Nc); r /= Nc;
    int j = (int)(r % 3);  r /= 3;
    int w = (int)(r % nw);
    int b = (int)(r / nw);
    int t = w + j;
    dst[idx] = src[(((long)b * Tin + t) * Nc + n) * Cc + c]
             + temb[t * Cc + c] + semb[n * Cc + c];
}

// ------- fused node-mean + NA/NB projection (R23 layout, R24: exact inv) ---
__global__ __launch_bounds__(256)
void mean_nab_k(const float* __restrict__ cur, const float* __restrict__ Wa,
                const float* __restrict__ Wb,
                ushort* __restrict__ NAH, ushort* __restrict__ NAL,
                ushort* __restrict__ NBH, ushort* __restrict__ NBL, int BW)
{
    __shared__ float Ns[4][64];    // [row][k] mean
    __shared__ float Ws[64][132];  // [k][ Wa | Wb ]
    const int m0 = blockIdx.x * 4;
    const int t = threadIdx.x;
    for (int e = t; e < 1024; e += 256) {
        int r = e >> 4, c4 = (e & 15) << 2;
        *(float4*)&Ws[r][c4]      = *(const float4*)&Wa[r * 64 + c4];
        *(float4*)&Ws[r][64 + c4] = *(const float4*)&Wb[r * 64 + c4];
    }
    {
        int row = t >> 6, c = t & 63;      // 4 rows x 64 channels
        int gm = m0 + row;
        float sv = 0.f;
        for (int bw = 0; bw < BW; bw++)
            sv += cur[((long)bw * Mc + gm) * Cc + c];
        const float inv = 1.f / BW;        // R24: multiply (exact R14 rounding)
        Ns[row][c] = sv * inv;
    }
    __syncthreads();
#pragma unroll
    for (int o = 0; o < 2; o++) {
        int e = t + o * 256;               // 0..511
        int row = e >> 7, col = e & 127;
        float acc = 0.f;
        for (int k = 0; k < 64; k++)
            acc += Ns[row][k] * Ws[k][col];
        int gm = m0 + row;
        short h, l;
        bsplit(acc, h, l);
        if (col < 64) { NAH[gm * 64 + col] = (ushort)h; NAL[gm * 64 + col] = (ushort)l; }
        else { NBH[gm * 64 + col - 64] = (ushort)h; NBL[gm * 64 + col - 64] = (ushort)l; }
    }
}

// ---------------- combined one-shot weight prep ----------------------------
__global__ __launch_bounds__(256)
void prep_k(const float* __restrict__ Wlin,
            ushort* __restrict__ WTH, ushort* __restrict__ WTL,
            const float* __restrict__ Wqkv,
            ushort* __restrict__ WQH, ushort* __restrict__ WQL)
{
    int i = blockIdx.x * 256 + threadIdx.x;
    if (i < 64 * 128) {
        int c = i >> 7, a = i & 127;
        short h, l;
        bsplit(Wlin[a * 64 + c], h, l);
        WTH[c * 128 + a] = (ushort)h;
        WTL[c * 128 + a] = (ushort)l;
    } else {
        int j = i - 64 * 128;
        if (j < 384 * 64) {
            int n = j >> 6, c = j & 63;
            short h, l;
            bsplit(Wqkv[c * 384 + n], h, l);
            WQH[n * 64 + c] = (ushort)h;
            WQL[n * 64 + c] = (ushort)l;
        }
    }
}

// ---- merged QKV projection + adjacency MM (R19-proven) --------------------
__global__ __launch_bounds__(256)
void qkv_adj_k(const float* __restrict__ CURp,
               const ushort* __restrict__ WQH, const ushort* __restrict__ WQL,
               const float* __restrict__ bias,
               ushort* __restrict__ QH, ushort* __restrict__ QL,
               ushort* __restrict__ KH, ushort* __restrict__ KL,
               ushort* __restrict__ VTH, ushort* __restrict__ VTL,
               const ushort* __restrict__ Ah, const ushort* __restrict__ Al,
               const ushort* __restrict__ Bh, const ushort* __restrict__ Bl,
               float* __restrict__ ADJ, int nqkv)
{
    __shared__ __align__(16) ushort SM[36864];   // 72 KB, multi-purpose
    const int t = threadIdx.x;
    const int lane = t & 63, w = t >> 6;
    const int lm = lane & 15, lq = lane >> 4;

    if ((int)blockIdx.x >= nqkv) {
        // ================= adjmm body =================
        const int b2 = blockIdx.x - nqkv;
        const int m0 = (b2 / 5) * 128, n0 = (b2 % 5) * 128;
        ushort (*As)[128][40] = (ushort (*)[128][40])(SM);          // 20 KB
        ushort (*Bs)[128][40] = (ushort (*)[128][40])(SM + 10240);  // 20 KB
        const int wm = (w >> 1) * 64, wn = (w & 1) * 64;

        f32x4 acc[4][4];
#pragma unroll
        for (int i = 0; i < 4; i++)
#pragma unroll
            for (int j = 0; j < 4; j++)
#pragma unroll
                for (int r = 0; r < 4; r++) acc[i][j][r] = 0.f;

        for (int k0 = 0; k0 < 64; k0 += 32) {
            __syncthreads();
#pragma unroll
            for (int p = 0; p < 2; p++) {
                int e = t + p * 256;
                int row = e >> 2, ks = (e & 3) << 3;
                {
                    int gm = m0 + row;
                    short8 vh, vl;
#pragma unroll
                    for (int q = 0; q < 8; q++) { vh[q] = 0; vl[q] = 0; }
                    if (gm < Mc) {
                        vh = *(const short8*)(Ah + (long)gm * 64 + k0 + ks);
                        vl = *(const short8*)(Al + (long)gm * 64 + k0 + ks);
                    }
                    *(short8*)&As[0][row][ks] = vh;
                    *(short8*)&As[1][row][ks] = vl;
                }
                {
                    int gn = n0 + row;
                    short8 vh, vl;
#pragma unroll
                    for (int q = 0; q < 8; q++) { vh[q] = 0; vl[q] = 0; }
                    if (gn < Mc) {
                        vh = *(const short8*)(Bh + (long)gn * 64 + k0 + ks);
                        vl = *(const short8*)(Bl + (long)gn * 64 + k0 + ks);
                    }
                    *(short8*)&Bs[0][row][ks] = vh;
                    *(short8*)&Bs[1][row][ks] = vl;
                }
            }
            __syncthreads();

            short8 af[4][2], bf[4][2];
#pragma unroll
            for (int i = 0; i < 4; i++) {
                af[i][0] = *(const short8*)&As[0][wm + i * 16 + lm][lq * 8];
                af[i][1] = *(const short8*)&As[1][wm + i * 16 + lm][lq * 8];
            }
#pragma unroll
            for (int j = 0; j < 4; j++) {
                bf[j][0] = *(const short8*)&Bs[0][wn + j * 16 + lm][lq * 8];
                bf[j][1] = *(const short8*)&Bs[1][wn + j * 16 + lm][lq * 8];
            }
#pragma unroll
            for (int i = 0; i < 4; i++)
#pragma unroll
                for (int j = 0; j < 4; j++) {
                    acc[i][j] = __builtin_amdgcn_mfma_f32_16x16x32_bf16(af[i][0], bf[j][0], acc[i][j], 0, 0, 0);
                    acc[i][j] = __builtin_amdgcn_mfma_f32_16x16x32_bf16(af[i][0], bf[j][1], acc[i][j], 0, 0, 0);
                    acc[i][j] = __builtin_amdgcn_mfma_f32_16x16x32_bf16(af[i][1], bf[j][0], acc[i][j], 0, 0, 0);
                }
        }
#pragma unroll
        for (int i = 0; i < 4; i++) {
            int gmb = m0 + wm + i * 16 + lq * 4;
#pragma unroll
            for (int j = 0; j < 4; j++) {
                int gn = n0 + wn + j * 16 + lm;
                if (gn >= Mc) continue;
#pragma unroll
                for (int r = 0; r < 4; r++) {
                    int gm = gmb + r;
                    if (gm < Mc)
                        ADJ[(long)gm * Mc + gn] = 1.f / (1.f + __expf(-acc[i][j][r] * 0.125f));
                }
            }
        }
        return;
    }

    // ================= qkv body (R14-proven) =================
    ushort* AsH = SM;                 // [128][72]
    ushort* AsL = SM + 9216;
    ushort* BsH = SM + 18432;
    ushort* BsL = SM + 27648;
    const int bid = blockIdx.x;
    const int xcd = bid & 7, slot = bid >> 3;
    const int z = (slot / 15) * 8 + xcd;
    const int r15 = slot % 15;
    const int which = r15 % 3;             // 0=q 1=k 2=v
    const int m0 = (r15 / 3) * 128;
    const int nb = which * 128;
    const float* A = CURp + (long)z * Mc * Cc;
    const int wm = (w >> 1) * 64, wn = (w & 1) * 64;

#pragma unroll
    for (int p = 0; p < 8; p++) {
        int e = t + p * 256;              // 0..2047
        int row = e >> 4, k4 = (e & 15) * 4;
        int gm = m0 + row;
        float4 v = make_float4(0.f, 0.f, 0.f, 0.f);
        if (gm < Mc) v = *(const float4*)(A + (long)gm * 64 + k4);
        short4v h4, l4;
        short hs, ls;
        bsplit(v.x, hs, ls); h4[0] = hs; l4[0] = ls;
        bsplit(v.y, hs, ls); h4[1] = hs; l4[1] = ls;
        bsplit(v.z, hs, ls); h4[2] = hs; l4[2] = ls;
        bsplit(v.w, hs, ls); h4[3] = hs; l4[3] = ls;
        *(short4v*)(AsH + row * 72 + k4) = h4;
        *(short4v*)(AsL + row * 72 + k4) = l4;
    }
#pragma unroll
    for (int p = 0; p < 4; p++) {
        int e = t + p * 256;              // 0..1023
        int row = e >> 3, seg = (e & 7) * 8;
        *(short8*)(BsH + row * 72 + seg) = *(const short8*)(WQH + (long)(nb + row) * 64 + seg);
        *(short8*)(BsL + row * 72 + seg) = *(const short8*)(WQL + (long)(nb + row) * 64 + seg);
    }
    __syncthreads();

    f32x4 acc[4][4];
#pragma unroll
    for (int i = 0; i < 4; i++)
#pragma unroll
        for (int j = 0; j < 4; j++)
#pragma unroll
            for (int r = 0; r < 4; r++) acc[i][j][r] = 0.f;

#pragma unroll
    for (int ks = 0; ks < 2; ks++) {
        short8 af[4][2], bf[4][2];
#pragma unroll
        for (int i = 0; i < 4; i++) {
            af[i][0] = *(const short8*)(AsH + (wm + i * 16 + lm) * 72 + ks * 32 + lq * 8);
            af[i][1] = *(const short8*)(AsL + (wm + i * 16 + lm) * 72 + ks * 32 + lq * 8);
        }
#pragma unroll
        for (int j = 0; j < 4; j++) {
            bf[j][0] = *(const short8*)(BsH + (wn + j * 16 + lm) * 72 + ks * 32 + lq * 8);
            bf[j][1] = *(const short8*)(BsL + (wn + j * 16 + lm) * 72 + ks * 32 + lq * 8);
        }
#pragma unroll
        for (int i = 0; i < 4; i++)
#pragma unroll
            for (int j = 0; j < 4; j++) {
                acc[i][j] = __builtin_amdgcn_mfma_f32_16x16x32_bf16(af[i][0], bf[j][0], acc[i][j], 0, 0, 0);
                acc[i][j] = __builtin_amdgcn_mfma_f32_16x16x32_bf16(af[i][0], bf[j][1], acc[i][j], 0, 0, 0);
                acc[i][j] = __builtin_amdgcn_mfma_f32_16x16x32_bf16(af[i][1], bf[j][0], acc[i][j], 0, 0, 0);
            }
    }
    __syncthreads();   // frags consumed; SM reused as C scratch

    uint* CP = (uint*)SM;                 // [128][132] uints
#pragma unroll
    for (int i = 0; i < 4; i++)
#pragma unroll
        for (int j = 0; j < 4; j++) {
            int col = wn + j * 16 + lm;
            float b = bias[nb + col];
#pragma unroll
            for (int r = 0; r < 4; r++) {
                int row = wm + i * 16 + lq * 4 + r;
                float v = acc[i][j][r] + b;
                if (which == 2) v = fmaxf(v, 0.f);
                short hs, ls;
                bsplit(v, hs, ls);
                CP[row * 132 + col] = ((uint)(ushort)ls << 16) | (uint)(ushort)hs;
            }
        }
    __syncthreads();

    if (which == 2) {
        ushort* vh = VTH + (long)z * ATTc * MPAD;
        ushort* vl = VTL + (long)z * ATTc * MPAD;
#pragma unroll
        for (int p = 0; p < 8; p++) {
            int e = t + p * 256;          // 0..2047
            int col = e >> 4, rg = (e & 15) * 8;
            if (m0 + rg < Mc) {
                short8 h8, l8;
#pragma unroll
                for (int q = 0; q < 8; q++) {
                    uint u = CP[(rg + q) * 132 + col];
                    h8[q] = (short)(u & 0xffff);
                    l8[q] = (short)(u >> 16);
                }
                *(short8*)(vh + (long)col * MPAD + m0 + rg) = h8;
                *(short8*)(vl + (long)col * MPAD + m0 + rg) = l8;
            }
        }
    } else {
        ushort* dh = (which == 0 ? QH : KH) + (long)z * Mc * ATTc;
        ushort* dl = (which == 0 ? QL : KL) + (long)z * Mc * ATTc;
#pragma unroll
        for (int p = 0; p < 8; p++) {
            int e = t + p * 256;
            int row = e >> 4, seg = (e & 15) * 8;
            int gm = m0 + row;
            if (gm < Mc) {
                short8 h8, l8;
#pragma unroll
                for (int q = 0; q < 8; q++) {
                    uint u = CP[row * 132 + seg + q];
                    h8[q] = (short)(u & 0xffff);
                    l8[q] = (short)(u >> 16);
                }
                *(short8*)(dh + (long)gm * ATTc + seg) = h8;
                *(short8*)(dl + (long)gm * ATTc + seg) = l8;
            }
        }
    }
}

// ---- fused attention + Wlin (R22/R23-proven; R24: setprio around MFMA) ----
#define ISSUE_K(Dh, Dl, kc_, g_)                                        \
  _Pragma("unroll")                                                     \
  for (int p = 0; p < 4; p++) {                                         \
    int key = (kc_) + srow0 + 32 * p;                                   \
    short8 vh, vl;                                                      \
    _Pragma("unroll")                                                   \
    for (int q2 = 0; q2 < 8; q2++) { vh[q2] = 0; vl[q2] = 0; }          \
    if (key < Mc) {                                                     \
      vh = *(const short8*)(Khz + (long)key * ATTc + (g_) * 64 + sks);  \
      vl = *(const short8*)(Klz + (long)key * ATTc + (g_) * 64 + sks);  \
    }                                                                   \
    Dh[p] = vh; Dl[p] = vl;                                             \
  }

#define ISSUE_V(Dh, Dl, kc_, g_)                                                   \
  _Pragma("unroll")                                                                \
  for (int p = 0; p < 4; p++) {                                                    \
    int att = srow0 + 32 * p;                                                      \
    Dh[p] = *(const short8*)(Vhz + (long)att * MPAD + (kc_) + (g_) * 64 + sks);    \
    Dl[p] = *(const short8*)(Vlz + (long)att * MPAD + (kc_) + (g_) * 64 + sks);    \
  }

#define WRITE_SB(Dh, Dl)                                                \
  _Pragma("unroll")                                                     \
  for (int p = 0; p < 4; p++) {                                         \
    *(short8*)&SB[0][srow0 + 32 * p][sks] = Dh[p];                      \
    *(short8*)&SB[1][srow0 + 32 * p][sks] = Dl[p];                      \
  }

#define MFMA_QK(base_)                                                   \
  __builtin_amdgcn_s_setprio(1);                                         \
  _Pragma("unroll")                                                      \
  for (int kk = 0; kk < 2; kk++) {                                       \
    _Pragma("unroll")                                                    \
    for (int j = 0; j < 8; j++) {                                        \
      short8 bh = *(const short8*)&SB[0][j * 16 + lm][kk * 32 + lq * 8]; \
      short8 bl = *(const short8*)&SB[1][j * 16 + lm][kk * 32 + lq * 8]; \
      sacc[j] = __builtin_amdgcn_mfma_f32_16x16x32_bf16(qh[(base_) + kk], bh, sacc[j], 0, 0, 0); \
      sacc[j] = __builtin_amdgcn_mfma_f32_16x16x32_bf16(qh[(base_) + kk], bl, sacc[j], 0, 0, 0); \
      sacc[j] = __builtin_amdgcn_mfma_f32_16x16x32_bf16(ql[(base_) + kk], bh, sacc[j], 0, 0, 0); \
    }                                                                    \
  }                                                                      \
  __builtin_amdgcn_s_setprio(0);

#define MFMA_PV(g_)                                                      \
  __builtin_amdgcn_s_setprio(1);                                         \
  _Pragma("unroll")                                                      \
  for (int kk = 0; kk < 2; kk++) {                                       \
    int po = ((g_) * 64 + kk * 32 + lq * 8) ^ ((lm >> 2) << 3);          \
    short8 ph = *(const short8*)&PH[w][lm][po];                          \
    short8 pl = *(const short8*)&PL[w][lm][po];                          \
    _Pragma("unroll")                                                    \
    for (int j = 0; j < 8; j++) {                                        \
      short8 vh = *(const short8*)&SB[0][j * 16 + lm][kk * 32 + lq * 8]; \
      short8 vl = *(const short8*)&SB[1][j * 16 + lm][kk * 32 + lq * 8]; \
      oacc[j] = __builtin_amdgcn_mfma_f32_16x16x32_bf16(ph, vh, oacc[j], 0, 0, 0); \
      oacc[j] = __builtin_amdgcn_mfma_f32_16x16x32_bf16(ph, vl, oacc[j], 0, 0, 0); \
      oacc[j] = __builtin_amdgcn_mfma_f32_16x16x32_bf16(pl, vh, oacc[j], 0, 0, 0); \
    }                                                                    \
  }                                                                      \
  __builtin_amdgcn_s_setprio(0);

__global__ __launch_bounds__(256, 2)
void attn_k(const ushort* __restrict__ QH, const ushort* __restrict__ QL,
            const ushort* __restrict__ KH, const ushort* __restrict__ KL,
            const ushort* __restrict__ VTH, const ushort* __restrict__ VTL,
            const float* __restrict__ adj,
            const ushort* __restrict__ WTH, const ushort* __restrict__ WTL,
            const float* __restrict__ blin,
            float* __restrict__ CUR, float* __restrict__ cand, int first,
            float scale)
{
    __shared__ __align__(16) ushort SMEM[37888];      // 75,776 B
    typedef ushort sb_t[128][72];
    typedef ushort ph_t[16][152];
    sb_t* SB = (sb_t*)SMEM;                           // [2][128][72]
    ph_t* PH = (ph_t*)(SMEM + 18432);                 // [4][16][152]
    ph_t* PL = (ph_t*)(SMEM + 28160);                 // [4][16][152]
    const int bid = blockIdx.x;
    const int xcd = bid & 7, slot = bid >> 3;
    const int z = (slot / 10) * 8 + xcd;
    const int m0 = (slot % 10) * 64;
    const int t = threadIdx.x;
    const int lane = t & 63, w = t >> 6;
    const int lm = lane & 15, lq = lane >> 4;
    const int qrow0 = m0 + w * 16;
    const int srow0 = t >> 3;          // staging row base 0..31
    const int sks   = (t & 7) << 3;    // staging col 0..56 (x8 shorts)

    const ushort* Qhz = QH + (long)z * Mc * ATTc;
    const ushort* Qlz = QL + (long)z * Mc * ATTc;
    const ushort* Khz = KH + (long)z * Mc * ATTc;
    const ushort* Klz = KL + (long)z * Mc * ATTc;
    const ushort* Vhz = VTH + (long)z * ATTc * MPAD;
    const ushort* Vlz = VTL + (long)z * ATTc * MPAD;

    // ---- prefetch round 0 (chunk 0, K half0) ----
    short8 RAh[4], RAl[4], RBh[4], RBl[4];
    ISSUE_K(RAh, RAl, 0, 0);

    // ---- Q fragments ----
    short8 qh[4], ql[4];
    {
        int qr = qrow0 + lm;
        if (qr < Mc) {
            const ushort* qp = Qhz + (long)qr * ATTc;
            const ushort* qp2 = Qlz + (long)qr * ATTc;
#pragma unroll
            for (int ks = 0; ks < 4; ks++) {
                qh[ks] = *(const short8*)(qp + ks * 32 + lq * 8);
                ql[ks] = *(const short8*)(qp2 + ks * 32 + lq * 8);
            }
        } else {
#pragma unroll
            for (int ks = 0; ks < 4; ks++)
#pragma unroll
                for (int q = 0; q < 8; q++) { qh[ks][q] = 0; ql[ks][q] = 0; }
        }
    }

    f32x4 oacc[8];
#pragma unroll
    for (int j = 0; j < 8; j++)
#pragma unroll
        for (int r = 0; r < 4; r++) oacc[j][r] = 0.f;
    float Er[4] = {}, Sr[4] = {};
    float adjv[8][4];

    for (int c = 0; c < 5; c++) {
        const int kc = c * 128;
        f32x4 sacc[8];
#pragma unroll
        for (int j = 0; j < 8; j++)
#pragma unroll
            for (int r = 0; r < 4; r++) sacc[j][r] = 0.f;

        // ---------- round 0: K half0 ----------
        __syncthreads();
        WRITE_SB(RAh, RAl);
        ISSUE_K(RBh, RBl, kc, 1);
        // prefetch this chunk's adj block into regs (consumed 2 phases later)
#pragma unroll
        for (int j = 0; j < 8; j++) {
            int col = kc + j * 16 + lm;
#pragma unroll
            for (int r = 0; r < 4; r++) {
                int row = qrow0 + lq * 4 + r;
                adjv[j][r] = (col < Mc && row < Mc) ? adj[(long)row * Mc + col] : 0.f;
            }
        }
        __syncthreads();
        MFMA_QK(0);

        // ---------- round 1: K half1 ----------
        __syncthreads();
        WRITE_SB(RBh, RBl);
        ISSUE_V(RAh, RAl, kc, 0);
        __syncthreads();
        MFMA_QK(2);

        // ---------- epilogue: P = exp(s*scale)*adj -> wave-private LDS ----
#pragma unroll
        for (int j = 0; j < 8; j++) {
            int col = kc + j * 16 + lm;
            bool cok = col < Mc;
#pragma unroll
            for (int r = 0; r < 4; r++) {
                float e = cok ? __expf(sacc[j][r] * scale) : 0.f;
                float p = e * adjv[j][r];
                Er[r] += e; Sr[r] += p;
                short hs, ls;
                bsplit(p, hs, ls);
                int cs = (j * 16 + lm) ^ (lq << 3);   // row>>2 == lq swizzle
                PH[w][lq * 4 + r][cs] = (ushort)hs;
                PL[w][lq * 4 + r][cs] = (ushort)ls;
            }
        }

        // ---------- round 2: V half0 ----------
        __syncthreads();
        WRITE_SB(RAh, RAl);
        ISSUE_V(RBh, RBl, kc, 1);
        __syncthreads();
        MFMA_PV(0);

        // ---------- round 3: V half1 ----------
        __syncthreads();
        WRITE_SB(RBh, RBl);
        if (c < 4) {
            ISSUE_K(RAh, RAl, kc + 128, 0);
        } else {
            // T14: issue WlinT epilogue staging loads; latency hides under
            // MFMA_PV(1) + row sums. RAh=WTH parts, RAl=WTL parts.
#pragma unroll
            for (int p = 0; p < 4; p++) {
                int e = t + p * 256;           // 0..1023
                int row = e >> 4, seg = (e & 15) << 3;
                RAh[p] = *(const short8*)(WTH + row * 128 + seg);
                RAl[p] = *(const short8*)(WTL + row * 128 + seg);
            }
        }
        __syncthreads();
        MFMA_PV(1);
    }

    // ---- row sums ----
#pragma unroll
    for (int mk = 1; mk <= 8; mk <<= 1)
#pragma unroll
        for (int r = 0; r < 4; r++) {
            Er[r] += __shfl_xor(Er[r], mk, 64);
            Sr[r] += __shfl_xor(Sr[r], mk, 64);
        }
    float inv[4];
#pragma unroll
    for (int r = 0; r < 4; r++) inv[r] = 1.f / (Sr[r] + 1e-8f * Er[r]);

    // ---- fused O @ Wlin: overlay LDS (SB/PH/PL dead) ----
    __syncthreads();                       // all waves done with SB/PH/PL
    uint*   OP  = (uint*)SMEM;             // [64][132] packed O (33.8 KB)
    ushort* BsF = SMEM + 16896;            // [2][64][136] WlinT (34.8 KB)

    // write pre-staged WlinT regs (loaded in last PV round)
#pragma unroll
    for (int p = 0; p < 4; p++) {
        int e = t + p * 256;               // 0..1023
        int row = e >> 4, seg = (e & 15) << 3;
        *(short8*)(BsF + row * 136 + seg) = RAh[p];
        *(short8*)(BsF + 64 * 136 + row * 136 + seg) = RAl[p];
    }
    // normalized O (packed bf16 hi|lo) -> OP, wave-private rows
#pragma unroll
    for (int j = 0; j < 8; j++)
#pragma unroll
        for (int r = 0; r < 4; r++) {
            int lrow = w * 16 + lq * 4 + r;
            float v = oacc[j][r] * inv[r];
            short hs, ls;
            bsplit(v, hs, ls);
            OP[lrow * 132 + j * 16 + lm] = ((uint)(ushort)ls << 16) | (uint)(ushort)hs;
        }
    __syncthreads();

    // block-local GEMM: each wave computes its 16 rows x 64 cols
    f32x4 cacc[4];
#pragma unroll
    for (int jj = 0; jj < 4; jj++)
#pragma unroll
        for (int r = 0; r < 4; r++) cacc[jj][r] = 0.f;

#pragma unroll
    for (int ks = 0; ks < 4; ks++) {
        short8 ah, al;
        {
            const uint* src = OP + (w * 16 + lm) * 132 + ks * 32 + lq * 8;
            const uint4 u0 = *(const uint4*)src;
            const uint4 u1 = *(const uint4*)(src + 4);
#pragma unroll
            for (int q = 0; q < 4; q++) {
                uint u = ((const uint*)&u0)[q];
                ah[q] = (short)(u & 0xffff); al[q] = (short)(u >> 16);
            }
#pragma unroll
            for (int q = 0; q < 4; q++) {
                uint u = ((const uint*)&u1)[q];
                ah[4 + q] = (short)(u & 0xffff); al[4 + q] = (short)(u >> 16);
            }
        }
#pragma unroll
        for (int jj = 0; jj < 4; jj++) {
            short8 bh = *(const short8*)(BsF + (jj * 16 + lm) * 136 + ks * 32 + lq * 8);
            short8 bl = *(const short8*)(BsF + 64 * 136 + (jj * 16 + lm) * 136 + ks * 32 + lq * 8);
            cacc[jj] = __builtin_amdgcn_mfma_f32_16x16x32_bf16(ah, bh, cacc[jj], 0, 0, 0);
            cacc[jj] = __builtin_amdgcn_mfma_f32_16x16x32_bf16(ah, bl, cacc[jj], 0, 0, 0);
            cacc[jj] = __builtin_amdgcn_mfma_f32_16x16x32_bf16(al, bh, cacc[jj], 0, 0, 0);
        }
    }

    // epilogue: bias + CUR write + fused middle-window running max
    float* CURz = CUR + (long)z * Mc * Cc;
#pragma unroll
    for (int jj = 0; jj < 4; jj++) {
        int col = jj * 16 + lm;
        float b = blin[col];
#pragma unroll
        for (int r = 0; r < 4; r++) {
            int row = m0 + w * 16 + lq * 4 + r;
            if (row < Mc) {
                float v = cacc[jj][r] + b;
                CURz[(long)row * Cc + col] = v;
                if (row >= 2 * Nc) {
                    long o = ((long)z * Nc + (row - 2 * Nc)) * Cc + col;
                    cand[o] = first ? v : fmaxf(cand[o], v);
                }
            }
        }
    }
}

#undef ISSUE_K
#undef ISSUE_V
#undef WRITE_SB
#undef MFMA_QK
#undef MFMA_PV

// ---------------- output layer ----------------
__global__ __launch_bounds__(128)
void output_k(const float* __restrict__ h2, const float* __restrict__ Wo,
              const float* __restrict__ bo, float* __restrict__ out)
{
    __shared__ float ds[512];
    int row = blockIdx.x;
    int b = row / Nc, n = row % Nc;
    int t = threadIdx.x;
    for (int e = t; e < 512; e += 128) {
        int tt = e >> 6, c = e & 63;
        ds[e] = h2[(((long)b * 8 + tt) * Nc + n) * Cc + c];
    }
    __syncthreads();
    float acc = bo[t];
    for (int e = 0; e < 512; e++) acc += ds[e] * Wo[e * OUTFc + t];
    acc = fmaxf(acc, 0.f);
    for (int p = 0; p < PREDc; p++)
        out[(((long)b * PREDc + p) * Nc + n) * (long)OUTFc + t] = acc;
}

extern "C" void kernel_launch(void* const* d_in, const int* in_sizes, int n_in,
                              void* d_out, int out_size, void* d_ws, size_t ws_size,
                              hipStream_t stream)
{
    (void)in_sizes; (void)n_in; (void)out_size; (void)ws_size;
    const float* x     = (const float*)d_in[0];
    const float* Wqkv  = (const float*)d_in[4];
    const float* bqkv  = (const float*)d_in[5];
    const float* Wlin  = (const float*)d_in[6];
    const float* blin  = (const float*)d_in[7];
    const float* Wa    = (const float*)d_in[8];
    const float* Wb    = (const float*)d_in[9];
    const float* temb0 = (const float*)d_in[13];
    const float* temb1 = (const float*)d_in[14];
    const float* semb  = (const float*)d_in[15];
    const float* Wo    = (const float*)d_in[16];
    const float* bo    = (const float*)d_in[17];
    float* out = (float*)d_out;

    // ---- workspace (float offsets, layout unchanged; OB slot unused) ------
    float* ws   = (float*)d_ws;
    float* CUR  = ws;                                  // 1,536,000
    float* ADJ  = CUR + (long)MAXBW * Mc * Cc;         // 360,000
    float* CAND = ADJ + (long)Mc * Mc;                 // 512,000
    uint*  OB   = (uint*)(CAND + (long)MAXBW * Nc * Cc); // unused
    float* QHf  = (float*)(OB + (long)MAXBW * Mc * ATTc);
    const long QSZ = (long)MAXBW * Mc * ATTc / 2;      // in floats
    float* QLf  = QHf + QSZ;
    float* KHf  = QLf + QSZ;
    float* KLf  = KHf + QSZ;
    float* VTHf = KLf + QSZ;
    float* VTLf = VTHf + (long)MAXBW * ATTc * MPAD / 2;
    ushort* NAH = (ushort*)(VTLf + (long)MAXBW * ATTc * MPAD / 2);
    ushort* NAL = NAH + Mc * Cc;
    ushort* NBH = NAL + Mc * Cc;
    ushort* NBL = NBH + Mc * Cc;
    ushort* WTH = NBL + Mc * Cc;                       // 64*128 each
    ushort* WTL = WTH + 64 * 128;
    ushort* WQH = WTL + 64 * 128;                      // 384*64 each
    ushort* WQL = WQH + 384 * 64;

    ushort* QH  = (ushort*)QHf;
    ushort* QL  = (ushort*)QLf;
    ushort* KH  = (ushort*)KHf;
    ushort* KL  = (ushort*)KLf;
    ushort* VTH = (ushort*)VTHf;
    ushort* VTL = (ushort*)VTLf;

    const float inv_sqrt_att = 0.08838834764831845f;   // 1/sqrt(128)

    // one-shot weight prep (both transposed bf16 hi/lo splits)
    prep_k<<<dim3(128), dim3(256), 0, stream>>>(Wlin, WTH, WTL, Wqkv, WQH, WQL);

    for (int layer = 0; layer < 2; layer++) {
        int Tin = layer ? 10 : 12;
        int nw  = Tin - 2;
        int BW  = Bc * nw;                             // 40 then 32
        const float* src  = layer ? CAND : x;
        const float* temb = layer ? temb1 : temb0;

        long etotal = (long)BW * Mc * Cc;
        embed_window_k<<<dim3((unsigned)((etotal + 255) / 256)), dim3(256), 0, stream>>>(
            src, temb, semb, CUR, Tin, nw, etotal);

        for (int it = 0; it < 3; it++) {
            // node-mean -> NA/NB (R23 layout, exact inv-multiply)
            mean_nab_k<<<dim3(150), dim3(256), 0, stream>>>(
                CUR, Wa, Wb, NAH, NAL, NBH, NBL, BW);

            // merged: QKV projection + adjacency MM (25 tail blocks)
            int nqkv = BW * 15;
            qkv_adj_k<<<dim3(nqkv + 25), dim3(256), 0, stream>>>(
                CUR, WQH, WQL, bqkv, QH, QL, KH, KL, VTH, VTL,
                NAH, NAL, NBH, NBL, ADJ, nqkv);

            // fused attention + O@Wlin + cand-max (R24: setprio)
            attn_k<<<dim3(BW * 10), dim3(256), 0, stream>>>(
                QH, QL, KH, KL, VTH, VTL, ADJ, WTH, WTL, blin,
                CUR, CAND, it == 0 ? 1 : 0, inv_sqrt_att);
        }
    }
    output_k<<<dim3(Bc * Nc), dim3(128), 0, stream>>>(CAND, Wo, bo, out);
}

// Round 12
// 619.538 us; speedup vs baseline: 1.4178x; 1.0049x over previous
//
#include <hip/hip_runtime.h>
#include <hip/hip_bf16.h>
#include <math.h>

constexpr int Bc   = 4;
constexpr int Nc   = 200;
constexpr int Cc   = 64;
constexpr int Mc   = 600;    // 3*N
constexpr int ATTc = 128;
constexpr int OUTFc = 128;
constexpr int PREDc = 12;
constexpr int MAXBW = 40;
constexpr int MPAD  = 640;   // padded V^T leading dim

typedef short short4v __attribute__((ext_vector_type(4)));
typedef short short8 __attribute__((ext_vector_type(8)));
typedef float f32x4  __attribute__((ext_vector_type(4)));

static __device__ __forceinline__ void bsplit(float v, short& h, short& l) {
    __hip_bfloat16 hb = __float2bfloat16(v);
    float hf = __bfloat162float(hb);
    __hip_bfloat16 lb = __float2bfloat16(v - hf);
    h = *(short*)&hb; l = *(short*)&lb;
}

// ------- fused node-mean + NA/NB projection (R25: inline embed for it=0) ---
__global__ __launch_bounds__(256)
void mean_nab_k(const float* __restrict__ cur, const float* __restrict__ Wa,
                const float* __restrict__ Wb,
                ushort* __restrict__ NAH, ushort* __restrict__ NAL,
                ushort* __restrict__ NBH, ushort* __restrict__ NBL, int BW,
                const float* __restrict__ src, const float* __restrict__ temb,
                const float* __restrict__ semb, int Tin, int nw, int emb)
{
    __shared__ float Ns[4][64];    // [row][k] mean
    __shared__ float Ws[64][132];  // [k][ Wa | Wb ]
    const int m0 = blockIdx.x * 4;
    const int t = threadIdx.x;
    for (int e = t; e < 1024; e += 256) {
        int r = e >> 4, c4 = (e & 15) << 2;
        *(float4*)&Ws[r][c4]      = *(const float4*)&Wa[r * 64 + c4];
        *(float4*)&Ws[r][64 + c4] = *(const float4*)&Wb[r * 64 + c4];
    }
    {
        int row = t >> 6, c = t & 63;      // 4 rows x 64 channels
        int gm = m0 + row;
        float sv = 0.f;
        if (emb) {
            // inline src+temb+semb, same bw order / same FP association
            int j = gm / Nc, n = gm - j * Nc;
            float sb = semb[n * Cc + c];
            for (int b = 0; b < Bc; b++)
                for (int w_ = 0; w_ < nw; w_++) {
                    int t_ = w_ + j;
                    float v = src[(((long)b * Tin + t_) * Nc + n) * Cc + c]
                            + temb[t_ * Cc + c] + sb;
                    sv += v;
                }
        } else {
            for (int bw = 0; bw < BW; bw++)
                sv += cur[((long)bw * Mc + gm) * Cc + c];
        }
        const float inv = 1.f / BW;
        Ns[row][c] = sv * inv;
    }
    __syncthreads();
#pragma unroll
    for (int o = 0; o < 2; o++) {
        int e = t + o * 256;               // 0..511
        int row = e >> 7, col = e & 127;
        float acc = 0.f;
        for (int k = 0; k < 64; k++)
            acc += Ns[row][k] * Ws[k][col];
        int gm = m0 + row;
        short h, l;
        bsplit(acc, h, l);
        if (col < 64) { NAH[gm * 64 + col] = (ushort)h; NAL[gm * 64 + col] = (ushort)l; }
        else { NBH[gm * 64 + col - 64] = (ushort)h; NBL[gm * 64 + col - 64] = (ushort)l; }
    }
}

// ---------------- combined one-shot weight prep ----------------------------
__global__ __launch_bounds__(256)
void prep_k(const float* __restrict__ Wlin,
            ushort* __restrict__ WTH, ushort* __restrict__ WTL,
            const float* __restrict__ Wqkv,
            ushort* __restrict__ WQH, ushort* __restrict__ WQL)
{
    int i = blockIdx.x * 256 + threadIdx.x;
    if (i < 64 * 128) {
        int c = i >> 7, a = i & 127;
        short h, l;
        bsplit(Wlin[a * 64 + c], h, l);
        WTH[c * 128 + a] = (ushort)h;
        WTL[c * 128 + a] = (ushort)l;
    } else {
        int j = i - 64 * 128;
        if (j < 384 * 64) {
            int n = j >> 6, c = j & 63;
            short h, l;
            bsplit(Wqkv[c * 384 + n], h, l);
            WQH[n * 64 + c] = (ushort)h;
            WQL[n * 64 + c] = (ushort)l;
        }
    }
}

// ---- merged QKV projection + adjacency MM (R25: inline embed for it=0) ----
__global__ __launch_bounds__(256)
void qkv_adj_k(const float* __restrict__ CURp,
               const ushort* __restrict__ WQH, const ushort* __restrict__ WQL,
               const float* __restrict__ bias,
               ushort* __restrict__ QH, ushort* __restrict__ QL,
               ushort* __restrict__ KH, ushort* __restrict__ KL,
               ushort* __restrict__ VTH, ushort* __restrict__ VTL,
               const ushort* __restrict__ Ah, const ushort* __restrict__ Al,
               const ushort* __restrict__ Bh, const ushort* __restrict__ Bl,
               float* __restrict__ ADJ, int nqkv,
               const float* __restrict__ src, const float* __restrict__ temb,
               const float* __restrict__ semb, int Tin, int nw, int emb)
{
    __shared__ __align__(16) ushort SM[36864];   // 72 KB, multi-purpose
    const int t = threadIdx.x;
    const int lane = t & 63, w = t >> 6;
    const int lm = lane & 15, lq = lane >> 4;

    if ((int)blockIdx.x >= nqkv) {
        // ================= adjmm body =================
        const int b2 = blockIdx.x - nqkv;
        const int m0 = (b2 / 5) * 128, n0 = (b2 % 5) * 128;
        ushort (*As)[128][40] = (ushort (*)[128][40])(SM);          // 20 KB
        ushort (*Bs)[128][40] = (ushort (*)[128][40])(SM + 10240);  // 20 KB
        const int wm = (w >> 1) * 64, wn = (w & 1) * 64;

        f32x4 acc[4][4];
#pragma unroll
        for (int i = 0; i < 4; i++)
#pragma unroll
            for (int j = 0; j < 4; j++)
#pragma unroll
                for (int r = 0; r < 4; r++) acc[i][j][r] = 0.f;

        for (int k0 = 0; k0 < 64; k0 += 32) {
            __syncthreads();
#pragma unroll
            for (int p = 0; p < 2; p++) {
                int e = t + p * 256;
                int row = e >> 2, ks = (e & 3) << 3;
                {
                    int gm = m0 + row;
                    short8 vh, vl;
#pragma unroll
                    for (int q = 0; q < 8; q++) { vh[q] = 0; vl[q] = 0; }
                    if (gm < Mc) {
                        vh = *(const short8*)(Ah + (long)gm * 64 + k0 + ks);
                        vl = *(const short8*)(Al + (long)gm * 64 + k0 + ks);
                    }
                    *(short8*)&As[0][row][ks] = vh;
                    *(short8*)&As[1][row][ks] = vl;
                }
                {
                    int gn = n0 + row;
                    short8 vh, vl;
#pragma unroll
                    for (int q = 0; q < 8; q++) { vh[q] = 0; vl[q] = 0; }
                    if (gn < Mc) {
                        vh = *(const short8*)(Bh + (long)gn * 64 + k0 + ks);
                        vl = *(const short8*)(Bl + (long)gn * 64 + k0 + ks);
                    }
                    *(short8*)&Bs[0][row][ks] = vh;
                    *(short8*)&Bs[1][row][ks] = vl;
                }
            }
            __syncthreads();

            short8 af[4][2], bf[4][2];
#pragma unroll
            for (int i = 0; i < 4; i++) {
                af[i][0] = *(const short8*)&As[0][wm + i * 16 + lm][lq * 8];
                af[i][1] = *(const short8*)&As[1][wm + i * 16 + lm][lq * 8];
            }
#pragma unroll
            for (int j = 0; j < 4; j++) {
                bf[j][0] = *(const short8*)&Bs[0][wn + j * 16 + lm][lq * 8];
                bf[j][1] = *(const short8*)&Bs[1][wn + j * 16 + lm][lq * 8];
            }
#pragma unroll
            for (int i = 0; i < 4; i++)
#pragma unroll
                for (int j = 0; j < 4; j++) {
                    acc[i][j] = __builtin_amdgcn_mfma_f32_16x16x32_bf16(af[i][0], bf[j][0], acc[i][j], 0, 0, 0);
                    acc[i][j] = __builtin_amdgcn_mfma_f32_16x16x32_bf16(af[i][0], bf[j][1], acc[i][j], 0, 0, 0);
                    acc[i][j] = __builtin_amdgcn_mfma_f32_16x16x32_bf16(af[i][1], bf[j][0], acc[i][j], 0, 0, 0);
                }
        }
#pragma unroll
        for (int i = 0; i < 4; i++) {
            int gmb = m0 + wm + i * 16 + lq * 4;
#pragma unroll
            for (int j = 0; j < 4; j++) {
                int gn = n0 + wn + j * 16 + lm;
                if (gn >= Mc) continue;
#pragma unroll
                for (int r = 0; r < 4; r++) {
                    int gm = gmb + r;
                    if (gm < Mc)
                        ADJ[(long)gm * Mc + gn] = 1.f / (1.f + __expf(-acc[i][j][r] * 0.125f));
                }
            }
        }
        return;
    }

    // ================= qkv body (R14-proven) =================
    ushort* AsH = SM;                 // [128][72]
    ushort* AsL = SM + 9216;
    ushort* BsH = SM + 18432;
    ushort* BsL = SM + 27648;
    const int bid = blockIdx.x;
    const int xcd = bid & 7, slot = bid >> 3;
    const int z = (slot / 15) * 8 + xcd;
    const int r15 = slot % 15;
    const int which = r15 % 3;             // 0=q 1=k 2=v
    const int m0 = (r15 / 3) * 128;
    const int nb = which * 128;
    const float* A = CURp + (long)z * Mc * Cc;
    const int wm = (w >> 1) * 64, wn = (w & 1) * 64;
    const int zb = z / nw, zw = z - zb * nw;   // batch, window (emb path)

#pragma unroll
    for (int p = 0; p < 8; p++) {
        int e = t + p * 256;              // 0..2047
        int row = e >> 4, k4 = (e & 15) * 4;
        int gm = m0 + row;
        float4 v = make_float4(0.f, 0.f, 0.f, 0.f);
        if (gm < Mc) {
            if (emb) {
                int j = gm / Nc, n = gm - j * Nc;
                int t_ = zw + j;
                v = *(const float4*)(src + (((long)zb * Tin + t_) * Nc + n) * Cc + k4);
                const float4 tb = *(const float4*)(temb + t_ * Cc + k4);
                const float4 sb = *(const float4*)(semb + n * Cc + k4);
                v.x = v.x + tb.x + sb.x; v.y = v.y + tb.y + sb.y;
                v.z = v.z + tb.z + sb.z; v.w = v.w + tb.w + sb.w;
            } else {
                v = *(const float4*)(A + (long)gm * 64 + k4);
            }
        }
        short4v h4, l4;
        short hs, ls;
        bsplit(v.x, hs, ls); h4[0] = hs; l4[0] = ls;
        bsplit(v.y, hs, ls); h4[1] = hs; l4[1] = ls;
        bsplit(v.z, hs, ls); h4[2] = hs; l4[2] = ls;
        bsplit(v.w, hs, ls); h4[3] = hs; l4[3] = ls;
        *(short4v*)(AsH + row * 72 + k4) = h4;
        *(short4v*)(AsL + row * 72 + k4) = l4;
    }
#pragma unroll
    for (int p = 0; p < 4; p++) {
        int e = t + p * 256;              // 0..1023
        int row = e >> 3, seg = (e & 7) * 8;
        *(short8*)(BsH + row * 72 + seg) = *(const short8*)(WQH + (long)(nb + row) * 64 + seg);
        *(short8*)(BsL + row * 72 + seg) = *(const short8*)(WQL + (long)(nb + row) * 64 + seg);
    }
    __syncthreads();

    f32x4 acc[4][4];
#pragma unroll
    for (int i = 0; i < 4; i++)
#pragma unroll
        for (int j = 0; j < 4; j++)
#pragma unroll
            for (int r = 0; r < 4; r++) acc[i][j][r] = 0.f;

#pragma unroll
    for (int ks = 0; ks < 2; ks++) {
        short8 af[4][2], bf[4][2];
#pragma unroll
        for (int i = 0; i < 4; i++) {
            af[i][0] = *(const short8*)(AsH + (wm + i * 16 + lm) * 72 + ks * 32 + lq * 8);
            af[i][1] = *(const short8*)(AsL + (wm + i * 16 + lm) * 72 + ks * 32 + lq * 8);
        }
#pragma unroll
        for (int j = 0; j < 4; j++) {
            bf[j][0] = *(const short8*)(BsH + (wn + j * 16 + lm) * 72 + ks * 32 + lq * 8);
            bf[j][1] = *(const short8*)(BsL + (wn + j * 16 + lm) * 72 + ks * 32 + lq * 8);
        }
#pragma unroll
        for (int i = 0; i < 4; i++)
#pragma unroll
            for (int j = 0; j < 4; j++) {
                acc[i][j] = __builtin_amdgcn_mfma_f32_16x16x32_bf16(af[i][0], bf[j][0], acc[i][j], 0, 0, 0);
                acc[i][j] = __builtin_amdgcn_mfma_f32_16x16x32_bf16(af[i][0], bf[j][1], acc[i][j], 0, 0, 0);
                acc[i][j] = __builtin_amdgcn_mfma_f32_16x16x32_bf16(af[i][1], bf[j][0], acc[i][j], 0, 0, 0);
            }
    }
    __syncthreads();   // frags consumed; SM reused as C scratch

    uint* CP = (uint*)SM;                 // [128][132] uints
#pragma unroll
    for (int i = 0; i < 4; i++)
#pragma unroll
        for (int j = 0; j < 4; j++) {
            int col = wn + j * 16 + lm;
            float b = bias[nb + col];
#pragma unroll
            for (int r = 0; r < 4; r++) {
                int row = wm + i * 16 + lq * 4 + r;
                float v = acc[i][j][r] + b;
                if (which == 2) v = fmaxf(v, 0.f);
                short hs, ls;
                bsplit(v, hs, ls);
                CP[row * 132 + col] = ((uint)(ushort)ls << 16) | (uint)(ushort)hs;
            }
        }
    __syncthreads();

    if (which == 2) {
        ushort* vh = VTH + (long)z * ATTc * MPAD;
        ushort* vl = VTL + (long)z * ATTc * MPAD;
#pragma unroll
        for (int p = 0; p < 8; p++) {
            int e = t + p * 256;          // 0..2047
            int col = e >> 4, rg = (e & 15) * 8;
            if (m0 + rg < Mc) {
                short8 h8, l8;
#pragma unroll
                for (int q = 0; q < 8; q++) {
                    uint u = CP[(rg + q) * 132 + col];
                    h8[q] = (short)(u & 0xffff);
                    l8[q] = (short)(u >> 16);
                }
                *(short8*)(vh + (long)col * MPAD + m0 + rg) = h8;
                *(short8*)(vl + (long)col * MPAD + m0 + rg) = l8;
            }
        }
    } else {
        ushort* dh = (which == 0 ? QH : KH) + (long)z * Mc * ATTc;
        ushort* dl = (which == 0 ? QL : KL) + (long)z * Mc * ATTc;
#pragma unroll
        for (int p = 0; p < 8; p++) {
            int e = t + p * 256;
            int row = e >> 4, seg = (e & 15) * 8;
            int gm = m0 + row;
            if (gm < Mc) {
                short8 h8, l8;
#pragma unroll
                for (int q = 0; q < 8; q++) {
                    uint u = CP[row * 132 + seg + q];
                    h8[q] = (short)(u & 0xffff);
                    l8[q] = (short)(u >> 16);
                }
                *(short8*)(dh + (long)gm * ATTc + seg) = h8;
                *(short8*)(dl + (long)gm * ATTc + seg) = l8;
            }
        }
    }
}

// ---- fused attention + Wlin (R22/R23/R24-proven) --------------------------
#define ISSUE_K(Dh, Dl, kc_, g_)                                        \
  _Pragma("unroll")                                                     \
  for (int p = 0; p < 4; p++) {                                         \
    int key = (kc_) + srow0 + 32 * p;                                   \
    short8 vh, vl;                                                      \
    _Pragma("unroll")                                                   \
    for (int q2 = 0; q2 < 8; q2++) { vh[q2] = 0; vl[q2] = 0; }          \
    if (key < Mc) {                                                     \
      vh = *(const short8*)(Khz + (long)key * ATTc + (g_) * 64 + sks);  \
      vl = *(const short8*)(Klz + (long)key * ATTc + (g_) * 64 + sks);  \
    }                                                                   \
    Dh[p] = vh; Dl[p] = vl;                                             \
  }

#define ISSUE_V(Dh, Dl, kc_, g_)                                                   \
  _Pragma("unroll")                                                                \
  for (int p = 0; p < 4; p++) {                                                    \
    int att = srow0 + 32 * p;                                                      \
    Dh[p] = *(const short8*)(Vhz + (long)att * MPAD + (kc_) + (g_) * 64 + sks);    \
    Dl[p] = *(const short8*)(Vlz + (long)att * MPAD + (kc_) + (g_) * 64 + sks);    \
  }

#define WRITE_SB(Dh, Dl)                                                \
  _Pragma("unroll")                                                     \
  for (int p = 0; p < 4; p++) {                                         \
    *(short8*)&SB[0][srow0 + 32 * p][sks] = Dh[p];                      \
    *(short8*)&SB[1][srow0 + 32 * p][sks] = Dl[p];                      \
  }

#define MFMA_QK(base_)                                                   \
  __builtin_amdgcn_s_setprio(1);                                         \
  _Pragma("unroll")                                                      \
  for (int kk = 0; kk < 2; kk++) {                                       \
    _Pragma("unroll")                                                    \
    for (int j = 0; j < 8; j++) {                                        \
      short8 bh = *(const short8*)&SB[0][j * 16 + lm][kk * 32 + lq * 8]; \
      short8 bl = *(const short8*)&SB[1][j * 16 + lm][kk * 32 + lq * 8]; \
      sacc[j] = __builtin_amdgcn_mfma_f32_16x16x32_bf16(qh[(base_) + kk], bh, sacc[j], 0, 0, 0); \
      sacc[j] = __builtin_amdgcn_mfma_f32_16x16x32_bf16(qh[(base_) + kk], bl, sacc[j], 0, 0, 0); \
      sacc[j] = __builtin_amdgcn_mfma_f32_16x16x32_bf16(ql[(base_) + kk], bh, sacc[j], 0, 0, 0); \
    }                                                                    \
  }                                                                      \
  __builtin_amdgcn_s_setprio(0);

#define MFMA_PV(g_)                                                      \
  __builtin_amdgcn_s_setprio(1);                                         \
  _Pragma("unroll")                                                      \
  for (int kk = 0; kk < 2; kk++) {                                       \
    int po = ((g_) * 64 + kk * 32 + lq * 8) ^ ((lm >> 2) << 3);          \
    short8 ph = *(const short8*)&PH[w][lm][po];                          \
    short8 pl = *(const short8*)&PL[w][lm][po];                          \
    _Pragma("unroll")                                                    \
    for (int j = 0; j < 8; j++) {                                        \
      short8 vh = *(const short8*)&SB[0][j * 16 + lm][kk * 32 + lq * 8]; \
      short8 vl = *(const short8*)&SB[1][j * 16 + lm][kk * 32 + lq * 8]; \
      oacc[j] = __builtin_amdgcn_mfma_f32_16x16x32_bf16(ph, vh, oacc[j], 0, 0, 0); \
      oacc[j] = __builtin_amdgcn_mfma_f32_16x16x32_bf16(ph, vl, oacc[j], 0, 0, 0); \
      oacc[j] = __builtin_amdgcn_mfma_f32_16x16x32_bf16(pl, vh, oacc[j], 0, 0, 0); \
    }                                                                    \
  }                                                                      \
  __builtin_amdgcn_s_setprio(0);

__global__ __launch_bounds__(256, 2)
void attn_k(const ushort* __restrict__ QH, const ushort* __restrict__ QL,
            const ushort* __restrict__ KH, const ushort* __restrict__ KL,
            const ushort* __restrict__ VTH, const ushort* __restrict__ VTL,
            const float* __restrict__ adj,
            const ushort* __restrict__ WTH, const ushort* __restrict__ WTL,
            const float* __restrict__ blin,
            float* __restrict__ CUR, float* __restrict__ cand, int first,
            float scale)
{
    __shared__ __align__(16) ushort SMEM[37888];      // 75,776 B
    typedef ushort sb_t[128][72];
    typedef ushort ph_t[16][152];
    sb_t* SB = (sb_t*)SMEM;                           // [2][128][72]
    ph_t* PH = (ph_t*)(SMEM + 18432);                 // [4][16][152]
    ph_t* PL = (ph_t*)(SMEM + 28160);                 // [4][16][152]
    const int bid = blockIdx.x;
    const int xcd = bid & 7, slot = bid >> 3;
    const int z = (slot / 10) * 8 + xcd;
    const int m0 = (slot % 10) * 64;
    const int t = threadIdx.x;
    const int lane = t & 63, w = t >> 6;
    const int lm = lane & 15, lq = lane >> 4;
    const int qrow0 = m0 + w * 16;
    const int srow0 = t >> 3;          // staging row base 0..31
    const int sks   = (t & 7) << 3;    // staging col 0..56 (x8 shorts)

    const ushort* Qhz = QH + (long)z * Mc * ATTc;
    const ushort* Qlz = QL + (long)z * Mc * ATTc;
    const ushort* Khz = KH + (long)z * Mc * ATTc;
    const ushort* Klz = KL + (long)z * Mc * ATTc;
    const ushort* Vhz = VTH + (long)z * ATTc * MPAD;
    const ushort* Vlz = VTL + (long)z * ATTc * MPAD;

    // ---- prefetch round 0 (chunk 0, K half0) ----
    short8 RAh[4], RAl[4], RBh[4], RBl[4];
    ISSUE_K(RAh, RAl, 0, 0);

    // ---- Q fragments ----
    short8 qh[4], ql[4];
    {
        int qr = qrow0 + lm;
        if (qr < Mc) {
            const ushort* qp = Qhz + (long)qr * ATTc;
            const ushort* qp2 = Qlz + (long)qr * ATTc;
#pragma unroll
            for (int ks = 0; ks < 4; ks++) {
                qh[ks] = *(const short8*)(qp + ks * 32 + lq * 8);
                ql[ks] = *(const short8*)(qp2 + ks * 32 + lq * 8);
            }
        } else {
#pragma unroll
            for (int ks = 0; ks < 4; ks++)
#pragma unroll
                for (int q = 0; q < 8; q++) { qh[ks][q] = 0; ql[ks][q] = 0; }
        }
    }

    f32x4 oacc[8];
#pragma unroll
    for (int j = 0; j < 8; j++)
#pragma unroll
        for (int r = 0; r < 4; r++) oacc[j][r] = 0.f;
    float Er[4] = {}, Sr[4] = {};
    float adjv[8][4];

    for (int c = 0; c < 5; c++) {
        const int kc = c * 128;
        f32x4 sacc[8];
#pragma unroll
        for (int j = 0; j < 8; j++)
#pragma unroll
            for (int r = 0; r < 4; r++) sacc[j][r] = 0.f;

        // ---------- round 0: K half0 ----------
        __syncthreads();
        WRITE_SB(RAh, RAl);
        ISSUE_K(RBh, RBl, kc, 1);
        // prefetch this chunk's adj block into regs (consumed 2 phases later)
#pragma unroll
        for (int j = 0; j < 8; j++) {
            int col = kc + j * 16 + lm;
#pragma unroll
            for (int r = 0; r < 4; r++) {
                int row = qrow0 + lq * 4 + r;
                adjv[j][r] = (col < Mc && row < Mc) ? adj[(long)row * Mc + col] : 0.f;
            }
        }
        __syncthreads();
        MFMA_QK(0);

        // ---------- round 1: K half1 ----------
        __syncthreads();
        WRITE_SB(RBh, RBl);
        ISSUE_V(RAh, RAl, kc, 0);
        __syncthreads();
        MFMA_QK(2);

        // ---------- epilogue: P = exp(s*scale)*adj -> wave-private LDS ----
#pragma unroll
        for (int j = 0; j < 8; j++) {
            int col = kc + j * 16 + lm;
            bool cok = col < Mc;
#pragma unroll
            for (int r = 0; r < 4; r++) {
                float e = cok ? __expf(sacc[j][r] * scale) : 0.f;
                float p = e * adjv[j][r];
                Er[r] += e; Sr[r] += p;
                short hs, ls;
                bsplit(p, hs, ls);
                int cs = (j * 16 + lm) ^ (lq << 3);   // row>>2 == lq swizzle
                PH[w][lq * 4 + r][cs] = (ushort)hs;
                PL[w][lq * 4 + r][cs] = (ushort)ls;
            }
        }

        // ---------- round 2: V half0 ----------
        __syncthreads();
        WRITE_SB(RAh, RAl);
        ISSUE_V(RBh, RBl, kc, 1);
        __syncthreads();
        MFMA_PV(0);

        // ---------- round 3: V half1 ----------
        __syncthreads();
        WRITE_SB(RBh, RBl);
        if (c < 4) {
            ISSUE_K(RAh, RAl, kc + 128, 0);
        } else {
            // T14: issue WlinT epilogue staging loads; latency hides under
            // MFMA_PV(1) + row sums. RAh=WTH parts, RAl=WTL parts.
#pragma unroll
            for (int p = 0; p < 4; p++) {
                int e = t + p * 256;           // 0..1023
                int row = e >> 4, seg = (e & 15) << 3;
                RAh[p] = *(const short8*)(WTH + row * 128 + seg);
                RAl[p] = *(const short8*)(WTL + row * 128 + seg);
            }
        }
        __syncthreads();
        MFMA_PV(1);
    }

    // ---- row sums ----
#pragma unroll
    for (int mk = 1; mk <= 8; mk <<= 1)
#pragma unroll
        for (int r = 0; r < 4; r++) {
            Er[r] += __shfl_xor(Er[r], mk, 64);
            Sr[r] += __shfl_xor(Sr[r], mk, 64);
        }
    float inv[4];
#pragma unroll
    for (int r = 0; r < 4; r++) inv[r] = 1.f / (Sr[r] + 1e-8f * Er[r]);

    // ---- fused O @ Wlin: overlay LDS (SB/PH/PL dead) ----
    __syncthreads();                       // all waves done with SB/PH/PL
    uint*   OP  = (uint*)SMEM;             // [64][132] packed O (33.8 KB)
    ushort* BsF = SMEM + 16896;            // [2][64][136] WlinT (34.8 KB)

    // write pre-staged WlinT regs (loaded in last PV round)
#pragma unroll
    for (int p = 0; p < 4; p++) {
        int e = t + p * 256;               // 0..1023
        int row = e >> 4, seg = (e & 15) << 3;
        *(short8*)(BsF + row * 136 + seg) = RAh[p];
        *(short8*)(BsF + 64 * 136 + row * 136 + seg) = RAl[p];
    }
    // normalized O (packed bf16 hi|lo) -> OP, wave-private rows
#pragma unroll
    for (int j = 0; j < 8; j++)
#pragma unroll
        for (int r = 0; r < 4; r++) {
            int lrow = w * 16 + lq * 4 + r;
            float v = oacc[j][r] * inv[r];
            short hs, ls;
            bsplit(v, hs, ls);
            OP[lrow * 132 + j * 16 + lm] = ((uint)(ushort)ls << 16) | (uint)(ushort)hs;
        }
    __syncthreads();

    // block-local GEMM: each wave computes its 16 rows x 64 cols
    f32x4 cacc[4];
#pragma unroll
    for (int jj = 0; jj < 4; jj++)
#pragma unroll
        for (int r = 0; r < 4; r++) cacc[jj][r] = 0.f;

#pragma unroll
    for (int ks = 0; ks < 4; ks++) {
        short8 ah, al;
        {
            const uint* src = OP + (w * 16 + lm) * 132 + ks * 32 + lq * 8;
            const uint4 u0 = *(const uint4*)src;
            const uint4 u1 = *(const uint4*)(src + 4);
#pragma unroll
            for (int q = 0; q < 4; q++) {
                uint u = ((const uint*)&u0)[q];
                ah[q] = (short)(u & 0xffff); al[q] = (short)(u >> 16);
            }
#pragma unroll
            for (int q = 0; q < 4; q++) {
                uint u = ((const uint*)&u1)[q];
                ah[4 + q] = (short)(u & 0xffff); al[4 + q] = (short)(u >> 16);
            }
        }
#pragma unroll
        for (int jj = 0; jj < 4; jj++) {
            short8 bh = *(const short8*)(BsF + (jj * 16 + lm) * 136 + ks * 32 + lq * 8);
            short8 bl = *(const short8*)(BsF + 64 * 136 + (jj * 16 + lm) * 136 + ks * 32 + lq * 8);
            cacc[jj] = __builtin_amdgcn_mfma_f32_16x16x32_bf16(ah, bh, cacc[jj], 0, 0, 0);
            cacc[jj] = __builtin_amdgcn_mfma_f32_16x16x32_bf16(ah, bl, cacc[jj], 0, 0, 0);
            cacc[jj] = __builtin_amdgcn_mfma_f32_16x16x32_bf16(al, bh, cacc[jj], 0, 0, 0);
        }
    }

    // epilogue: bias + CUR write + fused middle-window running max
    float* CURz = CUR + (long)z * Mc * Cc;
#pragma unroll
    for (int jj = 0; jj < 4; jj++) {
        int col = jj * 16 + lm;
        float b = blin[col];
#pragma unroll
        for (int r = 0; r < 4; r++) {
            int row = m0 + w * 16 + lq * 4 + r;
            if (row < Mc) {
                float v = cacc[jj][r] + b;
                CURz[(long)row * Cc + col] = v;
                if (row >= 2 * Nc) {
                    long o = ((long)z * Nc + (row - 2 * Nc)) * Cc + col;
                    cand[o] = first ? v : fmaxf(cand[o], v);
                }
            }
        }
    }
}

#undef ISSUE_K
#undef ISSUE_V
#undef WRITE_SB
#undef MFMA_QK
#undef MFMA_PV

// ---------------- output layer ----------------
__global__ __launch_bounds__(128)
void output_k(const float* __restrict__ h2, const float* __restrict__ Wo,
              const float* __restrict__ bo, float* __restrict__ out)
{
    __shared__ float ds[512];
    int row = blockIdx.x;
    int b = row / Nc, n = row % Nc;
    int t = threadIdx.x;
    for (int e = t; e < 512; e += 128) {
        int tt = e >> 6, c = e & 63;
        ds[e] = h2[(((long)b * 8 + tt) * Nc + n) * Cc + c];
    }
    __syncthreads();
    float acc = bo[t];
    for (int e = 0; e < 512; e++) acc += ds[e] * Wo[e * OUTFc + t];
    acc = fmaxf(acc, 0.f);
    for (int p = 0; p < PREDc; p++)
        out[(((long)b * PREDc + p) * Nc + n) * (long)OUTFc + t] = acc;
}

extern "C" void kernel_launch(void* const* d_in, const int* in_sizes, int n_in,
                              void* d_out, int out_size, void* d_ws, size_t ws_size,
                              hipStream_t stream)
{
    (void)in_sizes; (void)n_in; (void)out_size; (void)ws_size;
    const float* x     = (const float*)d_in[0];
    const float* Wqkv  = (const float*)d_in[4];
    const float* bqkv  = (const float*)d_in[5];
    const float* Wlin  = (const float*)d_in[6];
    const float* blin  = (const float*)d_in[7];
    const float* Wa    = (const float*)d_in[8];
    const float* Wb    = (const float*)d_in[9];
    const float* temb0 = (const float*)d_in[13];
    const float* temb1 = (const float*)d_in[14];
    const float* semb  = (const float*)d_in[15];
    const float* Wo    = (const float*)d_in[16];
    const float* bo    = (const float*)d_in[17];
    float* out = (float*)d_out;

    // ---- workspace (float offsets, layout unchanged; OB slot unused) ------
    float* ws   = (float*)d_ws;
    float* CUR  = ws;                                  // 1,536,000
    float* ADJ  = CUR + (long)MAXBW * Mc * Cc;         // 360,000
    float* CAND = ADJ + (long)Mc * Mc;                 // 512,000
    uint*  OB   = (uint*)(CAND + (long)MAXBW * Nc * Cc); // unused
    float* QHf  = (float*)(OB + (long)MAXBW * Mc * ATTc);
    const long QSZ = (long)MAXBW * Mc * ATTc / 2;      // in floats
    float* QLf  = QHf + QSZ;
    float* KHf  = QLf + QSZ;
    float* KLf  = KHf + QSZ;
    float* VTHf = KLf + QSZ;
    float* VTLf = VTHf + (long)MAXBW * ATTc * MPAD / 2;
    ushort* NAH = (ushort*)(VTLf + (long)MAXBW * ATTc * MPAD / 2);
    ushort* NAL = NAH + Mc * Cc;
    ushort* NBH = NAL + Mc * Cc;
    ushort* NBL = NBH + Mc * Cc;
    ushort* WTH = NBL + Mc * Cc;                       // 64*128 each
    ushort* WTL = WTH + 64 * 128;
    ushort* WQH = WTL + 64 * 128;                      // 384*64 each
    ushort* WQL = WQH + 384 * 64;

    ushort* QH  = (ushort*)QHf;
    ushort* QL  = (ushort*)QLf;
    ushort* KH  = (ushort*)KHf;
    ushort* KL  = (ushort*)KLf;
    ushort* VTH = (ushort*)VTHf;
    ushort* VTL = (ushort*)VTLf;

    const float inv_sqrt_att = 0.08838834764831845f;   // 1/sqrt(128)

    // one-shot weight prep (both transposed bf16 hi/lo splits)
    prep_k<<<dim3(128), dim3(256), 0, stream>>>(Wlin, WTH, WTL, Wqkv, WQH, WQL);

    for (int layer = 0; layer < 2; layer++) {
        int Tin = layer ? 10 : 12;
        int nw  = Tin - 2;
        int BW  = Bc * nw;                             // 40 then 32
        const float* src  = layer ? CAND : x;
        const float* temb = layer ? temb1 : temb0;

        for (int it = 0; it < 3; it++) {
            int emb = (it == 0) ? 1 : 0;   // iteration 0: inline embed

            // node-mean -> NA/NB (inline embed at it=0)
            mean_nab_k<<<dim3(150), dim3(256), 0, stream>>>(
                CUR, Wa, Wb, NAH, NAL, NBH, NBL, BW,
                src, temb, semb, Tin, nw, emb);

            // merged: QKV projection + adjacency MM (25 tail blocks)
            int nqkv = BW * 15;
            qkv_adj_k<<<dim3(nqkv + 25), dim3(256), 0, stream>>>(
                CUR, WQH, WQL, bqkv, QH, QL, KH, KL, VTH, VTL,
                NAH, NAL, NBH, NBL, ADJ, nqkv,
                src, temb, semb, Tin, nw, emb);

            // fused attention + O@Wlin + cand-max
            attn_k<<<dim3(BW * 10), dim3(256), 0, stream>>>(
                QH, QL, KH, KL, VTH, VTL, ADJ, WTH, WTL, blin,
                CUR, CAND, it == 0 ? 1 : 0, inv_sqrt_att);
        }
    }
    output_k<<<dim3(Bc * Nc), dim3(128), 0, stream>>>(CAND, Wo, bo, out);
}